// Round 7
// baseline (775.615 us; speedup 1.0000x reference)
//
#include <hip/hip_runtime.h>
#include <hip/hip_bf16.h>
#include <cstdint>
#include <cstddef>

#define NND 50000
#define DIN 1488
#define DINP 1536
#define DHID 1024
#define DOUT 512
#define DHC 256
#define NE 800000
#define NHD 8

typedef __attribute__((ext_vector_type(8))) short short8;
typedef __attribute__((ext_vector_type(4))) short short4v;
typedef __attribute__((ext_vector_type(4))) float f32x4;
typedef unsigned short ushort_t;

__device__ __forceinline__ unsigned short f2bf(float f){
  union { float f; unsigned u; } v; v.f = f;
  unsigned r = v.u + 0x7fffu + ((v.u >> 16) & 1u);
  return (unsigned short)(r >> 16);
}
__device__ __forceinline__ float bf2f(unsigned short u){
  union { unsigned u; float f; } v; v.u = ((unsigned)u) << 16;
  return v.f;
}

__device__ __forceinline__ void async16(const void* g, void* l){
  __builtin_amdgcn_global_load_lds((__attribute__((address_space(1))) void*)g,
                                   (__attribute__((address_space(3))) void*)l, 16, 0, 0);
}

// ---------------- LayerNorm (fp32 -> bf16, pad 1488 -> 1536) ----------------
__global__ __launch_bounds__(256) void ln_kernel(const float* __restrict__ x,
                                                 const float* __restrict__ gw,
                                                 const float* __restrict__ bw,
                                                 ushort_t* __restrict__ xn){
  const int row = blockIdx.x;
  const float* xr = x + (size_t)row * DIN;
  const int t = threadIdx.x;
  float s = 0.f, sq = 0.f;
  for (int i = t*4; i < DIN; i += 1024){
    f32x4 v = *(const f32x4*)(xr + i);
    s  += v.x + v.y + v.z + v.w;
    sq += v.x*v.x + v.y*v.y + v.z*v.z + v.w*v.w;
  }
  for (int o = 32; o; o >>= 1){ s += __shfl_xor(s, o); sq += __shfl_xor(sq, o); }
  __shared__ float rs[4], rq[4];
  const int wid = t >> 6, lane = t & 63;
  if (!lane){ rs[wid] = s; rq[wid] = sq; }
  __syncthreads();
  s = rs[0]+rs[1]+rs[2]+rs[3]; sq = rq[0]+rq[1]+rq[2]+rq[3];
  const float mu = s * (1.f/DIN);
  const float var = sq * (1.f/DIN) - mu*mu;
  const float rstd = rsqrtf(var + 1e-5f);
  ushort_t* xo = xn + (size_t)row * DINP;
  for (int i = t*4; i < DIN; i += 1024){
    f32x4 v = *(const f32x4*)(xr + i);
    f32x4 gg = *(const f32x4*)(gw + i);
    f32x4 bb = *(const f32x4*)(bw + i);
    union { ushort_t u[4]; unsigned long long q; } o;
    o.u[0] = f2bf((v.x-mu)*rstd*gg.x + bb.x);
    o.u[1] = f2bf((v.y-mu)*rstd*gg.y + bb.y);
    o.u[2] = f2bf((v.z-mu)*rstd*gg.z + bb.z);
    o.u[3] = f2bf((v.w-mu)*rstd*gg.w + bb.w);
    *(unsigned long long*)(xo + i) = o.q;
  }
  if (t < (DINP - DIN)) xo[DIN + t] = 0;   // zero K-pad (48 elems)
}

// ---------------- transpose + cast fp32 [K,N] -> bf16 [N,Kp] ----------------
__global__ __launch_bounds__(256) void transpose_cast(const float* __restrict__ W,
                                                      ushort_t* __restrict__ WT,
                                                      int K, int Nn, int Kp){
  __shared__ float tile[32][33];
  const int tx = threadIdx.x & 31, ty = threadIdx.x >> 5;
  const int k0 = blockIdx.x*32, n0 = blockIdx.y*32;
  for (int i = ty; i < 32; i += 8){
    int k = k0 + i, n = n0 + tx;
    tile[i][tx] = (k < K && n < Nn) ? W[(size_t)k*Nn + n] : 0.f;
  }
  __syncthreads();
  for (int i = ty; i < 32; i += 8){
    int n = n0 + i, k = k0 + tx;
    if (n < Nn && k < Kp) WT[(size_t)n*Kp + k] = f2bf(tile[tx][i]);
  }
}

// ------------- 8-phase pipelined 256x256 bf16 MFMA GEMM (T1..T5) -----------
// C[M,Nn] = A[M,K]*BT[Nn,K]^T + bias. K mult 64 (nk>=2), Nn mult 256.
// 512 thr = 8 waves (2Mx4N), BK=64, 128KB dbuf LDS, both-sides XOR swizzle.
// Per K-tile: 4 phases, each {ds_read subtile | stage | bar | lgkm(0) |
// 16 MFMA quadrant | bar}; stage T_{t+2}: A @ ph2, B @ ph3; vmcnt(8) once
// per tile after ph3 MFMA (0 only for the last two tiles).
template<int ACT, int MODE, int CB>
__global__ __launch_bounds__(512, 2) void gemm_bt(const ushort_t* __restrict__ A,
                                                  const ushort_t* __restrict__ BT,
                                                  const float* __restrict__ bias,
                                                  void* __restrict__ out0,
                                                  void* __restrict__ out1,
                                                  int M, int Nn, int K){
  __shared__ __align__(16) ushort_t lds[2][2][256*64];   // 128 KiB
  const int t = threadIdx.x, wid = t >> 6, lane = t & 63;

  // T1: XCD-chunked bijective swizzle (m204)
  const int bid = blockIdx.x, nwg = gridDim.x;
  const int q = nwg >> 3, r = nwg & 7;
  const int xcd = bid & 7, slot = bid >> 3;
  const int lg = (xcd < r ? xcd*(q+1) : r*(q+1) + (xcd - r)*q) + slot;
  const int brow = (lg / CB) * 256, bcol = (lg % CB) * 256;

  // staging addressing: thread t covers LDS row (rd*64 + t>>3), colbyte
  // (t&7)*16; source col pre-swizzled so linear LDS write lands swizzled.
  const int l8  = t >> 3;
  const int cb  = (t & 7) << 4;
  const unsigned scb = (unsigned)(cb ^ ((l8 & 7) << 4));
  unsigned rowA[4], rowB[4];
  #pragma unroll
  for (int rd = 0; rd < 4; ++rd){
    int ra = brow + rd*64 + l8; ra = ra < M ? ra : M-1;
    int rb = bcol + rd*64 + l8; rb = rb < Nn ? rb : Nn-1;
    rowA[rd] = (unsigned)ra * (unsigned)(K*2);
    rowB[rd] = (unsigned)rb * (unsigned)(K*2);
  }
  const int wst = (wid * 8) * 64;          // wave LDS elem base per 64-row rd

#define STAGE_A(buf, kt) do {                                             \
    const unsigned _ob = (unsigned)(kt)*128u + scb;                       \
    _Pragma("unroll")                                                     \
    for (int _rd = 0; _rd < 4; ++_rd)                                     \
      async16((const char*)A  + rowA[_rd] + _ob, &lds[buf][0][_rd*64*64 + wst]); \
  } while(0)
#define STAGE_B(buf, kt) do {                                             \
    const unsigned _ob = (unsigned)(kt)*128u + scb;                       \
    _Pragma("unroll")                                                     \
    for (int _rd = 0; _rd < 4; ++_rd)                                     \
      async16((const char*)BT + rowB[_rd] + _ob, &lds[buf][1][_rd*64*64 + wst]); \
  } while(0)

  f32x4 acc[8][4];
  #pragma unroll
  for (int i=0;i<8;i++)
    #pragma unroll
    for (int j=0;j<4;j++) acc[i][j] = (f32x4){0.f,0.f,0.f,0.f};

  const int wrow = (wid >> 2), wcol = (wid & 3);   // 2 x 4 waves
  const int fr = lane & 15;
  const int kb0 = (lane >> 4) << 4;
  const int sx  = (fr & 7) << 4;
  const int ko0 = ((kb0      ) ^ sx) >> 1;
  const int ko1 = ((kb0 | 64 ) ^ sx) >> 1;

#define RD_A(m) do {                                        \
    const int _ra = (wrow*128 + (m)*16 + fr)*64;            \
    af[m][0] = *(const short8*)&bA[_ra + ko0];              \
    af[m][1] = *(const short8*)&bA[_ra + ko1];              \
  } while(0)
#define RD_B(n) do {                                        \
    const int _rb = (wcol*64 + (n)*16 + fr)*64;             \
    bf[n][0] = *(const short8*)&bB[_rb + ko0];              \
    bf[n][1] = *(const short8*)&bB[_rb + ko1];              \
  } while(0)
#define SYNC_PRE() do {                                     \
    __builtin_amdgcn_s_barrier();                           \
    asm volatile("s_waitcnt lgkmcnt(0)" ::: "memory");      \
    __builtin_amdgcn_sched_barrier(0);                      \
  } while(0)
#define MFMA_Q(M0, N0) do {                                 \
    __builtin_amdgcn_s_setprio(1);                          \
    _Pragma("unroll")                                       \
    for (int _m=(M0); _m<(M0)+4; ++_m)                      \
      _Pragma("unroll")                                     \
      for (int _n=(N0); _n<(N0)+2; ++_n){                   \
        acc[_m][_n] = __builtin_amdgcn_mfma_f32_16x16x32_bf16(af[_m][0], bf[_n][0], acc[_m][_n], 0, 0, 0); \
        acc[_m][_n] = __builtin_amdgcn_mfma_f32_16x16x32_bf16(af[_m][1], bf[_n][1], acc[_m][_n], 0, 0, 0); \
      }                                                     \
    __builtin_amdgcn_s_setprio(0);                          \
  } while(0)

  const int nk = K >> 6;
  // prologue: stage tiles 0,1; make T0 visible
  STAGE_A(0, 0); STAGE_B(0, 0);
  STAGE_A(1, 1); STAGE_B(1, 1);
  asm volatile("s_waitcnt vmcnt(8)" ::: "memory");
  __builtin_amdgcn_s_barrier();

  for (int kt = 0; kt < nk; ++kt){
    const int buf = kt & 1;
    const ushort_t* bA = lds[buf][0];
    const ushort_t* bB = lds[buf][1];
    const bool st = (kt + 2 < nk);
    short8 af[8][2], bf[4][2];

    // ---- ph0: read A m0-3 (8) + B n0-1 (4); MFMA q0 = m[0,4) x n[0,2)
    RD_A(0); RD_A(1); RD_A(2); RD_A(3);
    RD_B(0); RD_B(1);
    SYNC_PRE();
    MFMA_Q(0, 0);
    __builtin_amdgcn_s_barrier();

    // ---- ph1: read A m4-7 (8); MFMA q1 = m[4,8) x n[0,2)
    RD_A(4); RD_A(5); RD_A(6); RD_A(7);
    SYNC_PRE();
    MFMA_Q(4, 0);
    __builtin_amdgcn_s_barrier();
    // all A-reads of this buffer complete across waves (lgkm(0)+barrier)

    // ---- ph2: read B n2-3 (4); stage A of T_{kt+2}; MFMA q2 = m[0,4) x n[2,4)
    RD_B(2); RD_B(3);
    if (st) STAGE_A(buf, kt + 2);
    SYNC_PRE();
    MFMA_Q(0, 2);
    __builtin_amdgcn_s_barrier();
    // all B-reads complete across waves

    // ---- ph3: stage B of T_{kt+2}; MFMA q3 = m[4,8) x n[2,4); vmcnt; bar
    if (st) STAGE_B(buf, kt + 2);
    __builtin_amdgcn_s_barrier();
    asm volatile("" ::: "memory");
    MFMA_Q(4, 2);
    if (st) asm volatile("s_waitcnt vmcnt(8)" ::: "memory");
    else    asm volatile("s_waitcnt vmcnt(0)" ::: "memory");
    __builtin_amdgcn_s_barrier();
  }
#undef STAGE_A
#undef STAGE_B
#undef RD_A
#undef RD_B
#undef SYNC_PRE
#undef MFMA_Q

  // ---- epilogue: repack through 128KB LDS, coalesced 512B-row stores ----
  const bool isf32 = (MODE == 0) || (MODE == 2 && bcol == 0);
  float bv[4];
  #pragma unroll
  for (int n=0;n<4;n++){
    const int col = bcol + wcol*64 + n*16 + (lane & 15);
    float b = 0.f;
    if (MODE == 1){ if (bias) b = bias[col]; }
    if (MODE == 2){ if (isf32) b = bias[col]; }
    bv[n] = b;
  }

  if (isf32){
    float* outF; int ostride, ocb;
    if (MODE == 0){ outF = (float*)out0; ostride = Nn;  ocb = bcol; }
    else          { outF = (float*)out0; ostride = 256; ocb = 0;    }
    float* sF = (float*)&lds[0][0][0];                 // [128][256] f32
    #pragma unroll
    for (int p = 0; p < 2; ++p){
      __syncthreads();
      if (wrow == p){
        #pragma unroll
        for (int m=0;m<8;m++){
          const int row = m*16 + (lane >> 4)*4;
          #pragma unroll
          for (int n=0;n<4;n++){
            const int col = wcol*64 + n*16 + (lane & 15);
            #pragma unroll
            for (int j=0;j<4;j++){
              float v = acc[m][n][j] + bv[n];
              if (ACT) v = v > 0.f ? v : 0.f;
              sF[(row+j)*256 + col] = v;
            }
          }
        }
      }
      __syncthreads();
      const int srow = t >> 6, scol4 = (t & 63) * 4;
      #pragma unroll
      for (int rr = 0; rr < 16; ++rr){
        const int rloc = rr*8 + srow;
        const int grow = brow + p*128 + rloc;
        if (grow < M)
          *(f32x4*)(outF + (size_t)grow*ostride + ocb + scol4) = *(const f32x4*)&sF[rloc*256 + scol4];
      }
    }
  } else {
    ushort_t* outB; int ostride, ocb;
    if (MODE == 1){ outB = (ushort_t*)out0; ostride = Nn;  ocb = bcol; }
    else          { outB = (ushort_t*)out1; ostride = 256; ocb = 0;    }
    ushort_t* sB = (ushort_t*)&lds[0][0][0];           // [256][256] bf16
    __syncthreads();
    #pragma unroll
    for (int m=0;m<8;m++){
      const int row = wrow*128 + m*16 + (lane >> 4)*4;
      #pragma unroll
      for (int n=0;n<4;n++){
        const int col = wcol*64 + n*16 + (lane & 15);
        #pragma unroll
        for (int j=0;j<4;j++){
          float v = acc[m][n][j] + bv[n];
          if (ACT) v = v > 0.f ? v : 0.f;
          sB[(row+j)*256 + col] = f2bf(v);
        }
      }
    }
    __syncthreads();
    const int srow = t >> 5, scol8 = (t & 31) * 8;
    #pragma unroll
    for (int rr = 0; rr < 16; ++rr){
      const int rloc = rr*16 + srow;
      const int grow = brow + rloc;
      if (grow < M)
        *(short8*)(outB + (size_t)grow*ostride + ocb + scol8) = *(const short8*)&sB[rloc*256 + scol8];
    }
  }
}

// ---------------- attention scores a_src/a_dst: [N,8] = sum_c g*att --------
__global__ __launch_bounds__(256) void att_scores(const ushort_t* __restrict__ gm,
                                                  const float* __restrict__ att_s,
                                                  const float* __restrict__ att_d,
                                                  float* __restrict__ asrc,
                                                  float* __restrict__ adst){
  __shared__ float ss[256], sd[256];
  const int t = threadIdx.x;
  ss[t] = att_s[t]; sd[t] = att_d[t];
  __syncthreads();
  const int idx = blockIdx.x*256 + t;
  if (idx >= NND*NHD) return;
  const int n = idx >> 3, h = idx & 7;
  const ushort_t* gr = gm + (size_t)n*DHC + h*32;
  float a = 0.f, d = 0.f;
  #pragma unroll
  for (int c0 = 0; c0 < 32; c0 += 8){
    short8 gv = *(const short8*)(gr + c0);
    #pragma unroll
    for (int j = 0; j < 8; ++j){
      float g = bf2f((ushort_t)gv[j]);
      a += g*ss[h*32+c0+j]; d += g*sd[h*32+c0+j];
    }
  }
  asrc[idx] = a; adst[idx] = d;
}

// ---------------- CSR build ----------------
__global__ void init_cnt(int* cnt){
  int i = blockIdx.x*256 + threadIdx.x;
  if (i < NND) cnt[i] = 1;                       // self-loop
}
__global__ void count_edges(const int* __restrict__ ei, int* cnt){
  int e = blockIdx.x*256 + threadIdx.x;
  if (e < NE) atomicAdd(&cnt[ei[NE + e]], 1);
}
__global__ __launch_bounds__(1024) void scan_kernel(const int* __restrict__ cnt,
                                                    int* __restrict__ offs,
                                                    int* __restrict__ cur){
  __shared__ int buf[1024];
  const int t = threadIdx.x;
  const int chunk = (NND + 1023) >> 10;
  const int s0 = t*chunk, s1 = (s0 + chunk < NND) ? s0 + chunk : NND;
  int s = 0;
  for (int i = s0; i < s1; ++i) s += cnt[i];
  buf[t] = s; __syncthreads();
  for (int o = 1; o < 1024; o <<= 1){
    int x = (t >= o) ? buf[t-o] : 0;
    __syncthreads();
    buf[t] += x;
    __syncthreads();
  }
  int run = buf[t] - s;                          // exclusive prefix
  for (int i = s0; i < s1; ++i){
    int c = cnt[i];
    cur[i] = run;
    run += c;
    offs[i+1] = run;
  }
  if (t == 0) offs[0] = 0;
}
__global__ void fill_self(int* cur, int* eidx){
  int i = blockIdx.x*256 + threadIdx.x;
  if (i < NND){ int p = atomicAdd(&cur[i], 1); eidx[p] = i; }
}
__global__ void fill_edges(const int* __restrict__ ei, int* cur, int* eidx){
  int e = blockIdx.x*256 + threadIdx.x;
  if (e < NE){
    int src = ei[e], dst = ei[NE + e];
    int p = atomicAdd(&cur[dst], 1);
    eidx[p] = src;
  }
}

// ---------------- fused GAT aggregate + elu + residual (1 wave / node) -----
__global__ __launch_bounds__(256) void gat_agg(const int* __restrict__ offs,
                                               const int* __restrict__ eidx,
                                               const float* __restrict__ asrc,
                                               const float* __restrict__ adst,
                                               const ushort_t* __restrict__ gm,
                                               const float* __restrict__ res,
                                               const float* __restrict__ bg,
                                               float* __restrict__ out){
  const int wid = threadIdx.x >> 6, lane = threadIdx.x & 63;
  const int node = blockIdx.x*4 + wid;
  if (node >= NND) return;
  const int h = lane >> 3;
  const int e0 = offs[node], deg = offs[node+1] - e0;
  const float adv = adst[node*NHD + h];

  float mx = -1e30f;
  for (int j = (lane & 7); j < deg; j += 8){
    int s = eidx[e0 + j];
    float e = asrc[s*NHD + h] + adv; e = e > 0.f ? e : 0.2f*e;
    mx = fmaxf(mx, e);
  }
  mx = fmaxf(mx, __shfl_xor(mx, 1));
  mx = fmaxf(mx, __shfl_xor(mx, 2));
  mx = fmaxf(mx, __shfl_xor(mx, 4));

  float sm = 0.f;
  for (int j = (lane & 7); j < deg; j += 8){
    int s = eidx[e0 + j];
    float e = asrc[s*NHD + h] + adv; e = e > 0.f ? e : 0.2f*e;
    sm += __expf(e - mx);
  }
  sm += __shfl_xor(sm, 1); sm += __shfl_xor(sm, 2); sm += __shfl_xor(sm, 4);
  const float inv = 1.f/(sm + 1e-16f);

  const int c4 = lane*4;                          // channels [c4, c4+4) ; head c4/32 == h
  f32x4 acc = {0.f,0.f,0.f,0.f};
  for (int j = 0; j < deg; ++j){
    int s = eidx[e0 + j];
    float e = asrc[s*NHD + h] + adv; e = e > 0.f ? e : 0.2f*e;
    float w = __expf(e - mx)*inv;
    short4v gv = *(const short4v*)(gm + (size_t)s*DHC + c4);
    acc.x += w*bf2f((ushort_t)gv.x);
    acc.y += w*bf2f((ushort_t)gv.y);
    acc.z += w*bf2f((ushort_t)gv.z);
    acc.w += w*bf2f((ushort_t)gv.w);
  }
  f32x4 bgv = *(const f32x4*)(bg + c4);
  f32x4 rv  = *(const f32x4*)(res + (size_t)node*DHC + c4);
  f32x4 o;
  #pragma unroll
  for (int q = 0; q < 4; ++q){
    float v = acc[q] + bgv[q];
    v = v > 0.f ? v : expm1f(v);
    o[q] = v + rv[q];
  }
  *(f32x4*)(out + (size_t)node*DHC + c4) = o;
}

extern "C" void kernel_launch(void* const* d_in, const int* in_sizes, int n_in,
                              void* d_out, int out_size, void* d_ws, size_t ws_size,
                              hipStream_t stream){
  (void)in_sizes; (void)n_in; (void)out_size; (void)ws_size;
  const float* x     = (const float*)d_in[0];
  const int*   ei    = (const int*)d_in[1];          // int32 per harness convention
  const float* ln_g  = (const float*)d_in[2];
  const float* ln_b  = (const float*)d_in[3];
  const float* W1    = (const float*)d_in[4];
  const float* b1    = (const float*)d_in[5];
  const float* W2    = (const float*)d_in[6];
  const float* b2    = (const float*)d_in[7];
  const float* Wr    = (const float*)d_in[8];
  const float* br    = (const float*)d_in[9];
  const float* Wg    = (const float*)d_in[10];
  const float* att_s = (const float*)d_in[11];
  const float* att_d = (const float*)d_in[12];
  const float* bg    = (const float*)d_in[13];
  float* out = (float*)d_out;

  char* p = (char*)d_ws;
  // persistent region (ws): xn 153.6MB + h1 102.4MB = 256.0MB
  ushort_t* xn   = (ushort_t*)(p);                   // [0, 153,600,000)
  ushort_t* h1   = (ushort_t*)(p + 153600000);       // 102,400,000 -> 256,000,000
  // transposed weights live in d_out (dead until gat_agg overwrites all of it)
  ushort_t* W1T  = (ushort_t*)d_out;                           // 3,145,728
  ushort_t* W2T  = (ushort_t*)((char*)d_out + 3145728);        // 1,048,576
  ushort_t* WrgT = (ushort_t*)((char*)d_out + 4194304);        //   524,288 -> 4,718,592
  // aliased into xn region (xn dead after gemm1)
  ushort_t* hb   = (ushort_t*)(p + 0);               //  51,200,000 (bf16)
  float*    res  = (float*)(p + 51200000);           //  51,200,000 (f32)
  ushort_t* gm   = (ushort_t*)(p + 102400000);       //  25,600,000 (bf16)
  float*    asrc = (float*)(p + 128000000);          //   1,600,000
  float*    adst = (float*)(p + 129600000);          //   1,600,000
  int*      cnt  = (int*)(p + 131200000);            //     200,000
  int*      offs = (int*)(p + 131400064);            //     200,004
  int*      cur  = (int*)(p + 131600128);            //     200,000
  int*      eidx = (int*)(p + 131800192);            //   3,400,000 -> end 135,200,192

  // weight prep (bf16, transposed, K-padded)
  transpose_cast<<<dim3(48,32), 256, 0, stream>>>(W1, W1T, DIN,  DHID, DINP);
  transpose_cast<<<dim3(32,16), 256, 0, stream>>>(W2, W2T, DHID, DOUT, DHID);
  transpose_cast<<<dim3(16, 8), 256, 0, stream>>>(Wr, WrgT,            DOUT, DHC, DOUT);
  transpose_cast<<<dim3(16, 8), 256, 0, stream>>>(Wg, WrgT + 256*DOUT, DOUT, DHC, DOUT);

  ln_kernel<<<NND, 256, 0, stream>>>(x, ln_g, ln_b, xn);

  const int RB = (NND + 255) / 256;   // 196 row blocks
  gemm_bt<1,1,4><<<RB*4, 512, 0, stream>>>(xn, W1T, b1, h1, nullptr, NND, DHID, DINP);
  gemm_bt<0,1,2><<<RB*2, 512, 0, stream>>>(h1, W2T, b2, hb, nullptr, NND, DOUT, DHID);
  gemm_bt<0,2,2><<<RB*2, 512, 0, stream>>>(hb, WrgT, br, res, gm, NND, 2*DHC, DOUT);

  att_scores<<<(NND*NHD + 255)/256, 256, 0, stream>>>(gm, att_s, att_d, asrc, adst);

  init_cnt<<<(NND + 255)/256, 256, 0, stream>>>(cnt);
  count_edges<<<(NE + 255)/256, 256, 0, stream>>>(ei, cnt);
  scan_kernel<<<1, 1024, 0, stream>>>(cnt, offs, cur);
  fill_self<<<(NND + 255)/256, 256, 0, stream>>>(cur, eidx);
  fill_edges<<<(NE + 255)/256, 256, 0, stream>>>(ei, cur, eidx);

  gat_agg<<<(NND + 3)/4, 256, 0, stream>>>(offs, eidx, asrc, adst, gm, res, bg, out);
}

// Round 8
// 762.426 us; speedup vs baseline: 1.0173x; 1.0173x over previous
//
#include <hip/hip_runtime.h>
#include <hip/hip_bf16.h>
#include <cstdint>
#include <cstddef>

#define NND 50000
#define DIN 1488
#define DINP 1536
#define DHID 1024
#define DOUT 512
#define DHC 256
#define NE 800000
#define NHD 8
#define SPLITC 256

typedef __attribute__((ext_vector_type(8))) short short8;
typedef __attribute__((ext_vector_type(4))) short short4v;
typedef __attribute__((ext_vector_type(4))) float f32x4;
typedef unsigned short ushort_t;

__device__ __forceinline__ unsigned short f2bf(float f){
  union { float f; unsigned u; } v; v.f = f;
  unsigned r = v.u + 0x7fffu + ((v.u >> 16) & 1u);
  return (unsigned short)(r >> 16);
}
__device__ __forceinline__ float bf2f(unsigned short u){
  union { unsigned u; float f; } v; v.u = ((unsigned)u) << 16;
  return v.f;
}

__device__ __forceinline__ void async16(const void* g, void* l){
  __builtin_amdgcn_global_load_lds((__attribute__((address_space(1))) void*)g,
                                   (__attribute__((address_space(3))) void*)l, 16, 0, 0);
}

// ---------------- LayerNorm (fp32 -> bf16, pad 1488 -> 1536) ----------------
__global__ __launch_bounds__(256) void ln_kernel(const float* __restrict__ x,
                                                 const float* __restrict__ gw,
                                                 const float* __restrict__ bw,
                                                 ushort_t* __restrict__ xn){
  const int row = blockIdx.x;
  const float* xr = x + (size_t)row * DIN;
  const int t = threadIdx.x;
  float s = 0.f, sq = 0.f;
  for (int i = t*4; i < DIN; i += 1024){
    f32x4 v = *(const f32x4*)(xr + i);
    s  += v.x + v.y + v.z + v.w;
    sq += v.x*v.x + v.y*v.y + v.z*v.z + v.w*v.w;
  }
  for (int o = 32; o; o >>= 1){ s += __shfl_xor(s, o); sq += __shfl_xor(sq, o); }
  __shared__ float rs[4], rq[4];
  const int wid = t >> 6, lane = t & 63;
  if (!lane){ rs[wid] = s; rq[wid] = sq; }
  __syncthreads();
  s = rs[0]+rs[1]+rs[2]+rs[3]; sq = rq[0]+rq[1]+rq[2]+rq[3];
  const float mu = s * (1.f/DIN);
  const float var = sq * (1.f/DIN) - mu*mu;
  const float rstd = rsqrtf(var + 1e-5f);
  ushort_t* xo = xn + (size_t)row * DINP;
  for (int i = t*4; i < DIN; i += 1024){
    f32x4 v = *(const f32x4*)(xr + i);
    f32x4 gg = *(const f32x4*)(gw + i);
    f32x4 bb = *(const f32x4*)(bw + i);
    union { ushort_t u[4]; unsigned long long q; } o;
    o.u[0] = f2bf((v.x-mu)*rstd*gg.x + bb.x);
    o.u[1] = f2bf((v.y-mu)*rstd*gg.y + bb.y);
    o.u[2] = f2bf((v.z-mu)*rstd*gg.z + bb.z);
    o.u[3] = f2bf((v.w-mu)*rstd*gg.w + bb.w);
    *(unsigned long long*)(xo + i) = o.q;
  }
  if (t < (DINP - DIN)) xo[DIN + t] = 0;   // zero K-pad (48 elems)
}

// ---------------- transpose + cast fp32 [K,N] -> bf16 [N,Kp] ----------------
__global__ __launch_bounds__(256) void transpose_cast(const float* __restrict__ W,
                                                      ushort_t* __restrict__ WT,
                                                      int K, int Nn, int Kp){
  __shared__ float tile[32][33];
  const int tx = threadIdx.x & 31, ty = threadIdx.x >> 5;
  const int k0 = blockIdx.x*32, n0 = blockIdx.y*32;
  for (int i = ty; i < 32; i += 8){
    int k = k0 + i, n = n0 + tx;
    tile[i][tx] = (k < K && n < Nn) ? W[(size_t)k*Nn + n] : 0.f;
  }
  __syncthreads();
  for (int i = ty; i < 32; i += 8){
    int n = n0 + i, k = k0 + tx;
    if (n < Nn && k < Kp) WT[(size_t)n*Kp + k] = f2bf(tile[tx][i]);
  }
}

// ------------- R5-proven 128x128 pipelined bf16 MFMA GEMM -------------------
template<int ACT, int MODE, int CB>
__global__ __launch_bounds__(256, 2) void gemm128(const ushort_t* __restrict__ A,
                                                  const ushort_t* __restrict__ BT,
                                                  const float* __restrict__ bias,
                                                  void* __restrict__ out0,
                                                  void* __restrict__ out1,
                                                  int M, int Nn, int K){
  __shared__ __align__(16) ushort_t lds[2][2][128*64];   // 64 KiB
  const int t = threadIdx.x, wid = t >> 6, lane = t & 63;

  const int bid = blockIdx.x, nwg = gridDim.x;
  const int q = nwg >> 3, r = nwg & 7;
  const int xcd = bid & 7, slot = bid >> 3;
  const int lg = (xcd < r ? xcd*(q+1) : r*(q+1) + (xcd - r)*q) + slot;
  const int brow = (lg / CB) * 128, bcol = (lg % CB) * 128;

  const int l8  = t >> 3;
  const int cb  = (t & 7) << 4;
  const int scb = cb ^ ((l8 & 7) << 4);
  const ushort_t* pAr[4]; const ushort_t* pBr[4];
  #pragma unroll
  for (int rd = 0; rd < 4; ++rd){
    int ra = brow + rd*32 + l8; ra = ra < M ? ra : M-1;
    int rb = bcol + rd*32 + l8; rb = rb < Nn ? rb : Nn-1;
    pAr[rd] = A  + (size_t)ra*K + (scb >> 1);
    pBr[rd] = BT + (size_t)rb*K + (scb >> 1);
  }
  const int w8 = wid * 8;

#define STAGE1(buf, kt) do {                                           \
    const int _o = (kt) * 64;                                          \
    _Pragma("unroll")                                                  \
    for (int _rd = 0; _rd < 4; ++_rd){                                 \
      async16(pAr[_rd] + _o, &lds[buf][0][(_rd*32 + w8)*64]);          \
      async16(pBr[_rd] + _o, &lds[buf][1][(_rd*32 + w8)*64]);          \
    }                                                                  \
  } while(0)

  f32x4 acc[4][4];
  #pragma unroll
  for (int i=0;i<4;i++)
    #pragma unroll
    for (int j=0;j<4;j++) acc[i][j] = (f32x4){0.f,0.f,0.f,0.f};

  const int wr = (wid >> 1)*64, wc = (wid & 1)*64;
  const int fr = lane & 15;
  const int kb0 = (lane >> 4) << 4;
  const int sx  = (fr & 7) << 4;
  const int ko0 = ((kb0      ) ^ sx) >> 1;
  const int ko1 = ((kb0 | 64 ) ^ sx) >> 1;

  const int nk = K >> 6;
  STAGE1(0, 0);
  STAGE1(1, 1);
  for (int kt = 0; kt < nk; ++kt){
    const ushort_t* bA = lds[kt & 1][0];
    const ushort_t* bB = lds[kt & 1][1];
    if (kt + 1 < nk) asm volatile("s_waitcnt vmcnt(8)" ::: "memory");
    else             asm volatile("s_waitcnt vmcnt(0)" ::: "memory");
    __builtin_amdgcn_s_barrier();
    short8 af[4][2], bf_[4][2];
    #pragma unroll
    for (int m=0;m<4;m++){
      const int ra = (wr + m*16 + fr)*64;
      const int rb = (wc + m*16 + fr)*64;
      af[m][0]  = *(const short8*)&bA[ra + ko0];
      af[m][1]  = *(const short8*)&bA[ra + ko1];
      bf_[m][0] = *(const short8*)&bB[rb + ko0];
      bf_[m][1] = *(const short8*)&bB[rb + ko1];
    }
    asm volatile("s_waitcnt lgkmcnt(0)" ::: "memory");
    __builtin_amdgcn_sched_barrier(0);
    __builtin_amdgcn_s_barrier();
    if (kt + 2 < nk) STAGE1(kt & 1, kt + 2);
    __builtin_amdgcn_s_setprio(1);
    #pragma unroll
    for (int m=0;m<4;m++)
      #pragma unroll
      for (int n=0;n<4;n++){
        acc[m][n] = __builtin_amdgcn_mfma_f32_16x16x32_bf16(af[m][0], bf_[n][0], acc[m][n], 0, 0, 0);
        acc[m][n] = __builtin_amdgcn_mfma_f32_16x16x32_bf16(af[m][1], bf_[n][1], acc[m][n], 0, 0, 0);
      }
    __builtin_amdgcn_s_setprio(0);
  }
#undef STAGE1

  // epilogue: repack through LDS, coalesced stores, 4 chunks of 32 rows
  bool isf32;
  float* outF = nullptr; ushort_t* outB = nullptr; int ostride = 0, ocb = 0;
  if (MODE == 0){ isf32 = true;  outF = (float*)out0;    ostride = Nn; ocb = bcol; }
  else if (MODE == 1){ isf32 = false; outB = (ushort_t*)out0; ostride = Nn; ocb = bcol; }
  else {
    if (bcol < SPLITC){ isf32 = true;  outF = (float*)out0;    ostride = SPLITC;      ocb = bcol; }
    else              { isf32 = false; outB = (ushort_t*)out1; ostride = Nn - SPLITC; ocb = bcol - SPLITC; }
  }
  float bv[4];
  #pragma unroll
  for (int n=0;n<4;n++){
    const int col = wc + n*16 + (lane & 15);
    float b = 0.f;
    if (MODE == 2){ if (isf32 && bias) b = bias[bcol + col]; }
    else if (bias) b = bias[bcol + col];
    bv[n] = b;
  }
  float* sF = (float*)&lds[0][0][0];
  ushort_t* sB = (ushort_t*)&lds[0][0][0];
  const int trow = t >> 3, tc16 = (t & 7) * 16;
  #pragma unroll
  for (int c = 0; c < 4; ++c){
    __syncthreads();
    if ((wid >> 1) == (c >> 1)){
      #pragma unroll
      for (int mm = 0; mm < 2; ++mm){
        const int m = 2*(c & 1) + mm;
        const int rbase = m*16 + (lane >> 4)*4 - (c & 1)*32;
        #pragma unroll
        for (int n = 0; n < 4; ++n){
          const int col = wc + n*16 + (lane & 15);
          #pragma unroll
          for (int j = 0; j < 4; ++j){
            float v = acc[m][n][j] + bv[n];
            if (ACT) v = v > 0.f ? v : 0.f;
            if (isf32) sF[(rbase + j)*128 + col] = v;
            else       sB[(rbase + j)*128 + col] = f2bf(v);
          }
        }
      }
    }
    __syncthreads();
    const int grow = brow + c*32 + trow;
    if (grow < M){
      if (isf32){
        float* dst = outF + (size_t)grow*ostride + ocb + tc16;
        const float* src = sF + trow*128 + tc16;
        #pragma unroll
        for (int q2 = 0; q2 < 4; ++q2) ((f32x4*)dst)[q2] = ((const f32x4*)src)[q2];
      } else {
        ushort_t* dst = outB + (size_t)grow*ostride + ocb + tc16;
        const ushort_t* src = sB + trow*128 + tc16;
        #pragma unroll
        for (int q2 = 0; q2 < 2; ++q2) ((short8*)dst)[q2] = ((const short8*)src)[q2];
      }
    }
  }
}

// ------------- R6-proven 256x256 pipelined bf16 MFMA GEMM -------------------
template<int ACT, int MODE, int CB>
__global__ __launch_bounds__(512, 2) void gemm256(const ushort_t* __restrict__ A,
                                                  const ushort_t* __restrict__ BT,
                                                  const float* __restrict__ bias,
                                                  void* __restrict__ out0,
                                                  void* __restrict__ out1,
                                                  int M, int Nn, int K){
  __shared__ __align__(16) ushort_t lds[2][2][256*64];   // 128 KiB
  const int t = threadIdx.x, wid = t >> 6, lane = t & 63;

  const int bid = blockIdx.x, nwg = gridDim.x;
  const int q = nwg >> 3, r = nwg & 7;
  const int xcd = bid & 7, slot = bid >> 3;
  const int lg = (xcd < r ? xcd*(q+1) : r*(q+1) + (xcd - r)*q) + slot;
  const int brow = (lg / CB) * 256, bcol = (lg % CB) * 256;

  const int l8  = t >> 3;
  const int cb  = (t & 7) << 4;
  const unsigned scb = (unsigned)(cb ^ ((l8 & 7) << 4));
  unsigned rowA[4], rowB[4];
  #pragma unroll
  for (int rd = 0; rd < 4; ++rd){
    int ra = brow + rd*64 + l8; ra = ra < M ? ra : M-1;
    int rb = bcol + rd*64 + l8; rb = rb < Nn ? rb : Nn-1;
    rowA[rd] = (unsigned)ra * (unsigned)(K*2);
    rowB[rd] = (unsigned)rb * (unsigned)(K*2);
  }
  const int wst = (wid * 8) * 64;

#define STAGE2(buf, kt) do {                                              \
    const unsigned _ob = (unsigned)(kt)*128u + scb;                       \
    _Pragma("unroll")                                                     \
    for (int _rd = 0; _rd < 4; ++_rd){                                    \
      async16((const char*)A  + rowA[_rd] + _ob, &lds[buf][0][_rd*64*64 + wst]); \
      async16((const char*)BT + rowB[_rd] + _ob, &lds[buf][1][_rd*64*64 + wst]); \
    }                                                                     \
  } while(0)

  f32x4 acc[8][4];
  #pragma unroll
  for (int i=0;i<8;i++)
    #pragma unroll
    for (int j=0;j<4;j++) acc[i][j] = (f32x4){0.f,0.f,0.f,0.f};

  const int wrow = (wid >> 2), wcol = (wid & 3);
  const int fr = lane & 15;
  const int kb0 = (lane >> 4) << 4;
  const int sx  = (fr & 7) << 4;
  const int ko0 = ((kb0      ) ^ sx) >> 1;
  const int ko1 = ((kb0 | 64 ) ^ sx) >> 1;

  const int nk = K >> 6;
  STAGE2(0, 0);
  STAGE2(1, 1);
  for (int kt = 0; kt < nk; ++kt){
    const ushort_t* bA = lds[kt & 1][0];
    const ushort_t* bB = lds[kt & 1][1];
    if (kt + 1 < nk) asm volatile("s_waitcnt vmcnt(8)" ::: "memory");
    else             asm volatile("s_waitcnt vmcnt(0)" ::: "memory");
    __builtin_amdgcn_s_barrier();
    short8 af[8][2], bf_[4][2];
    #pragma unroll
    for (int m=0;m<8;m++){
      const int ra = (wrow*128 + m*16 + fr)*64;
      af[m][0] = *(const short8*)&bA[ra + ko0];
      af[m][1] = *(const short8*)&bA[ra + ko1];
    }
    #pragma unroll
    for (int n=0;n<4;n++){
      const int rb = (wcol*64 + n*16 + fr)*64;
      bf_[n][0] = *(const short8*)&bB[rb + ko0];
      bf_[n][1] = *(const short8*)&bB[rb + ko1];
    }
    asm volatile("s_waitcnt lgkmcnt(0)" ::: "memory");
    __builtin_amdgcn_sched_barrier(0);
    __builtin_amdgcn_s_barrier();
    if (kt + 2 < nk) STAGE2(kt & 1, kt + 2);
    __builtin_amdgcn_s_setprio(1);
    #pragma unroll
    for (int m=0;m<8;m++)
      #pragma unroll
      for (int n=0;n<4;n++){
        acc[m][n] = __builtin_amdgcn_mfma_f32_16x16x32_bf16(af[m][0], bf_[n][0], acc[m][n], 0, 0, 0);
        acc[m][n] = __builtin_amdgcn_mfma_f32_16x16x32_bf16(af[m][1], bf_[n][1], acc[m][n], 0, 0, 0);
      }
    __builtin_amdgcn_s_setprio(0);
  }
#undef STAGE2

  const bool isf32 = (MODE == 0) || (MODE == 2 && bcol == 0);
  float bv[4];
  #pragma unroll
  for (int n=0;n<4;n++){
    const int col = bcol + wcol*64 + n*16 + (lane & 15);
    float b = 0.f;
    if (MODE == 1){ if (bias) b = bias[col]; }
    if (MODE == 2){ if (isf32) b = bias[col]; }
    bv[n] = b;
  }

  if (isf32){
    float* outF; int ostride, ocb;
    if (MODE == 0){ outF = (float*)out0; ostride = Nn;  ocb = bcol; }
    else          { outF = (float*)out0; ostride = 256; ocb = 0;    }
    float* sF = (float*)&lds[0][0][0];
    #pragma unroll
    for (int p = 0; p < 2; ++p){
      __syncthreads();
      if (wrow == p){
        #pragma unroll
        for (int m=0;m<8;m++){
          const int row = m*16 + (lane >> 4)*4;
          #pragma unroll
          for (int n=0;n<4;n++){
            const int col = wcol*64 + n*16 + (lane & 15);
            #pragma unroll
            for (int j=0;j<4;j++){
              float v = acc[m][n][j] + bv[n];
              if (ACT) v = v > 0.f ? v : 0.f;
              sF[(row+j)*256 + col] = v;
            }
          }
        }
      }
      __syncthreads();
      const int srow = t >> 6, scol4 = (t & 63) * 4;
      #pragma unroll
      for (int rr = 0; rr < 16; ++rr){
        const int rloc = rr*8 + srow;
        const int grow = brow + p*128 + rloc;
        if (grow < M)
          *(f32x4*)(outF + (size_t)grow*ostride + ocb + scol4) = *(const f32x4*)&sF[rloc*256 + scol4];
      }
    }
  } else {
    ushort_t* outB; int ostride, ocb;
    if (MODE == 1){ outB = (ushort_t*)out0; ostride = Nn;  ocb = bcol; }
    else          { outB = (ushort_t*)out1; ostride = 256; ocb = 0;    }
    ushort_t* sB = (ushort_t*)&lds[0][0][0];
    __syncthreads();
    #pragma unroll
    for (int m=0;m<8;m++){
      const int row = wrow*128 + m*16 + (lane >> 4)*4;
      #pragma unroll
      for (int n=0;n<4;n++){
        const int col = wcol*64 + n*16 + (lane & 15);
        #pragma unroll
        for (int j=0;j<4;j++){
          float v = acc[m][n][j] + bv[n];
          if (ACT) v = v > 0.f ? v : 0.f;
          sB[(row+j)*256 + col] = f2bf(v);
        }
      }
    }
    __syncthreads();
    const int srow = t >> 5, scol8 = (t & 31) * 8;
    #pragma unroll
    for (int rr = 0; rr < 16; ++rr){
      const int rloc = rr*16 + srow;
      const int grow = brow + rloc;
      if (grow < M)
        *(short8*)(outB + (size_t)grow*ostride + ocb + scol8) = *(const short8*)&sB[rloc*256 + scol8];
    }
  }
}

// ---------------- attention scores a_src/a_dst: [N,8] = sum_c g*att --------
__global__ __launch_bounds__(256) void att_scores(const ushort_t* __restrict__ gm,
                                                  const float* __restrict__ att_s,
                                                  const float* __restrict__ att_d,
                                                  float* __restrict__ asrc,
                                                  float* __restrict__ adst){
  __shared__ float ss[256], sd[256];
  const int t = threadIdx.x;
  ss[t] = att_s[t]; sd[t] = att_d[t];
  __syncthreads();
  const int idx = blockIdx.x*256 + t;
  if (idx >= NND*NHD) return;
  const int n = idx >> 3, h = idx & 7;
  const ushort_t* gr = gm + (size_t)n*DHC + h*32;
  float a = 0.f, d = 0.f;
  #pragma unroll
  for (int c0 = 0; c0 < 32; c0 += 8){
    short8 gv = *(const short8*)(gr + c0);
    #pragma unroll
    for (int j = 0; j < 8; ++j){
      float g = bf2f((ushort_t)gv[j]);
      a += g*ss[h*32+c0+j]; d += g*sd[h*32+c0+j];
    }
  }
  asrc[idx] = a; adst[idx] = d;
}

// ---------------- CSR build ----------------
__global__ void count_edges(const int* __restrict__ ei, int* cnt){
  int e = blockIdx.x*256 + threadIdx.x;
  if (e < NE) atomicAdd(&cnt[ei[NE + e]], 1);
}
__global__ __launch_bounds__(1024) void scan_kernel(const int* __restrict__ cnt,
                                                    int* __restrict__ offs,
                                                    int* __restrict__ cur){
  __shared__ int buf[1024];
  const int t = threadIdx.x;
  const int chunk = (NND + 1023) >> 10;
  const int s0 = t*chunk, s1 = (s0 + chunk < NND) ? s0 + chunk : NND;
  int s = 0;
  for (int i = s0; i < s1; ++i) s += cnt[i] + 1;      // +1 self-loop
  buf[t] = s; __syncthreads();
  for (int o = 1; o < 1024; o <<= 1){
    int x = (t >= o) ? buf[t-o] : 0;
    __syncthreads();
    buf[t] += x;
    __syncthreads();
  }
  int run = buf[t] - s;
  for (int i = s0; i < s1; ++i){
    int c = cnt[i] + 1;                                // +1 self-loop
    cur[i] = run;
    run += c;
    offs[i+1] = run;
  }
  if (t == 0) offs[0] = 0;
}
__global__ void fill_both(const int* __restrict__ ei, int* cur, int* eidx){
  int i = blockIdx.x*256 + threadIdx.x;
  if (i < NND){
    int p = atomicAdd(&cur[i], 1); eidx[p] = i;        // self-loop
  } else if (i < NND + NE){
    int e = i - NND;
    int src = ei[e], dst = ei[NE + e];
    int p = atomicAdd(&cur[dst], 1);
    eidx[p] = src;
  }
}

// ------- fused GAT aggregate + elu + residual (1 block of 4 waves / node) ---
__global__ __launch_bounds__(256) void gat_agg(const int* __restrict__ offs,
                                               const int* __restrict__ eidx,
                                               const float* __restrict__ asrc,
                                               const float* __restrict__ adst,
                                               const ushort_t* __restrict__ gm,
                                               const float* __restrict__ res,
                                               const float* __restrict__ bg,
                                               float* __restrict__ out){
  const int node = blockIdx.x;
  const int t = threadIdx.x, lane = t & 63, wid = t >> 6;
  const int e0 = offs[node], deg = offs[node+1] - e0;
  __shared__ float sm_[8], si_[8];
  __shared__ int   eidx_s[32];
  __shared__ float wgt_s[32][9];

  // scores: wave w covers heads {2w, 2w+1}; 32 lanes per head
  {
    const int h = 2*wid + (lane >> 5);
    const float adv = adst[node*NHD + h];
    float mx = -1e30f;
    for (int j = lane & 31; j < deg; j += 32){
      int s = eidx[e0 + j];
      float e = asrc[s*NHD + h] + adv; e = e > 0.f ? e : 0.2f*e;
      mx = fmaxf(mx, e);
    }
    #pragma unroll
    for (int o = 16; o; o >>= 1) mx = fmaxf(mx, __shfl_xor(mx, o));
    float sm = 0.f;
    for (int j = lane & 31; j < deg; j += 32){
      int s = eidx[e0 + j];
      float e = asrc[s*NHD + h] + adv; e = e > 0.f ? e : 0.2f*e;
      sm += __expf(e - mx);
    }
    #pragma unroll
    for (int o = 16; o; o >>= 1) sm += __shfl_xor(sm, o);
    if ((lane & 31) == 0){ sm_[h] = mx; si_[h] = 1.f/(sm + 1e-16f); }
  }
  __syncthreads();

  // gather: thread t owns channel t; per-32-edge chunk precompute weights
  const int c = t, hc = t >> 5;
  const int jh = t & 31, hw = t >> 5;
  const float advw = adst[node*NHD + hw];
  float acc = 0.f;
  for (int j0 = 0; j0 < deg; j0 += 32){
    const int cnt = deg - j0 < 32 ? deg - j0 : 32;
    if (t < cnt) eidx_s[t] = eidx[e0 + j0 + t];
    __syncthreads();
    if (jh < cnt){
      int s = eidx_s[jh];
      float e = asrc[s*NHD + hw] + advw; e = e > 0.f ? e : 0.2f*e;
      wgt_s[jh][hw] = __expf(e - sm_[hw]) * si_[hw];
    }
    __syncthreads();
    for (int j = 0; j < cnt; ++j)
      acc += wgt_s[j][hc] * bf2f(gm[(size_t)eidx_s[j]*DHC + c]);
    __syncthreads();
  }
  float v = acc + bg[c];
  v = v > 0.f ? v : expm1f(v);
  out[(size_t)node*DHC + c] = v + res[(size_t)node*DHC + c];
}

extern "C" void kernel_launch(void* const* d_in, const int* in_sizes, int n_in,
                              void* d_out, int out_size, void* d_ws, size_t ws_size,
                              hipStream_t stream){
  (void)in_sizes; (void)n_in; (void)out_size; (void)ws_size;
  const float* x     = (const float*)d_in[0];
  const int*   ei    = (const int*)d_in[1];
  const float* ln_g  = (const float*)d_in[2];
  const float* ln_b  = (const float*)d_in[3];
  const float* W1    = (const float*)d_in[4];
  const float* b1    = (const float*)d_in[5];
  const float* W2    = (const float*)d_in[6];
  const float* b2    = (const float*)d_in[7];
  const float* Wr    = (const float*)d_in[8];
  const float* br    = (const float*)d_in[9];
  const float* Wg    = (const float*)d_in[10];
  const float* att_s = (const float*)d_in[11];
  const float* att_d = (const float*)d_in[12];
  const float* bg    = (const float*)d_in[13];
  float* out = (float*)d_out;

  char* p = (char*)d_ws;
  // persistent region (ws): xn 153.6MB + h1 102.4MB = 256.0MB
  ushort_t* xn   = (ushort_t*)(p);                   // [0, 153,600,000)
  ushort_t* h1   = (ushort_t*)(p + 153600000);       // 102,400,000 -> 256,000,000
  // transposed weights live in d_out (dead until gat_agg overwrites all of it)
  ushort_t* W1T  = (ushort_t*)d_out;                           // 3,145,728
  ushort_t* W2T  = (ushort_t*)((char*)d_out + 3145728);        // 1,048,576
  ushort_t* WrgT = (ushort_t*)((char*)d_out + 4194304);        //   524,288
  // aliased into xn region (xn dead after gemm1)
  ushort_t* hb   = (ushort_t*)(p + 0);               //  51,200,000 (bf16)
  float*    res  = (float*)(p + 51200000);           //  51,200,000 (f32)
  ushort_t* gm   = (ushort_t*)(p + 102400000);       //  25,600,000 (bf16)
  float*    asrc = (float*)(p + 128000000);          //   1,600,000
  float*    adst = (float*)(p + 129600000);          //   1,600,000
  int*      cnt  = (int*)(p + 131200000);            //     200,000
  int*      offs = (int*)(p + 131400064);            //     200,004
  int*      cur  = (int*)(p + 131600128);            //     200,000
  int*      eidx = (int*)(p + 131800192);            //   3,400,000

  transpose_cast<<<dim3(48,32), 256, 0, stream>>>(W1, W1T, DIN,  DHID, DINP);
  transpose_cast<<<dim3(32,16), 256, 0, stream>>>(W2, W2T, DHID, DOUT, DHID);
  transpose_cast<<<dim3(16, 8), 256, 0, stream>>>(Wr, WrgT,            DOUT, DHC, DOUT);
  transpose_cast<<<dim3(16, 8), 256, 0, stream>>>(Wg, WrgT + 256*DOUT, DOUT, DHC, DOUT);

  ln_kernel<<<NND, 256, 0, stream>>>(x, ln_g, ln_b, xn);

  const int RB128 = (NND + 127) / 128;   // 391
  const int RB256 = (NND + 255) / 256;   // 196
  gemm128<1,1,8><<<RB128*8, 256, 0, stream>>>(xn, W1T, b1, h1, nullptr, NND, DHID, DINP);
  gemm256<0,1,2><<<RB256*2, 512, 0, stream>>>(h1, W2T, b2, hb, nullptr, NND, DOUT, DHID);
  gemm256<0,2,2><<<RB256*2, 512, 0, stream>>>(hb, WrgT, br, res, gm, NND, 2*DHC, DOUT);

  att_scores<<<(NND*NHD + 255)/256, 256, 0, stream>>>(gm, att_s, att_d, asrc, adst);

  hipMemsetAsync(cnt, 0, NND*sizeof(int), stream);
  count_edges<<<(NE + 255)/256, 256, 0, stream>>>(ei, cnt);
  scan_kernel<<<1, 1024, 0, stream>>>(cnt, offs, cur);
  fill_both<<<(NND + NE + 255)/256, 256, 0, stream>>>(ei, cur, eidx);

  gat_agg<<<NND, 256, 0, stream>>>(offs, eidx, asrc, adst, gm, res, bg, out);
}

// Round 9
// 712.165 us; speedup vs baseline: 1.0891x; 1.0706x over previous
//
#include <hip/hip_runtime.h>
#include <hip/hip_bf16.h>
#include <cstdint>
#include <cstddef>

#define NND 50000
#define DIN 1488
#define DINP 1536
#define DHID 1024
#define DOUT 512
#define DHC 256
#define NE 800000
#define NHD 8
#define SPLITC 256

typedef __attribute__((ext_vector_type(8))) short short8;
typedef __attribute__((ext_vector_type(4))) short short4v;
typedef __attribute__((ext_vector_type(4))) float f32x4;
typedef unsigned short ushort_t;

__device__ __forceinline__ unsigned short f2bf(float f){
  union { float f; unsigned u; } v; v.f = f;
  unsigned r = v.u + 0x7fffu + ((v.u >> 16) & 1u);
  return (unsigned short)(r >> 16);
}
__device__ __forceinline__ float bf2f(unsigned short u){
  union { unsigned u; float f; } v; v.u = ((unsigned)u) << 16;
  return v.f;
}

__device__ __forceinline__ void async16(const void* g, void* l){
  __builtin_amdgcn_global_load_lds((__attribute__((address_space(1))) void*)g,
                                   (__attribute__((address_space(3))) void*)l, 16, 0, 0);
}

// ---------------- LayerNorm: wave per row (fp32 -> bf16, pad to 1536) -------
__global__ __launch_bounds__(256) void ln_kernel(const float* __restrict__ x,
                                                 const float* __restrict__ gw,
                                                 const float* __restrict__ bw,
                                                 ushort_t* __restrict__ xn){
  const int wid = threadIdx.x >> 6, lane = threadIdx.x & 63;
  const int row = blockIdx.x*4 + wid;
  if (row >= NND) return;
  const float* xr = x + (size_t)row * DIN;
  float s = 0.f, sq = 0.f;
  for (int i = lane*4; i < DIN; i += 256){
    f32x4 v = *(const f32x4*)(xr + i);
    s  += v.x + v.y + v.z + v.w;
    sq += v.x*v.x + v.y*v.y + v.z*v.z + v.w*v.w;
  }
  #pragma unroll
  for (int o = 32; o; o >>= 1){ s += __shfl_xor(s, o); sq += __shfl_xor(sq, o); }
  const float mu = s * (1.f/DIN);
  const float var = sq * (1.f/DIN) - mu*mu;
  const float rstd = rsqrtf(var + 1e-5f);
  ushort_t* xo = xn + (size_t)row * DINP;
  for (int i = lane*4; i < DIN; i += 256){
    f32x4 v = *(const f32x4*)(xr + i);
    f32x4 gg = *(const f32x4*)(gw + i);
    f32x4 bb = *(const f32x4*)(bw + i);
    union { ushort_t u[4]; unsigned long long q; } o;
    o.u[0] = f2bf((v.x-mu)*rstd*gg.x + bb.x);
    o.u[1] = f2bf((v.y-mu)*rstd*gg.y + bb.y);
    o.u[2] = f2bf((v.z-mu)*rstd*gg.z + bb.z);
    o.u[3] = f2bf((v.w-mu)*rstd*gg.w + bb.w);
    *(unsigned long long*)(xo + i) = o.q;
  }
  if (lane < (DINP - DIN)) xo[DIN + lane] = 0;
}

// ---------------- transpose + cast fp32 [K,N] -> bf16 [N,Kp] ----------------
__global__ __launch_bounds__(256) void transpose_cast(const float* __restrict__ W,
                                                      ushort_t* __restrict__ WT,
                                                      int K, int Nn, int Kp){
  __shared__ float tile[32][33];
  const int tx = threadIdx.x & 31, ty = threadIdx.x >> 5;
  const int k0 = blockIdx.x*32, n0 = blockIdx.y*32;
  for (int i = ty; i < 32; i += 8){
    int k = k0 + i, n = n0 + tx;
    tile[i][tx] = (k < K && n < Nn) ? W[(size_t)k*Nn + n] : 0.f;
  }
  __syncthreads();
  for (int i = ty; i < 32; i += 8){
    int n = n0 + i, k = k0 + tx;
    if (n < Nn && k < Kp) WT[(size_t)n*Kp + k] = f2bf(tile[tx][i]);
  }
}

// ------------- R5-proven 128x128 pipelined bf16 MFMA GEMM -------------------
template<int ACT, int MODE, int CB>
__global__ __launch_bounds__(256, 2) void gemm128(const ushort_t* __restrict__ A,
                                                  const ushort_t* __restrict__ BT,
                                                  const float* __restrict__ bias,
                                                  void* __restrict__ out0,
                                                  void* __restrict__ out1,
                                                  int M, int Nn, int K){
  __shared__ __align__(16) ushort_t lds[2][2][128*64];   // 64 KiB
  const int t = threadIdx.x, wid = t >> 6, lane = t & 63;

  const int bid = blockIdx.x, nwg = gridDim.x;
  const int q = nwg >> 3, r = nwg & 7;
  const int xcd = bid & 7, slot = bid >> 3;
  const int lg = (xcd < r ? xcd*(q+1) : r*(q+1) + (xcd - r)*q) + slot;
  const int brow = (lg / CB) * 128, bcol = (lg % CB) * 128;

  const int l8  = t >> 3;
  const int cb  = (t & 7) << 4;
  const int scb = cb ^ ((l8 & 7) << 4);
  const ushort_t* pAr[4]; const ushort_t* pBr[4];
  #pragma unroll
  for (int rd = 0; rd < 4; ++rd){
    int ra = brow + rd*32 + l8; ra = ra < M ? ra : M-1;
    int rb = bcol + rd*32 + l8; rb = rb < Nn ? rb : Nn-1;
    pAr[rd] = A  + (size_t)ra*K + (scb >> 1);
    pBr[rd] = BT + (size_t)rb*K + (scb >> 1);
  }
  const int w8 = wid * 8;

#define STAGE1(buf, kt) do {                                           \
    const int _o = (kt) * 64;                                          \
    _Pragma("unroll")                                                  \
    for (int _rd = 0; _rd < 4; ++_rd){                                 \
      async16(pAr[_rd] + _o, &lds[buf][0][(_rd*32 + w8)*64]);          \
      async16(pBr[_rd] + _o, &lds[buf][1][(_rd*32 + w8)*64]);          \
    }                                                                  \
  } while(0)

  f32x4 acc[4][4];
  #pragma unroll
  for (int i=0;i<4;i++)
    #pragma unroll
    for (int j=0;j<4;j++) acc[i][j] = (f32x4){0.f,0.f,0.f,0.f};

  const int wr = (wid >> 1)*64, wc = (wid & 1)*64;
  const int fr = lane & 15;
  const int kb0 = (lane >> 4) << 4;
  const int sx  = (fr & 7) << 4;
  const int ko0 = ((kb0      ) ^ sx) >> 1;
  const int ko1 = ((kb0 | 64 ) ^ sx) >> 1;

  const int nk = K >> 6;
  STAGE1(0, 0);
  STAGE1(1, 1);
  for (int kt = 0; kt < nk; ++kt){
    const ushort_t* bA = lds[kt & 1][0];
    const ushort_t* bB = lds[kt & 1][1];
    if (kt + 1 < nk) asm volatile("s_waitcnt vmcnt(8)" ::: "memory");
    else             asm volatile("s_waitcnt vmcnt(0)" ::: "memory");
    __builtin_amdgcn_s_barrier();
    short8 af[4][2], bf_[4][2];
    #pragma unroll
    for (int m=0;m<4;m++){
      const int ra = (wr + m*16 + fr)*64;
      const int rb = (wc + m*16 + fr)*64;
      af[m][0]  = *(const short8*)&bA[ra + ko0];
      af[m][1]  = *(const short8*)&bA[ra + ko1];
      bf_[m][0] = *(const short8*)&bB[rb + ko0];
      bf_[m][1] = *(const short8*)&bB[rb + ko1];
    }
    asm volatile("s_waitcnt lgkmcnt(0)" ::: "memory");
    __builtin_amdgcn_sched_barrier(0);
    __builtin_amdgcn_s_barrier();
    if (kt + 2 < nk) STAGE1(kt & 1, kt + 2);
    __builtin_amdgcn_s_setprio(1);
    #pragma unroll
    for (int m=0;m<4;m++)
      #pragma unroll
      for (int n=0;n<4;n++){
        acc[m][n] = __builtin_amdgcn_mfma_f32_16x16x32_bf16(af[m][0], bf_[n][0], acc[m][n], 0, 0, 0);
        acc[m][n] = __builtin_amdgcn_mfma_f32_16x16x32_bf16(af[m][1], bf_[n][1], acc[m][n], 0, 0, 0);
      }
    __builtin_amdgcn_s_setprio(0);
  }
#undef STAGE1

  bool isf32;
  float* outF = nullptr; ushort_t* outB = nullptr; int ostride = 0, ocb = 0;
  if (MODE == 0){ isf32 = true;  outF = (float*)out0;    ostride = Nn; ocb = bcol; }
  else if (MODE == 1){ isf32 = false; outB = (ushort_t*)out0; ostride = Nn; ocb = bcol; }
  else {
    if (bcol < SPLITC){ isf32 = true;  outF = (float*)out0;    ostride = SPLITC;      ocb = bcol; }
    else              { isf32 = false; outB = (ushort_t*)out1; ostride = Nn - SPLITC; ocb = bcol - SPLITC; }
  }
  float bv[4];
  #pragma unroll
  for (int n=0;n<4;n++){
    const int col = wc + n*16 + (lane & 15);
    float b = 0.f;
    if (MODE == 2){ if (isf32 && bias) b = bias[bcol + col]; }
    else if (bias) b = bias[bcol + col];
    bv[n] = b;
  }
  float* sF = (float*)&lds[0][0][0];
  ushort_t* sB = (ushort_t*)&lds[0][0][0];
  const int trow = t >> 3, tc16 = (t & 7) * 16;
  #pragma unroll
  for (int c = 0; c < 4; ++c){
    __syncthreads();
    if ((wid >> 1) == (c >> 1)){
      #pragma unroll
      for (int mm = 0; mm < 2; ++mm){
        const int m = 2*(c & 1) + mm;
        const int rbase = m*16 + (lane >> 4)*4 - (c & 1)*32;
        #pragma unroll
        for (int n = 0; n < 4; ++n){
          const int col = wc + n*16 + (lane & 15);
          #pragma unroll
          for (int j = 0; j < 4; ++j){
            float v = acc[m][n][j] + bv[n];
            if (ACT) v = v > 0.f ? v : 0.f;
            if (isf32) sF[(rbase + j)*128 + col] = v;
            else       sB[(rbase + j)*128 + col] = f2bf(v);
          }
        }
      }
    }
    __syncthreads();
    const int grow = brow + c*32 + trow;
    if (grow < M){
      if (isf32){
        float* dst = outF + (size_t)grow*ostride + ocb + tc16;
        const float* src = sF + trow*128 + tc16;
        #pragma unroll
        for (int q2 = 0; q2 < 4; ++q2) ((f32x4*)dst)[q2] = ((const f32x4*)src)[q2];
      } else {
        ushort_t* dst = outB + (size_t)grow*ostride + ocb + tc16;
        const ushort_t* src = sB + trow*128 + tc16;
        #pragma unroll
        for (int q2 = 0; q2 < 2; ++q2) ((short8*)dst)[q2] = ((const short8*)src)[q2];
      }
    }
  }
}

// ------------- R6-proven 256x256 pipelined bf16 MFMA GEMM -------------------
template<int ACT, int MODE, int CB>
__global__ __launch_bounds__(512, 2) void gemm256(const ushort_t* __restrict__ A,
                                                  const ushort_t* __restrict__ BT,
                                                  const float* __restrict__ bias,
                                                  void* __restrict__ out0,
                                                  void* __restrict__ out1,
                                                  int M, int Nn, int K){
  __shared__ __align__(16) ushort_t lds[2][2][256*64];   // 128 KiB
  const int t = threadIdx.x, wid = t >> 6, lane = t & 63;

  const int bid = blockIdx.x, nwg = gridDim.x;
  const int q = nwg >> 3, r = nwg & 7;
  const int xcd = bid & 7, slot = bid >> 3;
  const int lg = (xcd < r ? xcd*(q+1) : r*(q+1) + (xcd - r)*q) + slot;
  const int brow = (lg / CB) * 256, bcol = (lg % CB) * 256;

  const int l8  = t >> 3;
  const int cb  = (t & 7) << 4;
  const unsigned scb = (unsigned)(cb ^ ((l8 & 7) << 4));
  unsigned rowA[4], rowB[4];
  #pragma unroll
  for (int rd = 0; rd < 4; ++rd){
    int ra = brow + rd*64 + l8; ra = ra < M ? ra : M-1;
    int rb = bcol + rd*64 + l8; rb = rb < Nn ? rb : Nn-1;
    rowA[rd] = (unsigned)ra * (unsigned)(K*2);
    rowB[rd] = (unsigned)rb * (unsigned)(K*2);
  }
  const int wst = (wid * 8) * 64;

#define STAGE2(buf, kt) do {                                              \
    const unsigned _ob = (unsigned)(kt)*128u + scb;                       \
    _Pragma("unroll")                                                     \
    for (int _rd = 0; _rd < 4; ++_rd){                                    \
      async16((const char*)A  + rowA[_rd] + _ob, &lds[buf][0][_rd*64*64 + wst]); \
      async16((const char*)BT + rowB[_rd] + _ob, &lds[buf][1][_rd*64*64 + wst]); \
    }                                                                     \
  } while(0)

  f32x4 acc[8][4];
  #pragma unroll
  for (int i=0;i<8;i++)
    #pragma unroll
    for (int j=0;j<4;j++) acc[i][j] = (f32x4){0.f,0.f,0.f,0.f};

  const int wrow = (wid >> 2), wcol = (wid & 3);
  const int fr = lane & 15;
  const int kb0 = (lane >> 4) << 4;
  const int sx  = (fr & 7) << 4;
  const int ko0 = ((kb0      ) ^ sx) >> 1;
  const int ko1 = ((kb0 | 64 ) ^ sx) >> 1;

  const int nk = K >> 6;
  STAGE2(0, 0);
  STAGE2(1, 1);
  for (int kt = 0; kt < nk; ++kt){
    const ushort_t* bA = lds[kt & 1][0];
    const ushort_t* bB = lds[kt & 1][1];
    if (kt + 1 < nk) asm volatile("s_waitcnt vmcnt(8)" ::: "memory");
    else             asm volatile("s_waitcnt vmcnt(0)" ::: "memory");
    __builtin_amdgcn_s_barrier();
    short8 af[8][2], bf_[4][2];
    #pragma unroll
    for (int m=0;m<8;m++){
      const int ra = (wrow*128 + m*16 + fr)*64;
      af[m][0] = *(const short8*)&bA[ra + ko0];
      af[m][1] = *(const short8*)&bA[ra + ko1];
    }
    #pragma unroll
    for (int n=0;n<4;n++){
      const int rb = (wcol*64 + n*16 + fr)*64;
      bf_[n][0] = *(const short8*)&bB[rb + ko0];
      bf_[n][1] = *(const short8*)&bB[rb + ko1];
    }
    asm volatile("s_waitcnt lgkmcnt(0)" ::: "memory");
    __builtin_amdgcn_sched_barrier(0);
    __builtin_amdgcn_s_barrier();
    if (kt + 2 < nk) STAGE2(kt & 1, kt + 2);
    __builtin_amdgcn_s_setprio(1);
    #pragma unroll
    for (int m=0;m<8;m++)
      #pragma unroll
      for (int n=0;n<4;n++){
        acc[m][n] = __builtin_amdgcn_mfma_f32_16x16x32_bf16(af[m][0], bf_[n][0], acc[m][n], 0, 0, 0);
        acc[m][n] = __builtin_amdgcn_mfma_f32_16x16x32_bf16(af[m][1], bf_[n][1], acc[m][n], 0, 0, 0);
      }
    __builtin_amdgcn_s_setprio(0);
  }
#undef STAGE2

  const bool isf32 = (MODE == 0) || (MODE == 2 && bcol == 0);
  float bv[4];
  #pragma unroll
  for (int n=0;n<4;n++){
    const int col = bcol + wcol*64 + n*16 + (lane & 15);
    float b = 0.f;
    if (MODE == 1){ if (bias) b = bias[col]; }
    if (MODE == 2){ if (isf32) b = bias[col]; }
    bv[n] = b;
  }

  if (isf32){
    float* outF; int ostride, ocb;
    if (MODE == 0){ outF = (float*)out0; ostride = Nn;  ocb = bcol; }
    else          { outF = (float*)out0; ostride = 256; ocb = 0;    }
    float* sF = (float*)&lds[0][0][0];
    #pragma unroll
    for (int p = 0; p < 2; ++p){
      __syncthreads();
      if (wrow == p){
        #pragma unroll
        for (int m=0;m<8;m++){
          const int row = m*16 + (lane >> 4)*4;
          #pragma unroll
          for (int n=0;n<4;n++){
            const int col = wcol*64 + n*16 + (lane & 15);
            #pragma unroll
            for (int j=0;j<4;j++){
              float v = acc[m][n][j] + bv[n];
              if (ACT) v = v > 0.f ? v : 0.f;
              sF[(row+j)*256 + col] = v;
            }
          }
        }
      }
      __syncthreads();
      const int srow = t >> 6, scol4 = (t & 63) * 4;
      #pragma unroll
      for (int rr = 0; rr < 16; ++rr){
        const int rloc = rr*8 + srow;
        const int grow = brow + p*128 + rloc;
        if (grow < M)
          *(f32x4*)(outF + (size_t)grow*ostride + ocb + scol4) = *(const f32x4*)&sF[rloc*256 + scol4];
      }
    }
  } else {
    ushort_t* outB; int ostride, ocb;
    if (MODE == 1){ outB = (ushort_t*)out0; ostride = Nn;  ocb = bcol; }
    else          { outB = (ushort_t*)out1; ostride = 256; ocb = 0;    }
    ushort_t* sB = (ushort_t*)&lds[0][0][0];
    __syncthreads();
    #pragma unroll
    for (int m=0;m<8;m++){
      const int row = wrow*128 + m*16 + (lane >> 4)*4;
      #pragma unroll
      for (int n=0;n<4;n++){
        const int col = wcol*64 + n*16 + (lane & 15);
        #pragma unroll
        for (int j=0;j<4;j++){
          float v = acc[m][n][j] + bv[n];
          if (ACT) v = v > 0.f ? v : 0.f;
          sB[(row+j)*256 + col] = f2bf(v);
        }
      }
    }
    __syncthreads();
    const int srow = t >> 5, scol8 = (t & 31) * 8;
    #pragma unroll
    for (int rr = 0; rr < 16; ++rr){
      const int rloc = rr*16 + srow;
      const int grow = brow + rloc;
      if (grow < M)
        *(short8*)(outB + (size_t)grow*ostride + ocb + scol8) = *(const short8*)&sB[rloc*256 + scol8];
    }
  }
}

// ---------------- attention scores a_src/a_dst: [N,8] = sum_c g*att --------
__global__ __launch_bounds__(256) void att_scores(const ushort_t* __restrict__ gm,
                                                  const float* __restrict__ att_s,
                                                  const float* __restrict__ att_d,
                                                  float* __restrict__ asrc,
                                                  float* __restrict__ adst){
  __shared__ float ss[256], sd[256];
  const int t = threadIdx.x;
  ss[t] = att_s[t]; sd[t] = att_d[t];
  __syncthreads();
  const int idx = blockIdx.x*256 + t;
  if (idx >= NND*NHD) return;
  const int n = idx >> 3, h = idx & 7;
  const ushort_t* gr = gm + (size_t)n*DHC + h*32;
  float a = 0.f, d = 0.f;
  #pragma unroll
  for (int c0 = 0; c0 < 32; c0 += 8){
    short8 gv = *(const short8*)(gr + c0);
    #pragma unroll
    for (int j = 0; j < 8; ++j){
      float g = bf2f((ushort_t)gv[j]);
      a += g*ss[h*32+c0+j]; d += g*sd[h*32+c0+j];
    }
  }
  asrc[idx] = a; adst[idx] = d;
}

// ---------------- CSR build ----------------
__global__ void count_edges(const int* __restrict__ ei, int* cnt){
  int e = blockIdx.x*256 + threadIdx.x;
  if (e < NE) atomicAdd(&cnt[ei[NE + e]], 1);
}
__global__ __launch_bounds__(1024) void scan_kernel(const int* __restrict__ cnt,
                                                    int* __restrict__ offs,
                                                    int* __restrict__ cur){
  __shared__ int buf[1024];
  const int t = threadIdx.x;
  const int chunk = (NND + 1023) >> 10;
  const int s0 = t*chunk, s1 = (s0 + chunk < NND) ? s0 + chunk : NND;
  int s = 0;
  for (int i = s0; i < s1; ++i) s += cnt[i] + 1;      // +1 self-loop
  buf[t] = s; __syncthreads();
  for (int o = 1; o < 1024; o <<= 1){
    int x = (t >= o) ? buf[t-o] : 0;
    __syncthreads();
    buf[t] += x;
    __syncthreads();
  }
  int run = buf[t] - s;
  for (int i = s0; i < s1; ++i){
    int c = cnt[i] + 1;
    cur[i] = run;
    run += c;
    offs[i+1] = run;
  }
  if (t == 0) offs[0] = 0;
}
__global__ void fill_both(const int* __restrict__ ei, int* cur, int* eidx){
  int i = blockIdx.x*256 + threadIdx.x;
  if (i < NND){
    int p = atomicAdd(&cur[i], 1); eidx[p] = i;        // self-loop
  } else if (i < NND + NE){
    int e = i - NND;
    int src = ei[e], dst = ei[NE + e];
    int p = atomicAdd(&cur[dst], 1);
    eidx[p] = src;
  }
}

// ---- fused GAT aggregate + elu + residual (wave/node, 8-edge chunks) ------
__global__ __launch_bounds__(256) void gat_agg(const int* __restrict__ offs,
                                               const int* __restrict__ eidx,
                                               const float* __restrict__ asrc,
                                               const float* __restrict__ adst,
                                               const ushort_t* __restrict__ gm,
                                               const float* __restrict__ res,
                                               const float* __restrict__ bg,
                                               float* __restrict__ out){
  const int wid = threadIdx.x >> 6, lane = threadIdx.x & 63;
  const int node = blockIdx.x*4 + wid;
  if (node >= NND) return;
  const int h = lane >> 3, jj = lane & 7;
  const int e0 = offs[node], deg = offs[node+1] - e0;
  const float adv = adst[node*NHD + h];

  // pass A: per-head max (8 lanes per head, strided edges)
  float mx = -1e30f;
  for (int j = jj; j < deg; j += 8){
    int s = eidx[e0 + j];
    float e = asrc[s*NHD + h] + adv; e = e > 0.f ? e : 0.2f*e;
    mx = fmaxf(mx, e);
  }
  mx = fmaxf(mx, __shfl_xor(mx, 1));
  mx = fmaxf(mx, __shfl_xor(mx, 2));
  mx = fmaxf(mx, __shfl_xor(mx, 4));

  // pass B: fused sum + gather in 8-edge chunks (normalize at the end)
  const int c4 = lane*4;                 // channels [c4,c4+4), head c4>>5 == h
  float sm = 0.f;
  f32x4 acc = {0.f,0.f,0.f,0.f};
  for (int j0 = 0; j0 < deg; j0 += 8){
    const int cnt = (deg - j0) < 8 ? (deg - j0) : 8;
    int s = 0; float w = 0.f;
    if (jj < cnt){
      s = eidx[e0 + j0 + jj];
      float e = asrc[s*NHD + h] + adv; e = e > 0.f ? e : 0.2f*e;
      w = __expf(e - mx);
      sm += w;
    }
    #pragma unroll
    for (int u = 0; u < 8; ++u){
      if (u < cnt){
        const int   su = __builtin_amdgcn_readlane(s, u);   // edge u's src (SGPR)
        const float wu = __shfl(w, (h << 3) | u);            // weight for (h, u)
        short4v gv = *(const short4v*)(gm + (size_t)su*DHC + c4);
        acc.x += wu*bf2f((ushort_t)gv.x);
        acc.y += wu*bf2f((ushort_t)gv.y);
        acc.z += wu*bf2f((ushort_t)gv.z);
        acc.w += wu*bf2f((ushort_t)gv.w);
      }
    }
  }
  sm += __shfl_xor(sm, 1); sm += __shfl_xor(sm, 2); sm += __shfl_xor(sm, 4);
  const float inv = 1.f/(sm + 1e-16f);

  f32x4 bgv = *(const f32x4*)(bg + c4);
  f32x4 rv  = *(const f32x4*)(res + (size_t)node*DHC + c4);
  f32x4 o;
  #pragma unroll
  for (int q = 0; q < 4; ++q){
    float v = acc[q]*inv + bgv[q];
    v = v > 0.f ? v : expm1f(v);
    o[q] = v + rv[q];
  }
  *(f32x4*)(out + (size_t)node*DHC + c4) = o;
}

extern "C" void kernel_launch(void* const* d_in, const int* in_sizes, int n_in,
                              void* d_out, int out_size, void* d_ws, size_t ws_size,
                              hipStream_t stream){
  (void)in_sizes; (void)n_in; (void)out_size; (void)ws_size;
  const float* x     = (const float*)d_in[0];
  const int*   ei    = (const int*)d_in[1];
  const float* ln_g  = (const float*)d_in[2];
  const float* ln_b  = (const float*)d_in[3];
  const float* W1    = (const float*)d_in[4];
  const float* b1    = (const float*)d_in[5];
  const float* W2    = (const float*)d_in[6];
  const float* b2    = (const float*)d_in[7];
  const float* Wr    = (const float*)d_in[8];
  const float* br    = (const float*)d_in[9];
  const float* Wg    = (const float*)d_in[10];
  const float* att_s = (const float*)d_in[11];
  const float* att_d = (const float*)d_in[12];
  const float* bg    = (const float*)d_in[13];
  float* out = (float*)d_out;

  char* p = (char*)d_ws;
  ushort_t* xn   = (ushort_t*)(p);                   // [0, 153,600,000)
  ushort_t* h1   = (ushort_t*)(p + 153600000);       // 102,400,000 -> 256,000,000
  ushort_t* W1T  = (ushort_t*)d_out;                           // 3,145,728
  ushort_t* W2T  = (ushort_t*)((char*)d_out + 3145728);        // 1,048,576
  ushort_t* WrgT = (ushort_t*)((char*)d_out + 4194304);        //   524,288
  ushort_t* hb   = (ushort_t*)(p + 0);               //  51,200,000 (bf16)
  float*    res  = (float*)(p + 51200000);           //  51,200,000 (f32)
  ushort_t* gm   = (ushort_t*)(p + 102400000);       //  25,600,000 (bf16)
  float*    asrc = (float*)(p + 128000000);          //   1,600,000
  float*    adst = (float*)(p + 129600000);          //   1,600,000
  int*      cnt  = (int*)(p + 131200000);            //     200,000
  int*      offs = (int*)(p + 131400064);            //     200,004
  int*      cur  = (int*)(p + 131600128);            //     200,000
  int*      eidx = (int*)(p + 131800192);            //   3,400,000

  transpose_cast<<<dim3(48,32), 256, 0, stream>>>(W1, W1T, DIN,  DHID, DINP);
  transpose_cast<<<dim3(32,16), 256, 0, stream>>>(W2, W2T, DHID, DOUT, DHID);
  transpose_cast<<<dim3(16, 8), 256, 0, stream>>>(Wr, WrgT,            DOUT, DHC, DOUT);
  transpose_cast<<<dim3(16, 8), 256, 0, stream>>>(Wg, WrgT + 256*DOUT, DOUT, DHC, DOUT);

  ln_kernel<<<(NND + 3)/4, 256, 0, stream>>>(x, ln_g, ln_b, xn);

  const int RB128 = (NND + 127) / 128;   // 391
  const int RB256 = (NND + 255) / 256;   // 196
  gemm128<1,1,8><<<RB128*8, 256, 0, stream>>>(xn, W1T, b1, h1, nullptr, NND, DHID, DINP);
  gemm256<0,1,2><<<RB256*2, 512, 0, stream>>>(h1, W2T, b2, hb, nullptr, NND, DOUT, DHID);
  gemm256<0,2,2><<<RB256*2, 512, 0, stream>>>(hb, WrgT, br, res, gm, NND, 2*DHC, DOUT);

  att_scores<<<(NND*NHD + 255)/256, 256, 0, stream>>>(gm, att_s, att_d, asrc, adst);

  hipMemsetAsync(cnt, 0, NND*sizeof(int), stream);
  count_edges<<<(NE + 255)/256, 256, 0, stream>>>(ei, cnt);
  scan_kernel<<<1, 1024, 0, stream>>>(cnt, offs, cur);
  fill_both<<<(NND + NE + 255)/256, 256, 0, stream>>>(ei, cur, eidx);

  gat_agg<<<(NND + 3)/4, 256, 0, stream>>>(offs, eidx, asrc, adst, gm, res, bg, out);
}

// Round 10
// 682.941 us; speedup vs baseline: 1.1357x; 1.0428x over previous
//
#include <hip/hip_runtime.h>
#include <hip/hip_bf16.h>
#include <cstdint>
#include <cstddef>

#define NND 50000
#define DIN 1488
#define DINP 1536
#define DHID 1024
#define DOUT 512
#define DHC 256
#define NE 800000
#define NHD 8
#define SPLITC 256

typedef __attribute__((ext_vector_type(8))) short short8;
typedef __attribute__((ext_vector_type(4))) short short4v;
typedef __attribute__((ext_vector_type(4))) float f32x4;
typedef unsigned short ushort_t;

__device__ __forceinline__ unsigned short f2bf(float f){
  union { float f; unsigned u; } v; v.f = f;
  unsigned r = v.u + 0x7fffu + ((v.u >> 16) & 1u);
  return (unsigned short)(r >> 16);
}
__device__ __forceinline__ float bf2f(unsigned short u){
  union { unsigned u; float f; } v; v.u = ((unsigned)u) << 16;
  return v.f;
}

__device__ __forceinline__ void async16(const void* g, void* l){
  __builtin_amdgcn_global_load_lds((__attribute__((address_space(1))) void*)g,
                                   (__attribute__((address_space(3))) void*)l, 16, 0, 0);
}

// ---- prep: 4 weight transposes (fp32 [K,N] -> bf16 [N,Kp]) + cnt zeroing ---
__device__ __forceinline__ void tc_tile(const float* __restrict__ W,
                                        ushort_t* __restrict__ WT,
                                        int K, int Nn, int Kp, int bx, int by){
  __shared__ float tile[32][33];
  const int tx = threadIdx.x & 31, ty = threadIdx.x >> 5;
  const int k0 = bx*32, n0 = by*32;
  for (int i = ty; i < 32; i += 8){
    int k = k0 + i, n = n0 + tx;
    tile[i][tx] = (k < K && n < Nn) ? W[(size_t)k*Nn + n] : 0.f;
  }
  __syncthreads();
  for (int i = ty; i < 32; i += 8){
    int n = n0 + i, k = k0 + tx;
    if (n < Nn && k < Kp) WT[(size_t)n*Kp + k] = f2bf(tile[tx][i]);
  }
}
__global__ __launch_bounds__(256) void prep_kernel(const float* W1, const float* W2,
                                                   const float* Wr, const float* Wg,
                                                   ushort_t* W1T, ushort_t* W2T,
                                                   ushort_t* WrgT, int* cnt){
  int b = blockIdx.x;
  if (b < 1536){ tc_tile(W1, W1T, DIN, DHID, DINP, b % 48, b / 48); return; }
  b -= 1536;
  if (b < 512){ tc_tile(W2, W2T, DHID, DOUT, DHID, b % 32, b / 32); return; }
  b -= 512;
  if (b < 128){ tc_tile(Wr, WrgT, DOUT, DHC, DOUT, b % 16, b / 16); return; }
  b -= 128;
  if (b < 128){ tc_tile(Wg, WrgT + 256*DOUT, DOUT, DHC, DOUT, b % 16, b / 16); return; }
  b -= 128;
  { int i = b*256 + threadIdx.x; if (i < NND) cnt[i] = 0; }
}

// ---- LayerNorm (wave/row) + count_edges, fused by block range --------------
#define LN_BLOCKS 12500
__global__ __launch_bounds__(256) void ln_count(const float* __restrict__ x,
                                                const float* __restrict__ gw,
                                                const float* __restrict__ bw,
                                                ushort_t* __restrict__ xn,
                                                const int* __restrict__ ei,
                                                int* __restrict__ cnt){
  const int bid = blockIdx.x;
  if (bid >= LN_BLOCKS){
    int e = (bid - LN_BLOCKS)*256 + threadIdx.x;
    if (e < NE) atomicAdd(&cnt[ei[NE + e]], 1);
    return;
  }
  const int wid = threadIdx.x >> 6, lane = threadIdx.x & 63;
  const int row = bid*4 + wid;
  if (row >= NND) return;
  const float* xr = x + (size_t)row * DIN;
  float s = 0.f, sq = 0.f;
  for (int i = lane*4; i < DIN; i += 256){
    f32x4 v = *(const f32x4*)(xr + i);
    s  += v.x + v.y + v.z + v.w;
    sq += v.x*v.x + v.y*v.y + v.z*v.z + v.w*v.w;
  }
  #pragma unroll
  for (int o = 32; o; o >>= 1){ s += __shfl_xor(s, o); sq += __shfl_xor(sq, o); }
  const float mu = s * (1.f/DIN);
  const float var = sq * (1.f/DIN) - mu*mu;
  const float rstd = rsqrtf(var + 1e-5f);
  ushort_t* xo = xn + (size_t)row * DINP;
  for (int i = lane*4; i < DIN; i += 256){
    f32x4 v = *(const f32x4*)(xr + i);
    f32x4 gg = *(const f32x4*)(gw + i);
    f32x4 bb = *(const f32x4*)(bw + i);
    union { ushort_t u[4]; unsigned long long q; } o;
    o.u[0] = f2bf((v.x-mu)*rstd*gg.x + bb.x);
    o.u[1] = f2bf((v.y-mu)*rstd*gg.y + bb.y);
    o.u[2] = f2bf((v.z-mu)*rstd*gg.z + bb.z);
    o.u[3] = f2bf((v.w-mu)*rstd*gg.w + bb.w);
    *(unsigned long long*)(xo + i) = o.q;
  }
  if (lane < (DINP - DIN)) xo[DIN + lane] = 0;
}

// ------------- 128x128 pipelined bf16 MFMA GEMM + optional scan block -------
#define G1_NWG 3128
template<int ACT, int MODE, int CB>
__global__ __launch_bounds__(256, 2) void gemm128(const ushort_t* __restrict__ A,
                                                  const ushort_t* __restrict__ BT,
                                                  const float* __restrict__ bias,
                                                  void* __restrict__ out0,
                                                  void* __restrict__ out1,
                                                  int M, int Nn, int K,
                                                  const int* __restrict__ cnt,
                                                  int* __restrict__ offs,
                                                  int* __restrict__ cur){
  __shared__ __align__(16) ushort_t lds[2][2][128*64];   // 64 KiB
  const int t = threadIdx.x, wid = t >> 6, lane = t & 63;

  if (blockIdx.x >= G1_NWG){
    // ---- scan block: exclusive prefix over (cnt[i]+1), 256 threads ----
    int* buf = (int*)&lds[0][0][0];
    const int chunk = (NND + 255) >> 8;
    const int s0 = t*chunk, s1 = (s0 + chunk < NND) ? s0 + chunk : NND;
    int s = 0;
    for (int i = s0; i < s1; ++i) s += cnt[i] + 1;
    buf[t] = s; __syncthreads();
    for (int o = 1; o < 256; o <<= 1){
      int xv = (t >= o) ? buf[t-o] : 0;
      __syncthreads();
      buf[t] += xv;
      __syncthreads();
    }
    int run = buf[t] - s;
    for (int i = s0; i < s1; ++i){
      int c = cnt[i] + 1;
      cur[i] = run;
      run += c;
      offs[i+1] = run;
    }
    if (t == 0) offs[0] = 0;
    return;
  }

  const int bid = blockIdx.x, nwg = G1_NWG;
  const int q = nwg >> 3, r = nwg & 7;
  const int xcd = bid & 7, slot = bid >> 3;
  const int lg = (xcd < r ? xcd*(q+1) : r*(q+1) + (xcd - r)*q) + slot;
  const int brow = (lg / CB) * 128, bcol = (lg % CB) * 128;

  const int l8  = t >> 3;
  const int cb  = (t & 7) << 4;
  const int scb = cb ^ ((l8 & 7) << 4);
  const ushort_t* pAr[4]; const ushort_t* pBr[4];
  #pragma unroll
  for (int rd = 0; rd < 4; ++rd){
    int ra = brow + rd*32 + l8; ra = ra < M ? ra : M-1;
    int rb = bcol + rd*32 + l8; rb = rb < Nn ? rb : Nn-1;
    pAr[rd] = A  + (size_t)ra*K + (scb >> 1);
    pBr[rd] = BT + (size_t)rb*K + (scb >> 1);
  }
  const int w8 = wid * 8;

#define STAGE1(buf, kt) do {                                           \
    const int _o = (kt) * 64;                                          \
    _Pragma("unroll")                                                  \
    for (int _rd = 0; _rd < 4; ++_rd){                                 \
      async16(pAr[_rd] + _o, &lds[buf][0][(_rd*32 + w8)*64]);          \
      async16(pBr[_rd] + _o, &lds[buf][1][(_rd*32 + w8)*64]);          \
    }                                                                  \
  } while(0)

  f32x4 acc[4][4];
  #pragma unroll
  for (int i=0;i<4;i++)
    #pragma unroll
    for (int j=0;j<4;j++) acc[i][j] = (f32x4){0.f,0.f,0.f,0.f};

  const int wr = (wid >> 1)*64, wc = (wid & 1)*64;
  const int fr = lane & 15;
  const int kb0 = (lane >> 4) << 4;
  const int sx  = (fr & 7) << 4;
  const int ko0 = ((kb0      ) ^ sx) >> 1;
  const int ko1 = ((kb0 | 64 ) ^ sx) >> 1;

  const int nk = K >> 6;
  STAGE1(0, 0);
  STAGE1(1, 1);
  for (int kt = 0; kt < nk; ++kt){
    const ushort_t* bA = lds[kt & 1][0];
    const ushort_t* bB = lds[kt & 1][1];
    if (kt + 1 < nk) asm volatile("s_waitcnt vmcnt(8)" ::: "memory");
    else             asm volatile("s_waitcnt vmcnt(0)" ::: "memory");
    __builtin_amdgcn_s_barrier();
    short8 af[4][2], bf_[4][2];
    #pragma unroll
    for (int m=0;m<4;m++){
      const int ra = (wr + m*16 + fr)*64;
      const int rb = (wc + m*16 + fr)*64;
      af[m][0]  = *(const short8*)&bA[ra + ko0];
      af[m][1]  = *(const short8*)&bA[ra + ko1];
      bf_[m][0] = *(const short8*)&bB[rb + ko0];
      bf_[m][1] = *(const short8*)&bB[rb + ko1];
    }
    asm volatile("s_waitcnt lgkmcnt(0)" ::: "memory");
    __builtin_amdgcn_sched_barrier(0);
    __builtin_amdgcn_s_barrier();
    if (kt + 2 < nk) STAGE1(kt & 1, kt + 2);
    __builtin_amdgcn_s_setprio(1);
    #pragma unroll
    for (int m=0;m<4;m++)
      #pragma unroll
      for (int n=0;n<4;n++){
        acc[m][n] = __builtin_amdgcn_mfma_f32_16x16x32_bf16(af[m][0], bf_[n][0], acc[m][n], 0, 0, 0);
        acc[m][n] = __builtin_amdgcn_mfma_f32_16x16x32_bf16(af[m][1], bf_[n][1], acc[m][n], 0, 0, 0);
      }
    __builtin_amdgcn_s_setprio(0);
  }
#undef STAGE1

  bool isf32;
  float* outF = nullptr; ushort_t* outB = nullptr; int ostride = 0, ocb = 0;
  if (MODE == 0){ isf32 = true;  outF = (float*)out0;    ostride = Nn; ocb = bcol; }
  else if (MODE == 1){ isf32 = false; outB = (ushort_t*)out0; ostride = Nn; ocb = bcol; }
  else {
    if (bcol < SPLITC){ isf32 = true;  outF = (float*)out0;    ostride = SPLITC;      ocb = bcol; }
    else              { isf32 = false; outB = (ushort_t*)out1; ostride = Nn - SPLITC; ocb = bcol - SPLITC; }
  }
  float bv[4];
  #pragma unroll
  for (int n=0;n<4;n++){
    const int col = wc + n*16 + (lane & 15);
    float b = 0.f;
    if (MODE == 2){ if (isf32 && bias) b = bias[bcol + col]; }
    else if (bias) b = bias[bcol + col];
    bv[n] = b;
  }
  float* sF = (float*)&lds[0][0][0];
  ushort_t* sB = (ushort_t*)&lds[0][0][0];
  const int trow = t >> 3, tc16 = (t & 7) * 16;
  #pragma unroll
  for (int c = 0; c < 4; ++c){
    __syncthreads();
    if ((wid >> 1) == (c >> 1)){
      #pragma unroll
      for (int mm = 0; mm < 2; ++mm){
        const int m = 2*(c & 1) + mm;
        const int rbase = m*16 + (lane >> 4)*4 - (c & 1)*32;
        #pragma unroll
        for (int n = 0; n < 4; ++n){
          const int col = wc + n*16 + (lane & 15);
          #pragma unroll
          for (int j = 0; j < 4; ++j){
            float v = acc[m][n][j] + bv[n];
            if (ACT) v = v > 0.f ? v : 0.f;
            if (isf32) sF[(rbase + j)*128 + col] = v;
            else       sB[(rbase + j)*128 + col] = f2bf(v);
          }
        }
      }
    }
    __syncthreads();
    const int grow = brow + c*32 + trow;
    if (grow < M){
      if (isf32){
        float* dst = outF + (size_t)grow*ostride + ocb + tc16;
        const float* src = sF + trow*128 + tc16;
        #pragma unroll
        for (int q2 = 0; q2 < 4; ++q2) ((f32x4*)dst)[q2] = ((const f32x4*)src)[q2];
      } else {
        ushort_t* dst = outB + (size_t)grow*ostride + ocb + tc16;
        const ushort_t* src = sB + trow*128 + tc16;
        #pragma unroll
        for (int q2 = 0; q2 < 2; ++q2) ((short8*)dst)[q2] = ((const short8*)src)[q2];
      }
    }
  }
}

// ------------- 256x256 pipelined bf16 MFMA GEMM -----------------------------
// EXTRA==1: blocks >= NWG do CSR fill. MODE==2: fused att-scores in bf16 branch.
#define G2_NWG 392
template<int ACT, int MODE, int CB, int EXTRA>
__global__ __launch_bounds__(512, 2) void gemm256(const ushort_t* __restrict__ A,
                                                  const ushort_t* __restrict__ BT,
                                                  const float* __restrict__ bias,
                                                  void* __restrict__ out0,
                                                  void* __restrict__ out1,
                                                  int M, int Nn, int K,
                                                  const int* __restrict__ ei,
                                                  int* __restrict__ cur,
                                                  int* __restrict__ eidx,
                                                  const float* __restrict__ att_s,
                                                  const float* __restrict__ att_d,
                                                  float* __restrict__ asrc,
                                                  float* __restrict__ adst){
  __shared__ __align__(16) ushort_t lds[2][2][256*64];   // 128 KiB
  const int t = threadIdx.x, wid = t >> 6, lane = t & 63;

  if (EXTRA == 1 && blockIdx.x >= G2_NWG){
    // ---- CSR fill (self-loops + edges), 512 threads/block ----
    int i = (blockIdx.x - G2_NWG)*512 + t;
    if (i < NND){
      int p = atomicAdd(&cur[i], 1); eidx[p] = i;
    } else if (i < NND + NE){
      int e = i - NND;
      int src = ei[e], dst = ei[NE + e];
      int p = atomicAdd(&cur[dst], 1);
      eidx[p] = src;
    }
    return;
  }

  const int bid = blockIdx.x, nwg = G2_NWG;
  const int q = nwg >> 3, r = nwg & 7;
  const int xcd = bid & 7, slot = bid >> 3;
  const int lg = (xcd < r ? xcd*(q+1) : r*(q+1) + (xcd - r)*q) + slot;
  const int brow = (lg / CB) * 256, bcol = (lg % CB) * 256;

  const int l8  = t >> 3;
  const int cb  = (t & 7) << 4;
  const unsigned scb = (unsigned)(cb ^ ((l8 & 7) << 4));
  unsigned rowA[4], rowB[4];
  #pragma unroll
  for (int rd = 0; rd < 4; ++rd){
    int ra = brow + rd*64 + l8; ra = ra < M ? ra : M-1;
    int rb = bcol + rd*64 + l8; rb = rb < Nn ? rb : Nn-1;
    rowA[rd] = (unsigned)ra * (unsigned)(K*2);
    rowB[rd] = (unsigned)rb * (unsigned)(K*2);
  }
  const int wst = (wid * 8) * 64;

#define STAGE2(buf, kt) do {                                              \
    const unsigned _ob = (unsigned)(kt)*128u + scb;                       \
    _Pragma("unroll")                                                     \
    for (int _rd = 0; _rd < 4; ++_rd){                                    \
      async16((const char*)A  + rowA[_rd] + _ob, &lds[buf][0][_rd*64*64 + wst]); \
      async16((const char*)BT + rowB[_rd] + _ob, &lds[buf][1][_rd*64*64 + wst]); \
    }                                                                     \
  } while(0)

  f32x4 acc[8][4];
  #pragma unroll
  for (int i=0;i<8;i++)
    #pragma unroll
    for (int j=0;j<4;j++) acc[i][j] = (f32x4){0.f,0.f,0.f,0.f};

  const int wrow = (wid >> 2), wcol = (wid & 3);
  const int fr = lane & 15;
  const int kb0 = (lane >> 4) << 4;
  const int sx  = (fr & 7) << 4;
  const int ko0 = ((kb0      ) ^ sx) >> 1;
  const int ko1 = ((kb0 | 64 ) ^ sx) >> 1;

  const int nk = K >> 6;
  STAGE2(0, 0);
  STAGE2(1, 1);
  for (int kt = 0; kt < nk; ++kt){
    const ushort_t* bA = lds[kt & 1][0];
    const ushort_t* bB = lds[kt & 1][1];
    if (kt + 1 < nk) asm volatile("s_waitcnt vmcnt(8)" ::: "memory");
    else             asm volatile("s_waitcnt vmcnt(0)" ::: "memory");
    __builtin_amdgcn_s_barrier();
    short8 af[8][2], bf_[4][2];
    #pragma unroll
    for (int m=0;m<8;m++){
      const int ra = (wrow*128 + m*16 + fr)*64;
      af[m][0] = *(const short8*)&bA[ra + ko0];
      af[m][1] = *(const short8*)&bA[ra + ko1];
    }
    #pragma unroll
    for (int n=0;n<4;n++){
      const int rb = (wcol*64 + n*16 + fr)*64;
      bf_[n][0] = *(const short8*)&bB[rb + ko0];
      bf_[n][1] = *(const short8*)&bB[rb + ko1];
    }
    asm volatile("s_waitcnt lgkmcnt(0)" ::: "memory");
    __builtin_amdgcn_sched_barrier(0);
    __builtin_amdgcn_s_barrier();
    if (kt + 2 < nk) STAGE2(kt & 1, kt + 2);
    __builtin_amdgcn_s_setprio(1);
    #pragma unroll
    for (int m=0;m<8;m++)
      #pragma unroll
      for (int n=0;n<4;n++){
        acc[m][n] = __builtin_amdgcn_mfma_f32_16x16x32_bf16(af[m][0], bf_[n][0], acc[m][n], 0, 0, 0);
        acc[m][n] = __builtin_amdgcn_mfma_f32_16x16x32_bf16(af[m][1], bf_[n][1], acc[m][n], 0, 0, 0);
      }
    __builtin_amdgcn_s_setprio(0);
  }
#undef STAGE2

  const bool isf32 = (MODE == 0) || (MODE == 2 && bcol == 0);
  float bv[4];
  #pragma unroll
  for (int n=0;n<4;n++){
    const int col = bcol + wcol*64 + n*16 + (lane & 15);
    float b = 0.f;
    if (MODE == 1){ if (bias) b = bias[col]; }
    if (MODE == 2){ if (isf32) b = bias[col]; }
    bv[n] = b;
  }

  if (isf32){
    float* outF; int ostride, ocb;
    if (MODE == 0){ outF = (float*)out0; ostride = Nn;  ocb = bcol; }
    else          { outF = (float*)out0; ostride = 256; ocb = 0;    }
    float* sF = (float*)&lds[0][0][0];
    #pragma unroll
    for (int p = 0; p < 2; ++p){
      __syncthreads();
      if (wrow == p){
        #pragma unroll
        for (int m=0;m<8;m++){
          const int row = m*16 + (lane >> 4)*4;
          #pragma unroll
          for (int n=0;n<4;n++){
            const int col = wcol*64 + n*16 + (lane & 15);
            #pragma unroll
            for (int j=0;j<4;j++){
              float v = acc[m][n][j] + bv[n];
              if (ACT) v = v > 0.f ? v : 0.f;
              sF[(row+j)*256 + col] = v;
            }
          }
        }
      }
      __syncthreads();
      const int srow = t >> 6, scol4 = (t & 63) * 4;
      #pragma unroll
      for (int rr = 0; rr < 16; ++rr){
        const int rloc = rr*8 + srow;
        const int grow = brow + p*128 + rloc;
        if (grow < M)
          *(f32x4*)(outF + (size_t)grow*ostride + ocb + scol4) = *(const f32x4*)&sF[rloc*256 + scol4];
      }
    }
  } else {
    ushort_t* outB; int ostride, ocb;
    if (MODE == 1){ outB = (ushort_t*)out0; ostride = Nn;  ocb = bcol; }
    else          { outB = (ushort_t*)out1; ostride = 256; ocb = 0;    }
    ushort_t* sB = (ushort_t*)&lds[0][0][0];
    __syncthreads();
    #pragma unroll
    for (int m=0;m<8;m++){
      const int row = wrow*128 + m*16 + (lane >> 4)*4;
      #pragma unroll
      for (int n=0;n<4;n++){
        const int col = wcol*64 + n*16 + (lane & 15);
        #pragma unroll
        for (int j=0;j<4;j++){
          float v = acc[m][n][j] + bv[n];
          if (ACT) v = v > 0.f ? v : 0.f;
          sB[(row+j)*256 + col] = f2bf(v);
        }
      }
    }
    __syncthreads();
    const int srow = t >> 5, scol8 = (t & 31) * 8;
    #pragma unroll
    for (int rr = 0; rr < 16; ++rr){
      const int rloc = rr*16 + srow;
      const int grow = brow + rloc;
      if (grow < M)
        *(short8*)(outB + (size_t)grow*ostride + ocb + scol8) = *(const short8*)&sB[rloc*256 + scol8];
    }
    if (MODE == 2){
      // fused att-scores from the gm tile in LDS: rows [brow,brow+256), 8 heads
      const int h = t & 7;
      const int hc0 = h * 32;
      #pragma unroll
      for (int k = 0; k < 4; ++k){
        const int rloc = (t >> 3) + k*64;
        const int grow = brow + rloc;
        if (grow < M){
          float a = 0.f, d = 0.f;
          #pragma unroll
          for (int c0 = 0; c0 < 32; c0 += 8){
            short8 gv = *(const short8*)&sB[rloc*256 + hc0 + c0];
            #pragma unroll
            for (int j = 0; j < 8; ++j){
              float g = bf2f((ushort_t)gv[j]);
              a += g*att_s[hc0 + c0 + j];
              d += g*att_d[hc0 + c0 + j];
            }
          }
          asrc[grow*NHD + h] = a;
          adst[grow*NHD + h] = d;
        }
      }
    }
  }
}

// ---- fused GAT aggregate + elu + residual (wave/node, 8-edge chunks) ------
__global__ __launch_bounds__(256) void gat_agg(const int* __restrict__ offs,
                                               const int* __restrict__ eidx,
                                               const float* __restrict__ asrc,
                                               const float* __restrict__ adst,
                                               const ushort_t* __restrict__ gm,
                                               const float* __restrict__ res,
                                               const float* __restrict__ bg,
                                               float* __restrict__ out){
  const int wid = threadIdx.x >> 6, lane = threadIdx.x & 63;
  const int node = blockIdx.x*4 + wid;
  if (node >= NND) return;
  const int h = lane >> 3, jj = lane & 7;
  const int e0 = offs[node], deg = offs[node+1] - e0;
  const float adv = adst[node*NHD + h];

  float mx = -1e30f;
  for (int j = jj; j < deg; j += 8){
    int s = eidx[e0 + j];
    float e = asrc[s*NHD + h] + adv; e = e > 0.f ? e : 0.2f*e;
    mx = fmaxf(mx, e);
  }
  mx = fmaxf(mx, __shfl_xor(mx, 1));
  mx = fmaxf(mx, __shfl_xor(mx, 2));
  mx = fmaxf(mx, __shfl_xor(mx, 4));

  const int c4 = lane*4;
  float sm = 0.f;
  f32x4 acc = {0.f,0.f,0.f,0.f};
  for (int j0 = 0; j0 < deg; j0 += 8){
    const int cnt = (deg - j0) < 8 ? (deg - j0) : 8;
    int s = 0; float w = 0.f;
    if (jj < cnt){
      s = eidx[e0 + j0 + jj];
      float e = asrc[s*NHD + h] + adv; e = e > 0.f ? e : 0.2f*e;
      w = __expf(e - mx);
      sm += w;
    }
    #pragma unroll
    for (int u = 0; u < 8; ++u){
      if (u < cnt){
        const int   su = __builtin_amdgcn_readlane(s, u);
        const float wu = __shfl(w, (h << 3) | u);
        short4v gv = *(const short4v*)(gm + (size_t)su*DHC + c4);
        acc.x += wu*bf2f((ushort_t)gv.x);
        acc.y += wu*bf2f((ushort_t)gv.y);
        acc.z += wu*bf2f((ushort_t)gv.z);
        acc.w += wu*bf2f((ushort_t)gv.w);
      }
    }
  }
  sm += __shfl_xor(sm, 1); sm += __shfl_xor(sm, 2); sm += __shfl_xor(sm, 4);
  const float inv = 1.f/(sm + 1e-16f);

  f32x4 bgv = *(const f32x4*)(bg + c4);
  f32x4 rv  = *(const f32x4*)(res + (size_t)node*DHC + c4);
  f32x4 o;
  #pragma unroll
  for (int q = 0; q < 4; ++q){
    float v = acc[q]*inv + bgv[q];
    v = v > 0.f ? v : expm1f(v);
    o[q] = v + rv[q];
  }
  *(f32x4*)(out + (size_t)node*DHC + c4) = o;
}

extern "C" void kernel_launch(void* const* d_in, const int* in_sizes, int n_in,
                              void* d_out, int out_size, void* d_ws, size_t ws_size,
                              hipStream_t stream){
  (void)in_sizes; (void)n_in; (void)out_size; (void)ws_size;
  const float* x     = (const float*)d_in[0];
  const int*   ei    = (const int*)d_in[1];
  const float* ln_g  = (const float*)d_in[2];
  const float* ln_b  = (const float*)d_in[3];
  const float* W1    = (const float*)d_in[4];
  const float* b1    = (const float*)d_in[5];
  const float* W2    = (const float*)d_in[6];
  const float* b2    = (const float*)d_in[7];
  const float* Wr    = (const float*)d_in[8];
  const float* br    = (const float*)d_in[9];
  const float* Wg    = (const float*)d_in[10];
  const float* att_s = (const float*)d_in[11];
  const float* att_d = (const float*)d_in[12];
  const float* bg    = (const float*)d_in[13];
  float* out = (float*)d_out;

  char* p = (char*)d_ws;
  ushort_t* xn   = (ushort_t*)(p);                   // [0, 153,600,000)
  ushort_t* h1   = (ushort_t*)(p + 153600000);       // -> 256,000,000
  // CSR + score buffers ABOVE h1 (no aliasing with xn during k3/k4)
  float*    asrc = (float*)(p + 256000000);          //   1,600,000
  float*    adst = (float*)(p + 257600000);          //   1,600,000
  int*      cnt  = (int*)(p + 259200000);            //     200,000
  int*      offs = (int*)(p + 259400064);            //     200,004
  int*      cur  = (int*)(p + 259600128);            //     200,000
  int*      eidx = (int*)(p + 259800192);            //   3,400,000 -> 263,200,192
  // transposed weights in d_out (dead until gat_agg)
  ushort_t* W1T  = (ushort_t*)d_out;                           // 3,145,728
  ushort_t* W2T  = (ushort_t*)((char*)d_out + 3145728);        // 1,048,576
  ushort_t* WrgT = (ushort_t*)((char*)d_out + 4194304);        //   524,288
  // aliased into xn region (xn dead after gemm1)
  ushort_t* hb   = (ushort_t*)(p + 0);               //  51,200,000 (bf16)
  float*    res  = (float*)(p + 51200000);           //  51,200,000 (f32)
  ushort_t* gm   = (ushort_t*)(p + 102400000);       //  25,600,000 (bf16)

  // k1: transposes + cnt zero  (1536+512+128+128+196 = 2500 blocks)
  prep_kernel<<<2500, 256, 0, stream>>>(W1, W2, Wr, Wg, W1T, W2T, WrgT, cnt);

  // k2: LN + count_edges  (12500 + 3125 blocks)
  ln_count<<<LN_BLOCKS + (NE + 255)/256, 256, 0, stream>>>(x, ln_g, ln_b, xn, ei, cnt);

  // k3: GEMM1 + scan block
  gemm128<1,1,8><<<G1_NWG + 1, 256, 0, stream>>>(xn, W1T, b1, h1, nullptr,
                                                 NND, DHID, DINP, cnt, offs, cur);

  // k4: GEMM2 + CSR fill blocks (850000/512 = 1661)
  gemm256<0,1,2,1><<<G2_NWG + (NND + NE + 511)/512, 512, 0, stream>>>(
      h1, W2T, b2, hb, nullptr, NND, DOUT, DHID,
      ei, cur, eidx, nullptr, nullptr, nullptr, nullptr);

  // k5: GEMM3 (split res|gm) + fused att-scores
  gemm256<0,2,2,0><<<G2_NWG, 512, 0, stream>>>(
      hb, WrgT, br, res, gm, NND, 2*DHC, DOUT,
      nullptr, nullptr, nullptr, att_s, att_d, asrc, adst);

  // k6: GAT aggregate
  gat_agg<<<(NND + 3)/4, 256, 0, stream>>>(offs, eidx, asrc, adst, gm, res, bg, out);
}

// Round 11
// 575.922 us; speedup vs baseline: 1.3467x; 1.1858x over previous
//
#include <hip/hip_runtime.h>
#include <hip/hip_bf16.h>
#include <cstdint>
#include <cstddef>

#define NND 50000
#define DIN 1488
#define DINP 1536
#define DHID 1024
#define DOUT 512
#define DHC 256
#define NE 800000
#define NHD 8
#define SPLITC 256

typedef __attribute__((ext_vector_type(8))) short short8;
typedef __attribute__((ext_vector_type(4))) short short4v;
typedef __attribute__((ext_vector_type(4))) float f32x4;
typedef __attribute__((ext_vector_type(4))) int int4v;
typedef unsigned short ushort_t;

__device__ __forceinline__ unsigned short f2bf(float f){
  union { float f; unsigned u; } v; v.f = f;
  unsigned r = v.u + 0x7fffu + ((v.u >> 16) & 1u);
  return (unsigned short)(r >> 16);
}
__device__ __forceinline__ float bf2f(unsigned short u){
  union { unsigned u; float f; } v; v.u = ((unsigned)u) << 16;
  return v.f;
}

__device__ __forceinline__ void async16(const void* g, void* l){
  __builtin_amdgcn_global_load_lds((__attribute__((address_space(1))) void*)g,
                                   (__attribute__((address_space(3))) void*)l, 16, 0, 0);
}

// ---- prep: 4 weight transposes (fp32 [K,N] -> bf16 [N,Kp]) + cnt zeroing ---
__device__ __forceinline__ void tc_tile(const float* __restrict__ W,
                                        ushort_t* __restrict__ WT,
                                        int K, int Nn, int Kp, int bx, int by){
  __shared__ float tile[32][33];
  const int tx = threadIdx.x & 31, ty = threadIdx.x >> 5;
  const int k0 = bx*32, n0 = by*32;
  for (int i = ty; i < 32; i += 8){
    int k = k0 + i, n = n0 + tx;
    tile[i][tx] = (k < K && n < Nn) ? W[(size_t)k*Nn + n] : 0.f;
  }
  __syncthreads();
  for (int i = ty; i < 32; i += 8){
    int n = n0 + i, k = k0 + tx;
    if (n < Nn && k < Kp) WT[(size_t)n*Kp + k] = f2bf(tile[tx][i]);
  }
}
__global__ __launch_bounds__(256) void prep_kernel(const float* W1, const float* W2,
                                                   const float* Wr, const float* Wg,
                                                   ushort_t* W1T, ushort_t* W2T,
                                                   ushort_t* WrgT, int* cnt){
  int b = blockIdx.x;
  if (b < 1536){ tc_tile(W1, W1T, DIN, DHID, DINP, b % 48, b / 48); return; }
  b -= 1536;
  if (b < 512){ tc_tile(W2, W2T, DHID, DOUT, DHID, b % 32, b / 32); return; }
  b -= 512;
  if (b < 128){ tc_tile(Wr, WrgT, DOUT, DHC, DOUT, b % 16, b / 16); return; }
  b -= 128;
  if (b < 128){ tc_tile(Wg, WrgT + 256*DOUT, DOUT, DHC, DOUT, b % 16, b / 16); return; }
  b -= 128;
  { int i = b*256 + threadIdx.x; if (i < NND) cnt[i] = 0; }
}

// ---- LayerNorm (wave/row) + count_edges, fused by block range --------------
#define LN_BLOCKS 12500
__global__ __launch_bounds__(256) void ln_count(const float* __restrict__ x,
                                                const float* __restrict__ gw,
                                                const float* __restrict__ bw,
                                                ushort_t* __restrict__ xn,
                                                const int* __restrict__ ei,
                                                int* __restrict__ cnt){
  const int bid = blockIdx.x;
  if (bid >= LN_BLOCKS){
    int e = (bid - LN_BLOCKS)*256 + threadIdx.x;
    if (e < NE) atomicAdd(&cnt[ei[NE + e]], 1);
    return;
  }
  const int wid = threadIdx.x >> 6, lane = threadIdx.x & 63;
  const int row = bid*4 + wid;
  if (row >= NND) return;
  const float* xr = x + (size_t)row * DIN;
  float s = 0.f, sq = 0.f;
  for (int i = lane*4; i < DIN; i += 256){
    f32x4 v = *(const f32x4*)(xr + i);
    s  += v.x + v.y + v.z + v.w;
    sq += v.x*v.x + v.y*v.y + v.z*v.z + v.w*v.w;
  }
  #pragma unroll
  for (int o = 32; o; o >>= 1){ s += __shfl_xor(s, o); sq += __shfl_xor(sq, o); }
  const float mu = s * (1.f/DIN);
  const float var = sq * (1.f/DIN) - mu*mu;
  const float rstd = rsqrtf(var + 1e-5f);
  ushort_t* xo = xn + (size_t)row * DINP;
  for (int i = lane*4; i < DIN; i += 256){
    f32x4 v = *(const f32x4*)(xr + i);
    f32x4 gg = *(const f32x4*)(gw + i);
    f32x4 bb = *(const f32x4*)(bw + i);
    union { ushort_t u[4]; unsigned long long q; } o;
    o.u[0] = f2bf((v.x-mu)*rstd*gg.x + bb.x);
    o.u[1] = f2bf((v.y-mu)*rstd*gg.y + bb.y);
    o.u[2] = f2bf((v.z-mu)*rstd*gg.z + bb.z);
    o.u[3] = f2bf((v.w-mu)*rstd*gg.w + bb.w);
    *(unsigned long long*)(xo + i) = o.q;
  }
  if (lane < (DINP - DIN)) xo[DIN + lane] = 0;
}

// ------------- 128x128 pipelined bf16 MFMA GEMM + scan as BLOCK 0 -----------
#define G1_NWG 3128
template<int ACT, int MODE, int CB>
__global__ __launch_bounds__(256, 2) void gemm128(const ushort_t* __restrict__ A,
                                                  const ushort_t* __restrict__ BT,
                                                  const float* __restrict__ bias,
                                                  void* __restrict__ out0,
                                                  void* __restrict__ out1,
                                                  int M, int Nn, int K,
                                                  const int* __restrict__ cnt,
                                                  int* __restrict__ offs,
                                                  int* __restrict__ cur){
  __shared__ __align__(16) ushort_t lds[2][2][128*64];   // 64 KiB
  const int t = threadIdx.x, wid = t >> 6, lane = t & 63;

  if (blockIdx.x == 0){
    // ---- scan block (runs first, hides under GEMM): exclusive prefix of
    //      (cnt[i]+1); offs[i] = cur[i] = exclusive prefix; offs[NND] = total.
    int* buf = (int*)&lds[0][0][0];
    const int chunk = (NND + 255) >> 8;                  // 196, mult of 4
    const int s0 = t*chunk;
    const int s1 = (s0 + chunk < NND) ? s0 + chunk : NND; // len mult of 4
    int s = 0;
    for (int i = s0; i < s1; i += 4){
      int4v v = *(const int4v*)(cnt + i);
      s += v.x + v.y + v.z + v.w + 4;
    }
    buf[t] = s; __syncthreads();
    for (int o = 1; o < 256; o <<= 1){
      int xv = (t >= o) ? buf[t-o] : 0;
      __syncthreads();
      buf[t] += xv;
      __syncthreads();
    }
    int run = buf[t] - s;                                // exclusive prefix
    for (int i = s0; i < s1; i += 4){
      int4v v = *(const int4v*)(cnt + i);
      int4v cu;
      cu.x = run; run += v.x + 1;
      cu.y = run; run += v.y + 1;
      cu.z = run; run += v.z + 1;
      cu.w = run; run += v.w + 1;
      *(int4v*)(cur + i)  = cu;
      *(int4v*)(offs + i) = cu;
    }
    if (t == 255) offs[NND] = run;
    return;
  }

  const int bid = blockIdx.x - 1, nwg = G1_NWG;
  const int q = nwg >> 3, r = nwg & 7;
  const int xcd = bid & 7, slot = bid >> 3;
  const int lg = (xcd < r ? xcd*(q+1) : r*(q+1) + (xcd - r)*q) + slot;
  const int brow = (lg / CB) * 128, bcol = (lg % CB) * 128;

  const int l8  = t >> 3;
  const int cb  = (t & 7) << 4;
  const int scb = cb ^ ((l8 & 7) << 4);
  const ushort_t* pAr[4]; const ushort_t* pBr[4];
  #pragma unroll
  for (int rd = 0; rd < 4; ++rd){
    int ra = brow + rd*32 + l8; ra = ra < M ? ra : M-1;
    int rb = bcol + rd*32 + l8; rb = rb < Nn ? rb : Nn-1;
    pAr[rd] = A  + (size_t)ra*K + (scb >> 1);
    pBr[rd] = BT + (size_t)rb*K + (scb >> 1);
  }
  const int w8 = wid * 8;

#define STAGE1(buf, kt) do {                                           \
    const int _o = (kt) * 64;                                          \
    _Pragma("unroll")                                                  \
    for (int _rd = 0; _rd < 4; ++_rd){                                 \
      async16(pAr[_rd] + _o, &lds[buf][0][(_rd*32 + w8)*64]);          \
      async16(pBr[_rd] + _o, &lds[buf][1][(_rd*32 + w8)*64]);          \
    }                                                                  \
  } while(0)

  f32x4 acc[4][4];
  #pragma unroll
  for (int i=0;i<4;i++)
    #pragma unroll
    for (int j=0;j<4;j++) acc[i][j] = (f32x4){0.f,0.f,0.f,0.f};

  const int wr = (wid >> 1)*64, wc = (wid & 1)*64;
  const int fr = lane & 15;
  const int kb0 = (lane >> 4) << 4;
  const int sx  = (fr & 7) << 4;
  const int ko0 = ((kb0      ) ^ sx) >> 1;
  const int ko1 = ((kb0 | 64 ) ^ sx) >> 1;

  const int nk = K >> 6;
  STAGE1(0, 0);
  STAGE1(1, 1);
  for (int kt = 0; kt < nk; ++kt){
    const ushort_t* bA = lds[kt & 1][0];
    const ushort_t* bB = lds[kt & 1][1];
    if (kt + 1 < nk) asm volatile("s_waitcnt vmcnt(8)" ::: "memory");
    else             asm volatile("s_waitcnt vmcnt(0)" ::: "memory");
    __builtin_amdgcn_s_barrier();
    short8 af[4][2], bf_[4][2];
    #pragma unroll
    for (int m=0;m<4;m++){
      const int ra = (wr + m*16 + fr)*64;
      const int rb = (wc + m*16 + fr)*64;
      af[m][0]  = *(const short8*)&bA[ra + ko0];
      af[m][1]  = *(const short8*)&bA[ra + ko1];
      bf_[m][0] = *(const short8*)&bB[rb + ko0];
      bf_[m][1] = *(const short8*)&bB[rb + ko1];
    }
    asm volatile("s_waitcnt lgkmcnt(0)" ::: "memory");
    __builtin_amdgcn_sched_barrier(0);
    __builtin_amdgcn_s_barrier();
    if (kt + 2 < nk) STAGE1(kt & 1, kt + 2);
    __builtin_amdgcn_s_setprio(1);
    #pragma unroll
    for (int m=0;m<4;m++)
      #pragma unroll
      for (int n=0;n<4;n++){
        acc[m][n] = __builtin_amdgcn_mfma_f32_16x16x32_bf16(af[m][0], bf_[n][0], acc[m][n], 0, 0, 0);
        acc[m][n] = __builtin_amdgcn_mfma_f32_16x16x32_bf16(af[m][1], bf_[n][1], acc[m][n], 0, 0, 0);
      }
    __builtin_amdgcn_s_setprio(0);
  }
#undef STAGE1

  bool isf32;
  float* outF = nullptr; ushort_t* outB = nullptr; int ostride = 0, ocb = 0;
  if (MODE == 0){ isf32 = true;  outF = (float*)out0;    ostride = Nn; ocb = bcol; }
  else if (MODE == 1){ isf32 = false; outB = (ushort_t*)out0; ostride = Nn; ocb = bcol; }
  else {
    if (bcol < SPLITC){ isf32 = true;  outF = (float*)out0;    ostride = SPLITC;      ocb = bcol; }
    else              { isf32 = false; outB = (ushort_t*)out1; ostride = Nn - SPLITC; ocb = bcol - SPLITC; }
  }
  float bv[4];
  #pragma unroll
  for (int n=0;n<4;n++){
    const int col = wc + n*16 + (lane & 15);
    float b = 0.f;
    if (MODE == 2){ if (isf32 && bias) b = bias[bcol + col]; }
    else if (bias) b = bias[bcol + col];
    bv[n] = b;
  }
  float* sF = (float*)&lds[0][0][0];
  ushort_t* sB = (ushort_t*)&lds[0][0][0];
  const int trow = t >> 3, tc16 = (t & 7) * 16;
  #pragma unroll
  for (int c = 0; c < 4; ++c){
    __syncthreads();
    if ((wid >> 1) == (c >> 1)){
      #pragma unroll
      for (int mm = 0; mm < 2; ++mm){
        const int m = 2*(c & 1) + mm;
        const int rbase = m*16 + (lane >> 4)*4 - (c & 1)*32;
        #pragma unroll
        for (int n = 0; n < 4; ++n){
          const int col = wc + n*16 + (lane & 15);
          #pragma unroll
          for (int j = 0; j < 4; ++j){
            float v = acc[m][n][j] + bv[n];
            if (ACT) v = v > 0.f ? v : 0.f;
            if (isf32) sF[(rbase + j)*128 + col] = v;
            else       sB[(rbase + j)*128 + col] = f2bf(v);
          }
        }
      }
    }
    __syncthreads();
    const int grow = brow + c*32 + trow;
    if (grow < M){
      if (isf32){
        float* dst = outF + (size_t)grow*ostride + ocb + tc16;
        const float* src = sF + trow*128 + tc16;
        #pragma unroll
        for (int q2 = 0; q2 < 4; ++q2) ((f32x4*)dst)[q2] = ((const f32x4*)src)[q2];
      } else {
        ushort_t* dst = outB + (size_t)grow*ostride + ocb + tc16;
        const ushort_t* src = sB + trow*128 + tc16;
        #pragma unroll
        for (int q2 = 0; q2 < 2; ++q2) ((short8*)dst)[q2] = ((const short8*)src)[q2];
      }
    }
  }
}

// ------------- 256x256 pipelined bf16 MFMA GEMM -----------------------------
// EXTRA==1: blocks >= NWG do CSR fill. MODE==2: fused att-scores in bf16 branch.
#define G2_NWG 392
template<int ACT, int MODE, int CB, int EXTRA>
__global__ __launch_bounds__(512, 2) void gemm256(const ushort_t* __restrict__ A,
                                                  const ushort_t* __restrict__ BT,
                                                  const float* __restrict__ bias,
                                                  void* __restrict__ out0,
                                                  void* __restrict__ out1,
                                                  int M, int Nn, int K,
                                                  const int* __restrict__ ei,
                                                  int* __restrict__ cur,
                                                  int* __restrict__ eidx,
                                                  const float* __restrict__ att_s,
                                                  const float* __restrict__ att_d,
                                                  float* __restrict__ asrc,
                                                  float* __restrict__ adst){
  __shared__ __align__(16) ushort_t lds[2][2][256*64];   // 128 KiB
  const int t = threadIdx.x, wid = t >> 6, lane = t & 63;

  if (EXTRA == 1 && blockIdx.x >= G2_NWG){
    // ---- CSR fill (self-loops + edges), 512 threads/block ----
    int i = (blockIdx.x - G2_NWG)*512 + t;
    if (i < NND){
      int p = atomicAdd(&cur[i], 1); eidx[p] = i;
    } else if (i < NND + NE){
      int e = i - NND;
      int src = ei[e], dst = ei[NE + e];
      int p = atomicAdd(&cur[dst], 1);
      eidx[p] = src;
    }
    return;
  }

  const int bid = blockIdx.x, nwg = G2_NWG;
  const int q = nwg >> 3, r = nwg & 7;
  const int xcd = bid & 7, slot = bid >> 3;
  const int lg = (xcd < r ? xcd*(q+1) : r*(q+1) + (xcd - r)*q) + slot;
  const int brow = (lg / CB) * 256, bcol = (lg % CB) * 256;

  const int l8  = t >> 3;
  const int cb  = (t & 7) << 4;
  const unsigned scb = (unsigned)(cb ^ ((l8 & 7) << 4));
  unsigned rowA[4], rowB[4];
  #pragma unroll
  for (int rd = 0; rd < 4; ++rd){
    int ra = brow + rd*64 + l8; ra = ra < M ? ra : M-1;
    int rb = bcol + rd*64 + l8; rb = rb < Nn ? rb : Nn-1;
    rowA[rd] = (unsigned)ra * (unsigned)(K*2);
    rowB[rd] = (unsigned)rb * (unsigned)(K*2);
  }
  const int wst = (wid * 8) * 64;

#define STAGE2(buf, kt) do {                                              \
    const unsigned _ob = (unsigned)(kt)*128u + scb;                       \
    _Pragma("unroll")                                                     \
    for (int _rd = 0; _rd < 4; ++_rd){                                    \
      async16((const char*)A  + rowA[_rd] + _ob, &lds[buf][0][_rd*64*64 + wst]); \
      async16((const char*)BT + rowB[_rd] + _ob, &lds[buf][1][_rd*64*64 + wst]); \
    }                                                                     \
  } while(0)

  f32x4 acc[8][4];
  #pragma unroll
  for (int i=0;i<8;i++)
    #pragma unroll
    for (int j=0;j<4;j++) acc[i][j] = (f32x4){0.f,0.f,0.f,0.f};

  const int wrow = (wid >> 2), wcol = (wid & 3);
  const int fr = lane & 15;
  const int kb0 = (lane >> 4) << 4;
  const int sx  = (fr & 7) << 4;
  const int ko0 = ((kb0      ) ^ sx) >> 1;
  const int ko1 = ((kb0 | 64 ) ^ sx) >> 1;

  const int nk = K >> 6;
  STAGE2(0, 0);
  STAGE2(1, 1);
  for (int kt = 0; kt < nk; ++kt){
    const ushort_t* bA = lds[kt & 1][0];
    const ushort_t* bB = lds[kt & 1][1];
    if (kt + 1 < nk) asm volatile("s_waitcnt vmcnt(8)" ::: "memory");
    else             asm volatile("s_waitcnt vmcnt(0)" ::: "memory");
    __builtin_amdgcn_s_barrier();
    short8 af[8][2], bf_[4][2];
    #pragma unroll
    for (int m=0;m<8;m++){
      const int ra = (wrow*128 + m*16 + fr)*64;
      af[m][0] = *(const short8*)&bA[ra + ko0];
      af[m][1] = *(const short8*)&bA[ra + ko1];
    }
    #pragma unroll
    for (int n=0;n<4;n++){
      const int rb = (wcol*64 + n*16 + fr)*64;
      bf_[n][0] = *(const short8*)&bB[rb + ko0];
      bf_[n][1] = *(const short8*)&bB[rb + ko1];
    }
    asm volatile("s_waitcnt lgkmcnt(0)" ::: "memory");
    __builtin_amdgcn_sched_barrier(0);
    __builtin_amdgcn_s_barrier();
    if (kt + 2 < nk) STAGE2(kt & 1, kt + 2);
    __builtin_amdgcn_s_setprio(1);
    #pragma unroll
    for (int m=0;m<8;m++)
      #pragma unroll
      for (int n=0;n<4;n++){
        acc[m][n] = __builtin_amdgcn_mfma_f32_16x16x32_bf16(af[m][0], bf_[n][0], acc[m][n], 0, 0, 0);
        acc[m][n] = __builtin_amdgcn_mfma_f32_16x16x32_bf16(af[m][1], bf_[n][1], acc[m][n], 0, 0, 0);
      }
    __builtin_amdgcn_s_setprio(0);
  }
#undef STAGE2

  const bool isf32 = (MODE == 0) || (MODE == 2 && bcol == 0);
  float bv[4];
  #pragma unroll
  for (int n=0;n<4;n++){
    const int col = bcol + wcol*64 + n*16 + (lane & 15);
    float b = 0.f;
    if (MODE == 1){ if (bias) b = bias[col]; }
    if (MODE == 2){ if (isf32) b = bias[col]; }
    bv[n] = b;
  }

  if (isf32){
    float* outF; int ostride, ocb;
    if (MODE == 0){ outF = (float*)out0; ostride = Nn;  ocb = bcol; }
    else          { outF = (float*)out0; ostride = 256; ocb = 0;    }
    float* sF = (float*)&lds[0][0][0];
    #pragma unroll
    for (int p = 0; p < 2; ++p){
      __syncthreads();
      if (wrow == p){
        #pragma unroll
        for (int m=0;m<8;m++){
          const int row = m*16 + (lane >> 4)*4;
          #pragma unroll
          for (int n=0;n<4;n++){
            const int col = wcol*64 + n*16 + (lane & 15);
            #pragma unroll
            for (int j=0;j<4;j++){
              float v = acc[m][n][j] + bv[n];
              if (ACT) v = v > 0.f ? v : 0.f;
              sF[(row+j)*256 + col] = v;
            }
          }
        }
      }
      __syncthreads();
      const int srow = t >> 6, scol4 = (t & 63) * 4;
      #pragma unroll
      for (int rr = 0; rr < 16; ++rr){
        const int rloc = rr*8 + srow;
        const int grow = brow + p*128 + rloc;
        if (grow < M)
          *(f32x4*)(outF + (size_t)grow*ostride + ocb + scol4) = *(const f32x4*)&sF[rloc*256 + scol4];
      }
    }
  } else {
    ushort_t* outB; int ostride, ocb;
    if (MODE == 1){ outB = (ushort_t*)out0; ostride = Nn;  ocb = bcol; }
    else          { outB = (ushort_t*)out1; ostride = 256; ocb = 0;    }
    ushort_t* sB = (ushort_t*)&lds[0][0][0];
    __syncthreads();
    #pragma unroll
    for (int m=0;m<8;m++){
      const int row = wrow*128 + m*16 + (lane >> 4)*4;
      #pragma unroll
      for (int n=0;n<4;n++){
        const int col = wcol*64 + n*16 + (lane & 15);
        #pragma unroll
        for (int j=0;j<4;j++){
          float v = acc[m][n][j] + bv[n];
          if (ACT) v = v > 0.f ? v : 0.f;
          sB[(row+j)*256 + col] = f2bf(v);
        }
      }
    }
    __syncthreads();
    const int srow = t >> 5, scol8 = (t & 31) * 8;
    #pragma unroll
    for (int rr = 0; rr < 16; ++rr){
      const int rloc = rr*16 + srow;
      const int grow = brow + rloc;
      if (grow < M)
        *(short8*)(outB + (size_t)grow*ostride + ocb + scol8) = *(const short8*)&sB[rloc*256 + scol8];
    }
    if (MODE == 2){
      // fused att-scores from the gm tile in LDS: rows [brow,brow+256), 8 heads
      const int h = t & 7;
      const int hc0 = h * 32;
      #pragma unroll
      for (int k = 0; k < 4; ++k){
        const int rloc = (t >> 3) + k*64;
        const int grow = brow + rloc;
        if (grow < M){
          float a = 0.f, d = 0.f;
          #pragma unroll
          for (int c0 = 0; c0 < 32; c0 += 8){
            short8 gv = *(const short8*)&sB[rloc*256 + hc0 + c0];
            #pragma unroll
            for (int j = 0; j < 8; ++j){
              float g = bf2f((ushort_t)gv[j]);
              a += g*att_s[hc0 + c0 + j];
              d += g*att_d[hc0 + c0 + j];
            }
          }
          asrc[grow*NHD + h] = a;
          adst[grow*NHD + h] = d;
        }
      }
    }
  }
}

// ---- fused GAT aggregate + elu + residual (wave/node, 8-edge chunks) ------
__global__ __launch_bounds__(256) void gat_agg(const int* __restrict__ offs,
                                               const int* __restrict__ eidx,
                                               const float* __restrict__ asrc,
                                               const float* __restrict__ adst,
                                               const ushort_t* __restrict__ gm,
                                               const float* __restrict__ res,
                                               const float* __restrict__ bg,
                                               float* __restrict__ out){
  const int wid = threadIdx.x >> 6, lane = threadIdx.x & 63;
  const int node = blockIdx.x*4 + wid;
  if (node >= NND) return;
  const int h = lane >> 3, jj = lane & 7;
  const int e0 = offs[node], deg = offs[node+1] - e0;
  const float adv = adst[node*NHD + h];

  float mx = -1e30f;
  for (int j = jj; j < deg; j += 8){
    int s = eidx[e0 + j];
    float e = asrc[s*NHD + h] + adv; e = e > 0.f ? e : 0.2f*e;
    mx = fmaxf(mx, e);
  }
  mx = fmaxf(mx, __shfl_xor(mx, 1));
  mx = fmaxf(mx, __shfl_xor(mx, 2));
  mx = fmaxf(mx, __shfl_xor(mx, 4));

  const int c4 = lane*4;
  float sm = 0.f;
  f32x4 acc = {0.f,0.f,0.f,0.f};
  for (int j0 = 0; j0 < deg; j0 += 8){
    const int cnt = (deg - j0) < 8 ? (deg - j0) : 8;
    int s = 0; float w = 0.f;
    if (jj < cnt){
      s = eidx[e0 + j0 + jj];
      float e = asrc[s*NHD + h] + adv; e = e > 0.f ? e : 0.2f*e;
      w = __expf(e - mx);
      sm += w;
    }
    #pragma unroll
    for (int u = 0; u < 8; ++u){
      if (u < cnt){
        const int   su = __builtin_amdgcn_readlane(s, u);
        const float wu = __shfl(w, (h << 3) | u);
        short4v gv = *(const short4v*)(gm + (size_t)su*DHC + c4);
        acc.x += wu*bf2f((ushort_t)gv.x);
        acc.y += wu*bf2f((ushort_t)gv.y);
        acc.z += wu*bf2f((ushort_t)gv.z);
        acc.w += wu*bf2f((ushort_t)gv.w);
      }
    }
  }
  sm += __shfl_xor(sm, 1); sm += __shfl_xor(sm, 2); sm += __shfl_xor(sm, 4);
  const float inv = 1.f/(sm + 1e-16f);

  f32x4 bgv = *(const f32x4*)(bg + c4);
  f32x4 rv  = *(const f32x4*)(res + (size_t)node*DHC + c4);
  f32x4 o;
  #pragma unroll
  for (int q = 0; q < 4; ++q){
    float v = acc[q]*inv + bgv[q];
    v = v > 0.f ? v : expm1f(v);
    o[q] = v + rv[q];
  }
  *(f32x4*)(out + (size_t)node*DHC + c4) = o;
}

extern "C" void kernel_launch(void* const* d_in, const int* in_sizes, int n_in,
                              void* d_out, int out_size, void* d_ws, size_t ws_size,
                              hipStream_t stream){
  (void)in_sizes; (void)n_in; (void)out_size; (void)ws_size;
  const float* x     = (const float*)d_in[0];
  const int*   ei    = (const int*)d_in[1];
  const float* ln_g  = (const float*)d_in[2];
  const float* ln_b  = (const float*)d_in[3];
  const float* W1    = (const float*)d_in[4];
  const float* b1    = (const float*)d_in[5];
  const float* W2    = (const float*)d_in[6];
  const float* b2    = (const float*)d_in[7];
  const float* Wr    = (const float*)d_in[8];
  const float* br    = (const float*)d_in[9];
  const float* Wg    = (const float*)d_in[10];
  const float* att_s = (const float*)d_in[11];
  const float* att_d = (const float*)d_in[12];
  const float* bg    = (const float*)d_in[13];
  float* out = (float*)d_out;

  char* p = (char*)d_ws;
  ushort_t* xn   = (ushort_t*)(p);                   // [0, 153,600,000)
  ushort_t* h1   = (ushort_t*)(p + 153600000);       // -> 256,000,000
  float*    asrc = (float*)(p + 256000000);          //   1,600,000
  float*    adst = (float*)(p + 257600000);          //   1,600,000
  int*      cnt  = (int*)(p + 259200000);            //     200,000
  int*      offs = (int*)(p + 259400064);            //     200,004
  int*      cur  = (int*)(p + 259600128);            //     200,000
  int*      eidx = (int*)(p + 259800192);            //   3,400,000 -> 263,200,192
  ushort_t* W1T  = (ushort_t*)d_out;                           // 3,145,728
  ushort_t* W2T  = (ushort_t*)((char*)d_out + 3145728);        // 1,048,576
  ushort_t* WrgT = (ushort_t*)((char*)d_out + 4194304);        //   524,288
  ushort_t* hb   = (ushort_t*)(p + 0);               //  51,200,000 (bf16)
  float*    res  = (float*)(p + 51200000);           //  51,200,000 (f32)
  ushort_t* gm   = (ushort_t*)(p + 102400000);       //  25,600,000 (bf16)

  // k1: transposes + cnt zero
  prep_kernel<<<2500, 256, 0, stream>>>(W1, W2, Wr, Wg, W1T, W2T, WrgT, cnt);

  // k2: LN + count_edges
  ln_count<<<LN_BLOCKS + (NE + 255)/256, 256, 0, stream>>>(x, ln_g, ln_b, xn, ei, cnt);

  // k3: GEMM1 + scan as block 0
  gemm128<1,1,8><<<G1_NWG + 1, 256, 0, stream>>>(xn, W1T, b1, h1, nullptr,
                                                 NND, DHID, DINP, cnt, offs, cur);

  // k4: GEMM2 + CSR fill blocks
  gemm256<0,1,2,1><<<G2_NWG + (NND + NE + 511)/512, 512, 0, stream>>>(
      h1, W2T, b2, hb, nullptr, NND, DOUT, DHID,
      ei, cur, eidx, nullptr, nullptr, nullptr, nullptr);

  // k5: GEMM3 (split res|gm) + fused att-scores
  gemm256<0,2,2,0><<<G2_NWG, 512, 0, stream>>>(
      hb, WrgT, br, res, gm, NND, 2*DHC, DOUT,
      nullptr, nullptr, nullptr, att_s, att_d, asrc, adst);

  // k6: GAT aggregate
  gat_agg<<<(NND + 3)/4, 256, 0, stream>>>(offs, eidx, asrc, adst, gm, res, bg, out);
}

// Round 12
// 551.406 us; speedup vs baseline: 1.4066x; 1.0445x over previous
//
#include <hip/hip_runtime.h>
#include <hip/hip_bf16.h>
#include <cstdint>
#include <cstddef>

#define NND 50000
#define DIN 1488
#define DINP 1536
#define DHID 1024
#define DOUT 512
#define DHC 256
#define NE 800000
#define NHD 8
#define SPLITC 256

typedef __attribute__((ext_vector_type(8))) short short8;
typedef __attribute__((ext_vector_type(4))) short short4v;
typedef __attribute__((ext_vector_type(4))) float f32x4;
typedef __attribute__((ext_vector_type(4))) int int4v;
typedef unsigned short ushort_t;

__device__ __forceinline__ unsigned short f2bf(float f){
  union { float f; unsigned u; } v; v.f = f;
  unsigned r = v.u + 0x7fffu + ((v.u >> 16) & 1u);
  return (unsigned short)(r >> 16);
}
__device__ __forceinline__ float bf2f(unsigned short u){
  union { unsigned u; float f; } v; v.u = ((unsigned)u) << 16;
  return v.f;
}

__device__ __forceinline__ void async16(const void* g, void* l){
  __builtin_amdgcn_global_load_lds((__attribute__((address_space(1))) void*)g,
                                   (__attribute__((address_space(3))) void*)l, 16, 0, 0);
}

// ---- prep: W1 transpose, Wrg transpose, W2 cast, b2rg fold, cnt zero -------
__device__ __forceinline__ void tc_tile(const float* __restrict__ W,
                                        ushort_t* __restrict__ WT,
                                        int K, int Nn, int Kp, int bx, int by){
  __shared__ float tile[32][33];
  const int tx = threadIdx.x & 31, ty = threadIdx.x >> 5;
  const int k0 = bx*32, n0 = by*32;
  for (int i = ty; i < 32; i += 8){
    int k = k0 + i, n = n0 + tx;
    tile[i][tx] = (k < K && n < Nn) ? W[(size_t)k*Nn + n] : 0.f;
  }
  __syncthreads();
  for (int i = ty; i < 32; i += 8){
    int n = n0 + i, k = k0 + tx;
    if (n < Nn && k < Kp) WT[(size_t)n*Kp + k] = f2bf(tile[tx][i]);
  }
}
__global__ __launch_bounds__(256) void prep_kernel(const float* W1, const float* Wr,
                                                   const float* Wg, const float* W2,
                                                   const float* b2, const float* br,
                                                   ushort_t* W1T, ushort_t* WrgT,
                                                   ushort_t* W2bf, float* b2rg,
                                                   int* cnt){
  int b = blockIdx.x;
  if (b < 1536){ tc_tile(W1, W1T, DIN, DHID, DINP, b % 48, b / 48); return; }
  b -= 1536;
  if (b < 128){ tc_tile(Wr, WrgT, DOUT, DHC, DOUT, b % 16, b / 16); return; }
  b -= 128;
  if (b < 128){ tc_tile(Wg, WrgT + 256*DOUT, DOUT, DHC, DOUT, b % 16, b / 16); return; }
  b -= 128;
  if (b < 256){                                   // W2 fp32 -> bf16 row-major cast
    const int idx = (b*256 + threadIdx.x)*8;
    f32x4 v0 = *(const f32x4*)(W2 + idx);
    f32x4 v1 = *(const f32x4*)(W2 + idx + 4);
    union { ushort_t u[8]; short8 s; } o;
    o.u[0]=f2bf(v0.x); o.u[1]=f2bf(v0.y); o.u[2]=f2bf(v0.z); o.u[3]=f2bf(v0.w);
    o.u[4]=f2bf(v1.x); o.u[5]=f2bf(v1.y); o.u[6]=f2bf(v1.z); o.u[7]=f2bf(v1.w);
    *(short8*)(W2bf + idx) = o.s;
    return;
  }
  b -= 256;
  if (b < 2){                                     // b2rg[c] = b2 . Wrg[:,c] (+br)
    const int c = b*256 + threadIdx.x;
    float acc = 0.f;
    if (c < 256){
      for (int j = 0; j < DOUT; ++j) acc += b2[j]*Wr[(size_t)j*DHC + c];
      acc += br[c];
    } else {
      const int cc = c - 256;
      for (int j = 0; j < DOUT; ++j) acc += b2[j]*Wg[(size_t)j*DHC + cc];
    }
    b2rg[c] = acc;
    return;
  }
  b -= 2;
  { int i = b*256 + threadIdx.x; if (i < NND) cnt[i] = 0; }
}

// ---- LayerNorm (wave/row) + count_edges, fused by block range --------------
#define LN_BLOCKS 12500
__global__ __launch_bounds__(256) void ln_count(const float* __restrict__ x,
                                                const float* __restrict__ gw,
                                                const float* __restrict__ bw,
                                                ushort_t* __restrict__ xn,
                                                const int* __restrict__ ei,
                                                int* __restrict__ cnt){
  const int bid = blockIdx.x;
  if (bid >= LN_BLOCKS){
    int e = (bid - LN_BLOCKS)*256 + threadIdx.x;
    if (e < NE) atomicAdd(&cnt[ei[NE + e]], 1);
    return;
  }
  const int wid = threadIdx.x >> 6, lane = threadIdx.x & 63;
  const int row = bid*4 + wid;
  if (row >= NND) return;
  const float* xr = x + (size_t)row * DIN;
  float s = 0.f, sq = 0.f;
  for (int i = lane*4; i < DIN; i += 256){
    f32x4 v = *(const f32x4*)(xr + i);
    s  += v.x + v.y + v.z + v.w;
    sq += v.x*v.x + v.y*v.y + v.z*v.z + v.w*v.w;
  }
  #pragma unroll
  for (int o = 32; o; o >>= 1){ s += __shfl_xor(s, o); sq += __shfl_xor(sq, o); }
  const float mu = s * (1.f/DIN);
  const float var = sq * (1.f/DIN) - mu*mu;
  const float rstd = rsqrtf(var + 1e-5f);
  ushort_t* xo = xn + (size_t)row * DINP;
  for (int i = lane*4; i < DIN; i += 256){
    f32x4 v = *(const f32x4*)(xr + i);
    f32x4 gg = *(const f32x4*)(gw + i);
    f32x4 bb = *(const f32x4*)(bw + i);
    union { ushort_t u[4]; unsigned long long q; } o;
    o.u[0] = f2bf((v.x-mu)*rstd*gg.x + bb.x);
    o.u[1] = f2bf((v.y-mu)*rstd*gg.y + bb.y);
    o.u[2] = f2bf((v.z-mu)*rstd*gg.z + bb.z);
    o.u[3] = f2bf((v.w-mu)*rstd*gg.w + bb.w);
    *(unsigned long long*)(xo + i) = o.q;
  }
  if (lane < (DINP - DIN)) xo[DIN + lane] = 0;
}

// ------------- 128x128 pipelined bf16 MFMA GEMM (+ scan block if SCAN) ------
template<int ACT, int MODE, int CB, int SCAN>
__global__ __launch_bounds__(256, 2) void gemm128(const ushort_t* __restrict__ A,
                                                  const ushort_t* __restrict__ BT,
                                                  const float* __restrict__ bias,
                                                  void* __restrict__ out0,
                                                  void* __restrict__ out1,
                                                  int M, int Nn, int K,
                                                  const int* __restrict__ cnt,
                                                  int* __restrict__ offs,
                                                  int* __restrict__ cur){
  __shared__ __align__(16) ushort_t lds[2][2][128*64];   // 64 KiB
  const int t = threadIdx.x, wid = t >> 6, lane = t & 63;

  if (SCAN == 1 && blockIdx.x == 0){
    int* buf = (int*)&lds[0][0][0];
    const int chunk = (NND + 255) >> 8;                  // 196, mult of 4
    const int s0 = t*chunk;
    const int s1 = (s0 + chunk < NND) ? s0 + chunk : NND;
    int s = 0;
    for (int i = s0; i < s1; i += 4){
      int4v v = *(const int4v*)(cnt + i);
      s += v.x + v.y + v.z + v.w + 4;
    }
    buf[t] = s; __syncthreads();
    for (int o = 1; o < 256; o <<= 1){
      int xv = (t >= o) ? buf[t-o] : 0;
      __syncthreads();
      buf[t] += xv;
      __syncthreads();
    }
    int run = buf[t] - s;
    for (int i = s0; i < s1; i += 4){
      int4v v = *(const int4v*)(cnt + i);
      int4v cu;
      cu.x = run; run += v.x + 1;
      cu.y = run; run += v.y + 1;
      cu.z = run; run += v.z + 1;
      cu.w = run; run += v.w + 1;
      *(int4v*)(cur + i)  = cu;
      *(int4v*)(offs + i) = cu;
    }
    if (t == 255) offs[NND] = run;
    return;
  }

  const int bid = blockIdx.x - SCAN, nwg = gridDim.x - SCAN;
  const int q = nwg >> 3, r = nwg & 7;
  const int xcd = bid & 7, slot = bid >> 3;
  const int lg = (xcd < r ? xcd*(q+1) : r*(q+1) + (xcd - r)*q) + slot;
  const int brow = (lg / CB) * 128, bcol = (lg % CB) * 128;

  const int l8  = t >> 3;
  const int cb  = (t & 7) << 4;
  const int scb = cb ^ ((l8 & 7) << 4);
  const ushort_t* pAr[4]; const ushort_t* pBr[4];
  #pragma unroll
  for (int rd = 0; rd < 4; ++rd){
    int ra = brow + rd*32 + l8; ra = ra < M ? ra : M-1;
    int rb = bcol + rd*32 + l8; rb = rb < Nn ? rb : Nn-1;
    pAr[rd] = A  + (size_t)ra*K + (scb >> 1);
    pBr[rd] = BT + (size_t)rb*K + (scb >> 1);
  }
  const int w8 = wid * 8;

#define STAGE1(buf, kt) do {                                           \
    const int _o = (kt) * 64;                                          \
    _Pragma("unroll")                                                  \
    for (int _rd = 0; _rd < 4; ++_rd){                                 \
      async16(pAr[_rd] + _o, &lds[buf][0][(_rd*32 + w8)*64]);          \
      async16(pBr[_rd] + _o, &lds[buf][1][(_rd*32 + w8)*64]);          \
    }                                                                  \
  } while(0)

  f32x4 acc[4][4];
  #pragma unroll
  for (int i=0;i<4;i++)
    #pragma unroll
    for (int j=0;j<4;j++) acc[i][j] = (f32x4){0.f,0.f,0.f,0.f};

  const int wr = (wid >> 1)*64, wc = (wid & 1)*64;
  const int fr = lane & 15;
  const int kb0 = (lane >> 4) << 4;
  const int sx  = (fr & 7) << 4;
  const int ko0 = ((kb0      ) ^ sx) >> 1;
  const int ko1 = ((kb0 | 64 ) ^ sx) >> 1;

  const int nk = K >> 6;
  STAGE1(0, 0);
  STAGE1(1, 1);
  for (int kt = 0; kt < nk; ++kt){
    const ushort_t* bA = lds[kt & 1][0];
    const ushort_t* bB = lds[kt & 1][1];
    if (kt + 1 < nk) asm volatile("s_waitcnt vmcnt(8)" ::: "memory");
    else             asm volatile("s_waitcnt vmcnt(0)" ::: "memory");
    __builtin_amdgcn_s_barrier();
    short8 af[4][2], bf_[4][2];
    #pragma unroll
    for (int m=0;m<4;m++){
      const int ra = (wr + m*16 + fr)*64;
      const int rb = (wc + m*16 + fr)*64;
      af[m][0]  = *(const short8*)&bA[ra + ko0];
      af[m][1]  = *(const short8*)&bA[ra + ko1];
      bf_[m][0] = *(const short8*)&bB[rb + ko0];
      bf_[m][1] = *(const short8*)&bB[rb + ko1];
    }
    asm volatile("s_waitcnt lgkmcnt(0)" ::: "memory");
    __builtin_amdgcn_sched_barrier(0);
    __builtin_amdgcn_s_barrier();
    if (kt + 2 < nk) STAGE1(kt & 1, kt + 2);
    __builtin_amdgcn_s_setprio(1);
    #pragma unroll
    for (int m=0;m<4;m++)
      #pragma unroll
      for (int n=0;n<4;n++){
        acc[m][n] = __builtin_amdgcn_mfma_f32_16x16x32_bf16(af[m][0], bf_[n][0], acc[m][n], 0, 0, 0);
        acc[m][n] = __builtin_amdgcn_mfma_f32_16x16x32_bf16(af[m][1], bf_[n][1], acc[m][n], 0, 0, 0);
      }
    __builtin_amdgcn_s_setprio(0);
  }
#undef STAGE1

  bool isf32;
  float* outF = nullptr; ushort_t* outB = nullptr; int ostride = 0, ocb = 0;
  if (MODE == 0){ isf32 = true;  outF = (float*)out0;    ostride = Nn; ocb = bcol; }
  else if (MODE == 1){ isf32 = false; outB = (ushort_t*)out0; ostride = Nn; ocb = bcol; }
  else {
    if (bcol < SPLITC){ isf32 = true;  outF = (float*)out0;    ostride = SPLITC;      ocb = bcol; }
    else              { isf32 = false; outB = (ushort_t*)out1; ostride = Nn - SPLITC; ocb = bcol - SPLITC; }
  }
  float bv[4];
  #pragma unroll
  for (int n=0;n<4;n++){
    const int col = wc + n*16 + (lane & 15);
    float b = 0.f;
    if (MODE == 2){ if (isf32 && bias) b = bias[bcol + col]; }
    else if (bias) b = bias[bcol + col];
    bv[n] = b;
  }
  float* sF = (float*)&lds[0][0][0];
  ushort_t* sB = (ushort_t*)&lds[0][0][0];
  const int trow = t >> 3, tc16 = (t & 7) * 16;
  #pragma unroll
  for (int c = 0; c < 4; ++c){
    __syncthreads();
    if ((wid >> 1) == (c >> 1)){
      #pragma unroll
      for (int mm = 0; mm < 2; ++mm){
        const int m = 2*(c & 1) + mm;
        const int rbase = m*16 + (lane >> 4)*4 - (c & 1)*32;
        #pragma unroll
        for (int n = 0; n < 4; ++n){
          const int col = wc + n*16 + (lane & 15);
          #pragma unroll
          for (int j = 0; j < 4; ++j){
            float v = acc[m][n][j] + bv[n];
            if (ACT) v = v > 0.f ? v : 0.f;
            if (isf32) sF[(rbase + j)*128 + col] = v;
            else       sB[(rbase + j)*128 + col] = f2bf(v);
          }
        }
      }
    }
    __syncthreads();
    const int grow = brow + c*32 + trow;
    if (grow < M){
      if (isf32){
        float* dst = outF + (size_t)grow*ostride + ocb + tc16;
        const float* src = sF + trow*128 + tc16;
        #pragma unroll
        for (int q2 = 0; q2 < 4; ++q2) ((f32x4*)dst)[q2] = ((const f32x4*)src)[q2];
      } else {
        ushort_t* dst = outB + (size_t)grow*ostride + ocb + tc16;
        const ushort_t* src = sB + trow*128 + tc16;
        #pragma unroll
        for (int q2 = 0; q2 < 2; ++q2) ((short8*)dst)[q2] = ((const short8*)src)[q2];
      }
    }
  }
}

// ------------- 256x256 pipelined bf16 MFMA GEMM -----------------------------
// EXTRA==1: blocks >= NWG do CSR fill. MODE==2: bias on BOTH halves + fused
// att-scores in the bf16 (gm) branch.
#define G2_NWG 392
template<int ACT, int MODE, int CB, int EXTRA>
__global__ __launch_bounds__(512, 2) void gemm256(const ushort_t* __restrict__ A,
                                                  const ushort_t* __restrict__ BT,
                                                  const float* __restrict__ bias,
                                                  void* __restrict__ out0,
                                                  void* __restrict__ out1,
                                                  int M, int Nn, int K,
                                                  const int* __restrict__ ei,
                                                  int* __restrict__ cur,
                                                  int* __restrict__ eidx,
                                                  const float* __restrict__ att_s,
                                                  const float* __restrict__ att_d,
                                                  float* __restrict__ asrc,
                                                  float* __restrict__ adst){
  __shared__ __align__(16) ushort_t lds[2][2][256*64];   // 128 KiB
  const int t = threadIdx.x, wid = t >> 6, lane = t & 63;

  if (EXTRA == 1 && blockIdx.x >= G2_NWG){
    int i = (blockIdx.x - G2_NWG)*512 + t;
    if (i < NND){
      int p = atomicAdd(&cur[i], 1); eidx[p] = i;
    } else if (i < NND + NE){
      int e = i - NND;
      int src = ei[e], dst = ei[NE + e];
      int p = atomicAdd(&cur[dst], 1);
      eidx[p] = src;
    }
    return;
  }

  const int bid = blockIdx.x, nwg = G2_NWG;
  const int q = nwg >> 3, r = nwg & 7;
  const int xcd = bid & 7, slot = bid >> 3;
  const int lg = (xcd < r ? xcd*(q+1) : r*(q+1) + (xcd - r)*q) + slot;
  const int brow = (lg / CB) * 256, bcol = (lg % CB) * 256;

  const int l8  = t >> 3;
  const int cb  = (t & 7) << 4;
  const unsigned scb = (unsigned)(cb ^ ((l8 & 7) << 4));
  unsigned rowA[4], rowB[4];
  #pragma unroll
  for (int rd = 0; rd < 4; ++rd){
    int ra = brow + rd*64 + l8; ra = ra < M ? ra : M-1;
    int rb = bcol + rd*64 + l8; rb = rb < Nn ? rb : Nn-1;
    rowA[rd] = (unsigned)ra * (unsigned)(K*2);
    rowB[rd] = (unsigned)rb * (unsigned)(K*2);
  }
  const int wst = (wid * 8) * 64;

#define STAGE2(buf, kt) do {                                              \
    const unsigned _ob = (unsigned)(kt)*128u + scb;                       \
    _Pragma("unroll")                                                     \
    for (int _rd = 0; _rd < 4; ++_rd){                                    \
      async16((const char*)A  + rowA[_rd] + _ob, &lds[buf][0][_rd*64*64 + wst]); \
      async16((const char*)BT + rowB[_rd] + _ob, &lds[buf][1][_rd*64*64 + wst]); \
    }                                                                     \
  } while(0)

  f32x4 acc[8][4];
  #pragma unroll
  for (int i=0;i<8;i++)
    #pragma unroll
    for (int j=0;j<4;j++) acc[i][j] = (f32x4){0.f,0.f,0.f,0.f};

  const int wrow = (wid >> 2), wcol = (wid & 3);
  const int fr = lane & 15;
  const int kb0 = (lane >> 4) << 4;
  const int sx  = (fr & 7) << 4;
  const int ko0 = ((kb0      ) ^ sx) >> 1;
  const int ko1 = ((kb0 | 64 ) ^ sx) >> 1;

  const int nk = K >> 6;
  STAGE2(0, 0);
  STAGE2(1, 1);
  for (int kt = 0; kt < nk; ++kt){
    const ushort_t* bA = lds[kt & 1][0];
    const ushort_t* bB = lds[kt & 1][1];
    if (kt + 1 < nk) asm volatile("s_waitcnt vmcnt(8)" ::: "memory");
    else             asm volatile("s_waitcnt vmcnt(0)" ::: "memory");
    __builtin_amdgcn_s_barrier();
    short8 af[8][2], bf_[4][2];
    #pragma unroll
    for (int m=0;m<8;m++){
      const int ra = (wrow*128 + m*16 + fr)*64;
      af[m][0] = *(const short8*)&bA[ra + ko0];
      af[m][1] = *(const short8*)&bA[ra + ko1];
    }
    #pragma unroll
    for (int n=0;n<4;n++){
      const int rb = (wcol*64 + n*16 + fr)*64;
      bf_[n][0] = *(const short8*)&bB[rb + ko0];
      bf_[n][1] = *(const short8*)&bB[rb + ko1];
    }
    asm volatile("s_waitcnt lgkmcnt(0)" ::: "memory");
    __builtin_amdgcn_sched_barrier(0);
    __builtin_amdgcn_s_barrier();
    if (kt + 2 < nk) STAGE2(kt & 1, kt + 2);
    __builtin_amdgcn_s_setprio(1);
    #pragma unroll
    for (int m=0;m<8;m++)
      #pragma unroll
      for (int n=0;n<4;n++){
        acc[m][n] = __builtin_amdgcn_mfma_f32_16x16x32_bf16(af[m][0], bf_[n][0], acc[m][n], 0, 0, 0);
        acc[m][n] = __builtin_amdgcn_mfma_f32_16x16x32_bf16(af[m][1], bf_[n][1], acc[m][n], 0, 0, 0);
      }
    __builtin_amdgcn_s_setprio(0);
  }
#undef STAGE2

  const bool isf32 = (MODE == 0) || (MODE == 2 && bcol == 0);
  float bv[4];
  #pragma unroll
  for (int n=0;n<4;n++){
    const int col = bcol + wcol*64 + n*16 + (lane & 15);
    float b = 0.f;
    if (MODE == 1){ if (bias) b = bias[col]; }
    if (MODE == 2){ b = bias[col]; }          // fused b2rg on BOTH halves
    bv[n] = b;
  }

  if (isf32){
    float* outF; int ostride, ocb;
    if (MODE == 0){ outF = (float*)out0; ostride = Nn;  ocb = bcol; }
    else          { outF = (float*)out0; ostride = 256; ocb = 0;    }
    float* sF = (float*)&lds[0][0][0];
    #pragma unroll
    for (int p = 0; p < 2; ++p){
      __syncthreads();
      if (wrow == p){
        #pragma unroll
        for (int m=0;m<8;m++){
          const int row = m*16 + (lane >> 4)*4;
          #pragma unroll
          for (int n=0;n<4;n++){
            const int col = wcol*64 + n*16 + (lane & 15);
            #pragma unroll
            for (int j=0;j<4;j++){
              float v = acc[m][n][j] + bv[n];
              if (ACT) v = v > 0.f ? v : 0.f;
              sF[(row+j)*256 + col] = v;
            }
          }
        }
      }
      __syncthreads();
      const int srow = t >> 6, scol4 = (t & 63) * 4;
      #pragma unroll
      for (int rr = 0; rr < 16; ++rr){
        const int rloc = rr*8 + srow;
        const int grow = brow + p*128 + rloc;
        if (grow < M)
          *(f32x4*)(outF + (size_t)grow*ostride + ocb + scol4) = *(const f32x4*)&sF[rloc*256 + scol4];
      }
    }
  } else {
    ushort_t* outB; int ostride, ocb;
    if (MODE == 1){ outB = (ushort_t*)out0; ostride = Nn;  ocb = bcol; }
    else          { outB = (ushort_t*)out1; ostride = 256; ocb = 0;    }
    ushort_t* sB = (ushort_t*)&lds[0][0][0];
    __syncthreads();
    #pragma unroll
    for (int m=0;m<8;m++){
      const int row = wrow*128 + m*16 + (lane >> 4)*4;
      #pragma unroll
      for (int n=0;n<4;n++){
        const int col = wcol*64 + n*16 + (lane & 15);
        #pragma unroll
        for (int j=0;j<4;j++){
          float v = acc[m][n][j] + bv[n];
          if (ACT) v = v > 0.f ? v : 0.f;
          sB[(row+j)*256 + col] = f2bf(v);
        }
      }
    }
    __syncthreads();
    const int srow = t >> 5, scol8 = (t & 31) * 8;
    #pragma unroll
    for (int rr = 0; rr < 16; ++rr){
      const int rloc = rr*16 + srow;
      const int grow = brow + rloc;
      if (grow < M)
        *(short8*)(outB + (size_t)grow*ostride + ocb + scol8) = *(const short8*)&sB[rloc*256 + scol8];
    }
    if (MODE == 2){
      const int h = t & 7;
      const int hc0 = h * 32;
      #pragma unroll
      for (int k = 0; k < 4; ++k){
        const int rloc = (t >> 3) + k*64;
        const int grow = brow + rloc;
        if (grow < M){
          float a = 0.f, d = 0.f;
          #pragma unroll
          for (int c0 = 0; c0 < 32; c0 += 8){
            short8 gv = *(const short8*)&sB[rloc*256 + hc0 + c0];
            #pragma unroll
            for (int j = 0; j < 8; ++j){
              float g = bf2f((ushort_t)gv[j]);
              a += g*att_s[hc0 + c0 + j];
              d += g*att_d[hc0 + c0 + j];
            }
          }
          asrc[grow*NHD + h] = a;
          adst[grow*NHD + h] = d;
        }
      }
    }
  }
}

// ---- fused GAT aggregate + elu + residual (wave/node, 8-edge chunks) ------
__global__ __launch_bounds__(256) void gat_agg(const int* __restrict__ offs,
                                               const int* __restrict__ eidx,
                                               const float* __restrict__ asrc,
                                               const float* __restrict__ adst,
                                               const ushort_t* __restrict__ gm,
                                               const float* __restrict__ res,
                                               const float* __restrict__ bg,
                                               float* __restrict__ out){
  const int wid = threadIdx.x >> 6, lane = threadIdx.x & 63;
  const int node = blockIdx.x*4 + wid;
  if (node >= NND) return;
  const int h = lane >> 3, jj = lane & 7;
  const int e0 = offs[node], deg = offs[node+1] - e0;
  const float adv = adst[node*NHD + h];

  float mx = -1e30f;
  for (int j = jj; j < deg; j += 8){
    int s = eidx[e0 + j];
    float e = asrc[s*NHD + h] + adv; e = e > 0.f ? e : 0.2f*e;
    mx = fmaxf(mx, e);
  }
  mx = fmaxf(mx, __shfl_xor(mx, 1));
  mx = fmaxf(mx, __shfl_xor(mx, 2));
  mx = fmaxf(mx, __shfl_xor(mx, 4));

  const int c4 = lane*4;
  float sm = 0.f;
  f32x4 acc = {0.f,0.f,0.f,0.f};
  for (int j0 = 0; j0 < deg; j0 += 8){
    const int cnt = (deg - j0) < 8 ? (deg - j0) : 8;
    int s = 0; float w = 0.f;
    if (jj < cnt){
      s = eidx[e0 + j0 + jj];
      float e = asrc[s*NHD + h] + adv; e = e > 0.f ? e : 0.2f*e;
      w = __expf(e - mx);
      sm += w;
    }
    #pragma unroll
    for (int u = 0; u < 8; ++u){
      if (u < cnt){
        const int   su = __builtin_amdgcn_readlane(s, u);
        const float wu = __shfl(w, (h << 3) | u);
        short4v gv = *(const short4v*)(gm + (size_t)su*DHC + c4);
        acc.x += wu*bf2f((ushort_t)gv.x);
        acc.y += wu*bf2f((ushort_t)gv.y);
        acc.z += wu*bf2f((ushort_t)gv.z);
        acc.w += wu*bf2f((ushort_t)gv.w);
      }
    }
  }
  sm += __shfl_xor(sm, 1); sm += __shfl_xor(sm, 2); sm += __shfl_xor(sm, 4);
  const float inv = 1.f/(sm + 1e-16f);

  f32x4 bgv = *(const f32x4*)(bg + c4);
  f32x4 rv  = *(const f32x4*)(res + (size_t)node*DHC + c4);
  f32x4 o;
  #pragma unroll
  for (int q = 0; q < 4; ++q){
    float v = acc[q]*inv + bgv[q];
    v = v > 0.f ? v : expm1f(v);
    o[q] = v + rv[q];
  }
  *(f32x4*)(out + (size_t)node*DHC + c4) = o;
}

extern "C" void kernel_launch(void* const* d_in, const int* in_sizes, int n_in,
                              void* d_out, int out_size, void* d_ws, size_t ws_size,
                              hipStream_t stream){
  (void)in_sizes; (void)n_in; (void)out_size; (void)ws_size;
  const float* x     = (const float*)d_in[0];
  const int*   ei    = (const int*)d_in[1];
  const float* ln_g  = (const float*)d_in[2];
  const float* ln_b  = (const float*)d_in[3];
  const float* W1    = (const float*)d_in[4];
  const float* b1    = (const float*)d_in[5];
  const float* W2    = (const float*)d_in[6];
  const float* b2    = (const float*)d_in[7];
  const float* Wr    = (const float*)d_in[8];
  const float* br    = (const float*)d_in[9];
  const float* Wg    = (const float*)d_in[10];
  const float* att_s = (const float*)d_in[11];
  const float* att_d = (const float*)d_in[12];
  const float* bg    = (const float*)d_in[13];
  float* out = (float*)d_out;

  char* p = (char*)d_ws;
  ushort_t* xn   = (ushort_t*)(p);                   // [0, 153,600,000)
  ushort_t* h1   = (ushort_t*)(p + 153600000);       // -> 256,000,000
  float*    asrc = (float*)(p + 256000000);
  float*    adst = (float*)(p + 257600000);
  int*      cnt  = (int*)(p + 259200000);
  int*      offs = (int*)(p + 259400064);
  int*      cur  = (int*)(p + 259600128);
  int*      eidx = (int*)(p + 259800192);            // -> 263,200,192
  // scratch in d_out (dead until gat_agg writes out)
  ushort_t* W1T  = (ushort_t*)d_out;                           // 3,145,728
  ushort_t* WrgT = (ushort_t*)((char*)d_out + 3145728);        //   524,288
  ushort_t* W2bf = (ushort_t*)((char*)d_out + 3670016);        // 1,048,576
  ushort_t* WcT  = (ushort_t*)((char*)d_out + 4718592);        // 1,048,576
  float*    b2rg = (float*)((char*)d_out + 5767168);           //     2,048
  // aliased into xn region (xn dead after gemm1)
  float*    res  = (float*)(p + 0);                  //  51,200,000 (f32)
  ushort_t* gm   = (ushort_t*)(p + 51200000);        //  25,600,000 (bf16)

  // k1: W1T + WrgT transposes, W2 cast, b2rg fold, cnt zero
  prep_kernel<<<2246, 256, 0, stream>>>(W1, Wr, Wg, W2, b2, br,
                                        W1T, WrgT, W2bf, b2rg, cnt);

  // k2: WcT = (W2 @ [Wr|Wg])^T  — tiny GEMM: M=512, Nn=1024, K=512
  gemm128<0,1,8,0><<<32, 256, 0, stream>>>(WrgT, W2bf, nullptr, WcT, nullptr,
                                           512, 1024, 512, nullptr, nullptr, nullptr);

  // k3: LN + count_edges
  ln_count<<<LN_BLOCKS + (NE + 255)/256, 256, 0, stream>>>(x, ln_g, ln_b, xn, ei, cnt);

  // k4: GEMM1 + scan as block 0
  gemm128<1,1,8,1><<<3128 + 1, 256, 0, stream>>>(xn, W1T, b1, h1, nullptr,
                                                 NND, DHID, DINP, cnt, offs, cur);

  // k5: fused [res|gm] = h1 @ WcT^T + b2rg  (split epilogue + att + fill)
  gemm256<0,2,2,1><<<G2_NWG + (NND + NE + 511)/512, 512, 0, stream>>>(
      h1, WcT, b2rg, res, gm, NND, 2*DHC, DHID,
      ei, cur, eidx, att_s, att_d, asrc, adst);

  // k6: GAT aggregate
  gat_agg<<<(NND + 3)/4, 256, 0, stream>>>(offs, eidx, asrc, adst, gm, res, bg, out);
}

// Round 13
// 530.376 us; speedup vs baseline: 1.4624x; 1.0397x over previous
//
#include <hip/hip_runtime.h>
#include <hip/hip_bf16.h>
#include <cstdint>
#include <cstddef>

#define NND 50000
#define DIN 1488
#define DINP 1536
#define DHID 1024
#define DOUT 512
#define DHC 256
#define NE 800000
#define NHD 8
#define SPLITC 256

typedef __attribute__((ext_vector_type(8))) short short8;
typedef __attribute__((ext_vector_type(4))) short short4v;
typedef __attribute__((ext_vector_type(4))) float f32x4;
typedef __attribute__((ext_vector_type(4))) int int4v;
typedef unsigned short ushort_t;

__device__ __forceinline__ unsigned short f2bf(float f){
  union { float f; unsigned u; } v; v.f = f;
  unsigned r = v.u + 0x7fffu + ((v.u >> 16) & 1u);
  return (unsigned short)(r >> 16);
}
__device__ __forceinline__ float bf2f(unsigned short u){
  union { unsigned u; float f; } v; v.u = ((unsigned)u) << 16;
  return v.f;
}

__device__ __forceinline__ void async16(const void* g, void* l){
  __builtin_amdgcn_global_load_lds((__attribute__((address_space(1))) void*)g,
                                   (__attribute__((address_space(3))) void*)l, 16, 0, 0);
}

// ---- prep: W1 transpose, Wrg transpose, W2 cast, b2rg fold, cnt zero -------
__device__ __forceinline__ void tc_tile(const float* __restrict__ W,
                                        ushort_t* __restrict__ WT,
                                        int K, int Nn, int Kp, int bx, int by){
  __shared__ float tile[32][33];
  const int tx = threadIdx.x & 31, ty = threadIdx.x >> 5;
  const int k0 = bx*32, n0 = by*32;
  for (int i = ty; i < 32; i += 8){
    int k = k0 + i, n = n0 + tx;
    tile[i][tx] = (k < K && n < Nn) ? W[(size_t)k*Nn + n] : 0.f;
  }
  __syncthreads();
  for (int i = ty; i < 32; i += 8){
    int n = n0 + i, k = k0 + tx;
    if (n < Nn && k < Kp) WT[(size_t)n*Kp + k] = f2bf(tile[tx][i]);
  }
}
__global__ __launch_bounds__(256) void prep_kernel(const float* W1, const float* Wr,
                                                   const float* Wg, const float* W2,
                                                   const float* b2, const float* br,
                                                   ushort_t* W1T, ushort_t* WrgT,
                                                   ushort_t* W2bf, float* b2rg,
                                                   int* cnt){
  int b = blockIdx.x;
  if (b < 1536){ tc_tile(W1, W1T, DIN, DHID, DINP, b % 48, b / 48); return; }
  b -= 1536;
  if (b < 128){ tc_tile(Wr, WrgT, DOUT, DHC, DOUT, b % 16, b / 16); return; }
  b -= 128;
  if (b < 128){ tc_tile(Wg, WrgT + 256*DOUT, DOUT, DHC, DOUT, b % 16, b / 16); return; }
  b -= 128;
  if (b < 256){                                   // W2 fp32 -> bf16 row-major cast
    const int idx = (b*256 + threadIdx.x)*8;
    f32x4 v0 = *(const f32x4*)(W2 + idx);
    f32x4 v1 = *(const f32x4*)(W2 + idx + 4);
    union { ushort_t u[8]; short8 s; } o;
    o.u[0]=f2bf(v0.x); o.u[1]=f2bf(v0.y); o.u[2]=f2bf(v0.z); o.u[3]=f2bf(v0.w);
    o.u[4]=f2bf(v1.x); o.u[5]=f2bf(v1.y); o.u[6]=f2bf(v1.z); o.u[7]=f2bf(v1.w);
    *(short8*)(W2bf + idx) = o.s;
    return;
  }
  b -= 256;
  if (b < 2){                                     // b2rg[c] = b2 . Wrg[:,c] (+br)
    const int c = b*256 + threadIdx.x;
    float acc = 0.f;
    if (c < 256){
      for (int j = 0; j < DOUT; ++j) acc += b2[j]*Wr[(size_t)j*DHC + c];
      acc += br[c];
    } else {
      const int cc = c - 256;
      for (int j = 0; j < DOUT; ++j) acc += b2[j]*Wg[(size_t)j*DHC + cc];
    }
    b2rg[c] = acc;
    return;
  }
  b -= 2;
  { int i = b*256 + threadIdx.x; if (i < NND) cnt[i] = 0; }
}

// ---- LayerNorm (wave/row) + count_edges, fused by block range --------------
#define LN_BLOCKS 12500
__global__ __launch_bounds__(256) void ln_count(const float* __restrict__ x,
                                                const float* __restrict__ gw,
                                                const float* __restrict__ bw,
                                                ushort_t* __restrict__ xn,
                                                const int* __restrict__ ei,
                                                int* __restrict__ cnt){
  const int bid = blockIdx.x;
  if (bid >= LN_BLOCKS){
    int e = (bid - LN_BLOCKS)*256 + threadIdx.x;
    if (e < NE) atomicAdd(&cnt[ei[NE + e]], 1);
    return;
  }
  const int wid = threadIdx.x >> 6, lane = threadIdx.x & 63;
  const int row = bid*4 + wid;
  if (row >= NND) return;
  const float* xr = x + (size_t)row * DIN;
  float s = 0.f, sq = 0.f;
  for (int i = lane*4; i < DIN; i += 256){
    f32x4 v = *(const f32x4*)(xr + i);
    s  += v.x + v.y + v.z + v.w;
    sq += v.x*v.x + v.y*v.y + v.z*v.z + v.w*v.w;
  }
  #pragma unroll
  for (int o = 32; o; o >>= 1){ s += __shfl_xor(s, o); sq += __shfl_xor(sq, o); }
  const float mu = s * (1.f/DIN);
  const float var = sq * (1.f/DIN) - mu*mu;
  const float rstd = rsqrtf(var + 1e-5f);
  ushort_t* xo = xn + (size_t)row * DINP;
  for (int i = lane*4; i < DIN; i += 256){
    f32x4 v = *(const f32x4*)(xr + i);
    f32x4 gg = *(const f32x4*)(gw + i);
    f32x4 bb = *(const f32x4*)(bw + i);
    union { ushort_t u[4]; unsigned long long q; } o;
    o.u[0] = f2bf((v.x-mu)*rstd*gg.x + bb.x);
    o.u[1] = f2bf((v.y-mu)*rstd*gg.y + bb.y);
    o.u[2] = f2bf((v.z-mu)*rstd*gg.z + bb.z);
    o.u[3] = f2bf((v.w-mu)*rstd*gg.w + bb.w);
    *(unsigned long long*)(xo + i) = o.q;
  }
  if (lane < (DINP - DIN)) xo[DIN + lane] = 0;
}

// ------------- 128x128 pipelined bf16 MFMA GEMM (tiny WcT GEMM) -------------
template<int ACT, int MODE, int CB, int SCAN>
__global__ __launch_bounds__(256, 2) void gemm128(const ushort_t* __restrict__ A,
                                                  const ushort_t* __restrict__ BT,
                                                  const float* __restrict__ bias,
                                                  void* __restrict__ out0,
                                                  void* __restrict__ out1,
                                                  int M, int Nn, int K,
                                                  const int* __restrict__ cnt,
                                                  int* __restrict__ offs,
                                                  int* __restrict__ cur){
  __shared__ __align__(16) ushort_t lds[2][2][128*64];   // 64 KiB
  const int t = threadIdx.x, wid = t >> 6, lane = t & 63;

  const int bid = blockIdx.x - SCAN, nwg = gridDim.x - SCAN;
  const int q = nwg >> 3, r = nwg & 7;
  const int xcd = bid & 7, slot = bid >> 3;
  const int lg = (xcd < r ? xcd*(q+1) : r*(q+1) + (xcd - r)*q) + slot;
  const int brow = (lg / CB) * 128, bcol = (lg % CB) * 128;

  const int l8  = t >> 3;
  const int cb  = (t & 7) << 4;
  const int scb = cb ^ ((l8 & 7) << 4);
  const ushort_t* pAr[4]; const ushort_t* pBr[4];
  #pragma unroll
  for (int rd = 0; rd < 4; ++rd){
    int ra = brow + rd*32 + l8; ra = ra < M ? ra : M-1;
    int rb = bcol + rd*32 + l8; rb = rb < Nn ? rb : Nn-1;
    pAr[rd] = A  + (size_t)ra*K + (scb >> 1);
    pBr[rd] = BT + (size_t)rb*K + (scb >> 1);
  }
  const int w8 = wid * 8;

#define STAGE1(buf, kt) do {                                           \
    const int _o = (kt) * 64;                                          \
    _Pragma("unroll")                                                  \
    for (int _rd = 0; _rd < 4; ++_rd){                                 \
      async16(pAr[_rd] + _o, &lds[buf][0][(_rd*32 + w8)*64]);          \
      async16(pBr[_rd] + _o, &lds[buf][1][(_rd*32 + w8)*64]);          \
    }                                                                  \
  } while(0)

  f32x4 acc[4][4];
  #pragma unroll
  for (int i=0;i<4;i++)
    #pragma unroll
    for (int j=0;j<4;j++) acc[i][j] = (f32x4){0.f,0.f,0.f,0.f};

  const int wr = (wid >> 1)*64, wc = (wid & 1)*64;
  const int fr = lane & 15;
  const int kb0 = (lane >> 4) << 4;
  const int sx  = (fr & 7) << 4;
  const int ko0 = ((kb0      ) ^ sx) >> 1;
  const int ko1 = ((kb0 | 64 ) ^ sx) >> 1;

  const int nk = K >> 6;
  STAGE1(0, 0);
  STAGE1(1, 1);
  for (int kt = 0; kt < nk; ++kt){
    const ushort_t* bA = lds[kt & 1][0];
    const ushort_t* bB = lds[kt & 1][1];
    if (kt + 1 < nk) asm volatile("s_waitcnt vmcnt(8)" ::: "memory");
    else             asm volatile("s_waitcnt vmcnt(0)" ::: "memory");
    __builtin_amdgcn_s_barrier();
    short8 af[4][2], bf_[4][2];
    #pragma unroll
    for (int m=0;m<4;m++){
      const int ra = (wr + m*16 + fr)*64;
      const int rb = (wc + m*16 + fr)*64;
      af[m][0]  = *(const short8*)&bA[ra + ko0];
      af[m][1]  = *(const short8*)&bA[ra + ko1];
      bf_[m][0] = *(const short8*)&bB[rb + ko0];
      bf_[m][1] = *(const short8*)&bB[rb + ko1];
    }
    asm volatile("s_waitcnt lgkmcnt(0)" ::: "memory");
    __builtin_amdgcn_sched_barrier(0);
    __builtin_amdgcn_s_barrier();
    if (kt + 2 < nk) STAGE1(kt & 1, kt + 2);
    __builtin_amdgcn_s_setprio(1);
    #pragma unroll
    for (int m=0;m<4;m++)
      #pragma unroll
      for (int n=0;n<4;n++){
        acc[m][n] = __builtin_amdgcn_mfma_f32_16x16x32_bf16(af[m][0], bf_[n][0], acc[m][n], 0, 0, 0);
        acc[m][n] = __builtin_amdgcn_mfma_f32_16x16x32_bf16(af[m][1], bf_[n][1], acc[m][n], 0, 0, 0);
      }
    __builtin_amdgcn_s_setprio(0);
  }
#undef STAGE1

  bool isf32;
  float* outF = nullptr; ushort_t* outB = nullptr; int ostride = 0, ocb = 0;
  if (MODE == 0){ isf32 = true;  outF = (float*)out0;    ostride = Nn; ocb = bcol; }
  else if (MODE == 1){ isf32 = false; outB = (ushort_t*)out0; ostride = Nn; ocb = bcol; }
  else {
    if (bcol < SPLITC){ isf32 = true;  outF = (float*)out0;    ostride = SPLITC;      ocb = bcol; }
    else              { isf32 = false; outB = (ushort_t*)out1; ostride = Nn - SPLITC; ocb = bcol - SPLITC; }
  }
  float bv[4];
  #pragma unroll
  for (int n=0;n<4;n++){
    const int col = wc + n*16 + (lane & 15);
    float b = 0.f;
    if (MODE == 2){ if (isf32 && bias) b = bias[bcol + col]; }
    else if (bias) b = bias[bcol + col];
    bv[n] = b;
  }
  float* sF = (float*)&lds[0][0][0];
  ushort_t* sB = (ushort_t*)&lds[0][0][0];
  const int trow = t >> 3, tc16 = (t & 7) * 16;
  #pragma unroll
  for (int c = 0; c < 4; ++c){
    __syncthreads();
    if ((wid >> 1) == (c >> 1)){
      #pragma unroll
      for (int mm = 0; mm < 2; ++mm){
        const int m = 2*(c & 1) + mm;
        const int rbase = m*16 + (lane >> 4)*4 - (c & 1)*32;
        #pragma unroll
        for (int n = 0; n < 4; ++n){
          const int col = wc + n*16 + (lane & 15);
          #pragma unroll
          for (int j = 0; j < 4; ++j){
            float v = acc[m][n][j] + bv[n];
            if (ACT) v = v > 0.f ? v : 0.f;
            if (isf32) sF[(rbase + j)*128 + col] = v;
            else       sB[(rbase + j)*128 + col] = f2bf(v);
          }
        }
      }
    }
    __syncthreads();
    const int grow = brow + c*32 + trow;
    if (grow < M){
      if (isf32){
        float* dst = outF + (size_t)grow*ostride + ocb + tc16;
        const float* src = sF + trow*128 + tc16;
        #pragma unroll
        for (int q2 = 0; q2 < 4; ++q2) ((f32x4*)dst)[q2] = ((const f32x4*)src)[q2];
      } else {
        ushort_t* dst = outB + (size_t)grow*ostride + ocb + tc16;
        const ushort_t* src = sB + trow*128 + tc16;
        #pragma unroll
        for (int q2 = 0; q2 < 2; ++q2) ((short8*)dst)[q2] = ((const short8*)src)[q2];
      }
    }
  }
}

// ------- 256x256 8-phase m201-style GEMM (GEMM1) + scan as block 0 ----------
// Per tile T (BK=64): ph1{rd A m0-3 + B n0-1, stg B-h0(T+1)} ph2{rd A m4-7,
// stg B-h1(T+1)} ph3{rd B n2-3, stg A-h0(T+2)} ph4{stg A-h1(T+2), vmcnt(4),
// bar, MFMA}. 4 barriers + 1 counted vmcnt per tile; half-tile = 128x64.
template<int ACT, int CB>
__global__ __launch_bounds__(512, 1) void gemm256p8(const ushort_t* __restrict__ A,
                                                    const ushort_t* __restrict__ BT,
                                                    const float* __restrict__ bias,
                                                    ushort_t* __restrict__ out0,
                                                    int M, int Nn, int K,
                                                    const int* __restrict__ cnt,
                                                    int* __restrict__ offs,
                                                    int* __restrict__ cur){
  __shared__ __align__(16) ushort_t lds[2][2][2][64*128];  // [dbuf][A,B][half][8K elem]
  const int t = threadIdx.x, wid = t >> 6, lane = t & 63;

  if (blockIdx.x == 0){
    // ---- CSR scan (512 threads, 256 active), hides under the GEMM ----
    int* sbuf = (int*)&lds[0][0][0][0];
    const int chunk = (NND + 255) >> 8;                  // 196, mult of 4
    int s = 0;
    if (t < 256){
      const int s0 = t*chunk;
      const int s1 = (s0 + chunk < NND) ? s0 + chunk : NND;
      for (int i = s0; i < s1; i += 4){
        int4v v = *(const int4v*)(cnt + i);
        s += v.x + v.y + v.z + v.w + 4;
      }
    }
    sbuf[t] = s; __syncthreads();
    for (int o = 1; o < 256; o <<= 1){
      int xv = (t >= o && t < 256) ? sbuf[t-o] : 0;
      __syncthreads();
      if (t < 256) sbuf[t] += xv;
      __syncthreads();
    }
    if (t < 256){
      int run = sbuf[t] - s;
      const int s0 = t*chunk;
      const int s1 = (s0 + chunk < NND) ? s0 + chunk : NND;
      for (int i = s0; i < s1; i += 4){
        int4v v = *(const int4v*)(cnt + i);
        int4v cu;
        cu.x = run; run += v.x + 1;
        cu.y = run; run += v.y + 1;
        cu.z = run; run += v.z + 1;
        cu.w = run; run += v.w + 1;
        *(int4v*)(cur + i)  = cu;
        *(int4v*)(offs + i) = cu;
      }
      if (t == 255) offs[NND] = run;
    }
    return;
  }

  const int bid = blockIdx.x - 1, nwg = gridDim.x - 1;
  const int q = nwg >> 3, r = nwg & 7;
  const int xcd = bid & 7, slot = bid >> 3;
  const int lg = (xcd < r ? xcd*(q+1) : r*(q+1) + (xcd - r)*q) + slot;
  const int brow = (lg / CB) * 256, bcol = (lg % CB) * 256;

  // staging: thread t covers (row_local = rd*64 + t>>3, colbyte (t&7)*16)
  const int l8  = t >> 3;
  const int cb  = (t & 7) << 4;
  const unsigned scb = (unsigned)(cb ^ ((l8 & 7) << 4));
  unsigned rowA[2][2], rowB[2][2];
  #pragma unroll
  for (int hf = 0; hf < 2; ++hf)
    #pragma unroll
    for (int rd = 0; rd < 2; ++rd){
      int ra = brow + hf*128 + rd*64 + l8; ra = ra < M ? ra : M-1;
      int rb = bcol + hf*128 + rd*64 + l8; rb = rb < Nn ? rb : Nn-1;
      rowA[hf][rd] = (unsigned)ra * (unsigned)(K*2);
      rowB[hf][rd] = (unsigned)rb * (unsigned)(K*2);
    }
  const int w8 = wid * 8;

#define STG_A(buf, hf, kt) do {                                               \
    const unsigned _ob = (unsigned)(kt)*128u + scb;                           \
    async16((const char*)A + rowA[hf][0] + _ob, &lds[buf][0][hf][(w8)*64]);   \
    async16((const char*)A + rowA[hf][1] + _ob, &lds[buf][0][hf][(64+w8)*64]);\
  } while(0)
#define STG_B(buf, hf, kt) do {                                               \
    const unsigned _ob = (unsigned)(kt)*128u + scb;                           \
    async16((const char*)BT + rowB[hf][0] + _ob, &lds[buf][1][hf][(w8)*64]);  \
    async16((const char*)BT + rowB[hf][1] + _ob, &lds[buf][1][hf][(64+w8)*64]);\
  } while(0)

  f32x4 acc[8][4];
  #pragma unroll
  for (int i=0;i<8;i++)
    #pragma unroll
    for (int j=0;j<4;j++) acc[i][j] = (f32x4){0.f,0.f,0.f,0.f};

  const int wrow = (wid >> 2), wcol = (wid & 3);   // 2 x 4 waves, out 128x64
  const int fr = lane & 15;
  const int kb0 = (lane >> 4) << 4;
  const int sx  = (fr & 7) << 4;
  const int ko0 = ((kb0      ) ^ sx) >> 1;
  const int ko1 = ((kb0 | 64 ) ^ sx) >> 1;
  const int bhalf = wcol >> 1, brl = (wcol & 1)*64;

#define RD_A(buf, m) do {                                          \
    const int _ra = ((m)*16 + fr)*64;                              \
    af[m][0] = *(const short8*)&lds[buf][0][wrow][_ra + ko0];      \
    af[m][1] = *(const short8*)&lds[buf][0][wrow][_ra + ko1];      \
  } while(0)
#define RD_B(buf, n) do {                                          \
    const int _rb = (brl + (n)*16 + fr)*64;                        \
    bf[n][0] = *(const short8*)&lds[buf][1][bhalf][_rb + ko0];     \
    bf[n][1] = *(const short8*)&lds[buf][1][bhalf][_rb + ko1];     \
  } while(0)
#define SYNC_PH() do {                                             \
    __builtin_amdgcn_s_barrier();                                  \
    asm volatile("s_waitcnt lgkmcnt(0)" ::: "memory");             \
    __builtin_amdgcn_sched_barrier(0);                             \
  } while(0)
#define MFMA_Q(M0, N0) do {                                        \
    __builtin_amdgcn_s_setprio(1);                                 \
    _Pragma("unroll")                                              \
    for (int _m=(M0); _m<(M0)+4; ++_m)                             \
      _Pragma("unroll")                                            \
      for (int _n=(N0); _n<(N0)+2; ++_n){                          \
        acc[_m][_n] = __builtin_amdgcn_mfma_f32_16x16x32_bf16(af[_m][0], bf[_n][0], acc[_m][_n], 0, 0, 0); \
        acc[_m][_n] = __builtin_amdgcn_mfma_f32_16x16x32_bf16(af[_m][1], bf[_n][1], acc[_m][_n], 0, 0, 0); \
      }                                                            \
    __builtin_amdgcn_s_setprio(0);                                 \
  } while(0)

  const int nk = K >> 6;
  // prologue: tile0 (A+B) + A(1); vmcnt(4) leaves A(1) in flight (steady state)
  STG_A(0,0,0); STG_A(0,1,0); STG_B(0,0,0); STG_B(0,1,0);
  STG_A(1,0,1); STG_A(1,1,1);
  asm volatile("s_waitcnt vmcnt(4)" ::: "memory");
  __builtin_amdgcn_s_barrier();

  for (int kt = 0; kt < nk; ++kt){
    const int buf = kt & 1, obuf = buf ^ 1;
    short8 af[8][2], bf[4][2];
    // ph1
    RD_A(buf,0); RD_A(buf,1); RD_A(buf,2); RD_A(buf,3);
    RD_B(buf,0); RD_B(buf,1);
    if (kt + 1 < nk) STG_B(obuf, 0, kt + 1);
    SYNC_PH();
    MFMA_Q(0, 0);
    // ph2
    RD_A(buf,4); RD_A(buf,5); RD_A(buf,6); RD_A(buf,7);
    if (kt + 1 < nk) STG_B(obuf, 1, kt + 1);
    SYNC_PH();
    MFMA_Q(4, 0);
    // ph3
    RD_B(buf,2); RD_B(buf,3);
    if (kt + 2 < nk) STG_A(buf, 0, kt + 2);
    SYNC_PH();
    MFMA_Q(0, 2);
    // ph4
    if (kt + 2 < nk){
      STG_A(buf, 1, kt + 2);
      asm volatile("s_waitcnt vmcnt(4)" ::: "memory");
    } else {
      asm volatile("s_waitcnt vmcnt(0)" ::: "memory");
    }
    __builtin_amdgcn_s_barrier();
    MFMA_Q(4, 2);
  }
#undef STG_A
#undef STG_B
#undef RD_A
#undef RD_B
#undef SYNC_PH
#undef MFMA_Q

  // ---- epilogue: bf16 out (stride Nn), bias + optional relu ----
  float bv[4];
  #pragma unroll
  for (int n=0;n<4;n++){
    const int col = bcol + wcol*64 + n*16 + (lane & 15);
    bv[n] = bias ? bias[col] : 0.f;
  }
  ushort_t* sB = (ushort_t*)&lds[0][0][0][0];
  __syncthreads();
  #pragma unroll
  for (int m=0;m<8;m++){
    const int row = wrow*128 + m*16 + (lane >> 4)*4;
    #pragma unroll
    for (int n=0;n<4;n++){
      const int col = wcol*64 + n*16 + (lane & 15);
      #pragma unroll
      for (int j=0;j<4;j++){
        float v = acc[m][n][j] + bv[n];
        if (ACT) v = v > 0.f ? v : 0.f;
        sB[(row+j)*256 + col] = f2bf(v);
      }
    }
  }
  __syncthreads();
  const int srow = t >> 5, scol8 = (t & 31) * 8;
  #pragma unroll
  for (int rr = 0; rr < 16; ++rr){
    const int rloc = rr*16 + srow;
    const int grow = brow + rloc;
    if (grow < M)
      *(short8*)(out0 + (size_t)grow*Nn + bcol + scol8) = *(const short8*)&sB[rloc*256 + scol8];
  }
}

// ------------- 256x256 2-phase bf16 MFMA GEMM (k5) --------------------------
#define G2_NWG 392
template<int ACT, int MODE, int CB, int EXTRA>
__global__ __launch_bounds__(512, 2) void gemm256(const ushort_t* __restrict__ A,
                                                  const ushort_t* __restrict__ BT,
                                                  const float* __restrict__ bias,
                                                  void* __restrict__ out0,
                                                  void* __restrict__ out1,
                                                  int M, int Nn, int K,
                                                  const int* __restrict__ ei,
                                                  int* __restrict__ cur,
                                                  int* __restrict__ eidx,
                                                  const float* __restrict__ att_s,
                                                  const float* __restrict__ att_d,
                                                  float* __restrict__ asrc,
                                                  float* __restrict__ adst){
  __shared__ __align__(16) ushort_t lds[2][2][256*64];   // 128 KiB
  const int t = threadIdx.x, wid = t >> 6, lane = t & 63;

  if (EXTRA == 1 && blockIdx.x >= G2_NWG){
    int i = (blockIdx.x - G2_NWG)*512 + t;
    if (i < NND){
      int p = atomicAdd(&cur[i], 1); eidx[p] = i;
    } else if (i < NND + NE){
      int e = i - NND;
      int src = ei[e], dst = ei[NE + e];
      int p = atomicAdd(&cur[dst], 1);
      eidx[p] = src;
    }
    return;
  }

  const int bid = blockIdx.x, nwg = G2_NWG;
  const int q = nwg >> 3, r = nwg & 7;
  const int xcd = bid & 7, slot = bid >> 3;
  const int lg = (xcd < r ? xcd*(q+1) : r*(q+1) + (xcd - r)*q) + slot;
  const int brow = (lg / CB) * 256, bcol = (lg % CB) * 256;

  const int l8  = t >> 3;
  const int cb  = (t & 7) << 4;
  const unsigned scb = (unsigned)(cb ^ ((l8 & 7) << 4));
  unsigned rowA[4], rowB[4];
  #pragma unroll
  for (int rd = 0; rd < 4; ++rd){
    int ra = brow + rd*64 + l8; ra = ra < M ? ra : M-1;
    int rb = bcol + rd*64 + l8; rb = rb < Nn ? rb : Nn-1;
    rowA[rd] = (unsigned)ra * (unsigned)(K*2);
    rowB[rd] = (unsigned)rb * (unsigned)(K*2);
  }
  const int wst = (wid * 8) * 64;

#define STAGE2(buf, kt) do {                                              \
    const unsigned _ob = (unsigned)(kt)*128u + scb;                       \
    _Pragma("unroll")                                                     \
    for (int _rd = 0; _rd < 4; ++_rd){                                    \
      async16((const char*)A  + rowA[_rd] + _ob, &lds[buf][0][_rd*64*64 + wst]); \
      async16((const char*)BT + rowB[_rd] + _ob, &lds[buf][1][_rd*64*64 + wst]); \
    }                                                                     \
  } while(0)

  f32x4 acc[8][4];
  #pragma unroll
  for (int i=0;i<8;i++)
    #pragma unroll
    for (int j=0;j<4;j++) acc[i][j] = (f32x4){0.f,0.f,0.f,0.f};

  const int wrow = (wid >> 2), wcol = (wid & 3);
  const int fr = lane & 15;
  const int kb0 = (lane >> 4) << 4;
  const int sx  = (fr & 7) << 4;
  const int ko0 = ((kb0      ) ^ sx) >> 1;
  const int ko1 = ((kb0 | 64 ) ^ sx) >> 1;

  const int nk = K >> 6;
  STAGE2(0, 0);
  STAGE2(1, 1);
  for (int kt = 0; kt < nk; ++kt){
    const ushort_t* bA = lds[kt & 1][0];
    const ushort_t* bB = lds[kt & 1][1];
    if (kt + 1 < nk) asm volatile("s_waitcnt vmcnt(8)" ::: "memory");
    else             asm volatile("s_waitcnt vmcnt(0)" ::: "memory");
    __builtin_amdgcn_s_barrier();
    short8 af[8][2], bf_[4][2];
    #pragma unroll
    for (int m=0;m<8;m++){
      const int ra = (wrow*128 + m*16 + fr)*64;
      af[m][0] = *(const short8*)&bA[ra + ko0];
      af[m][1] = *(const short8*)&bA[ra + ko1];
    }
    #pragma unroll
    for (int n=0;n<4;n++){
      const int rb = (wcol*64 + n*16 + fr)*64;
      bf_[n][0] = *(const short8*)&bB[rb + ko0];
      bf_[n][1] = *(const short8*)&bB[rb + ko1];
    }
    asm volatile("s_waitcnt lgkmcnt(0)" ::: "memory");
    __builtin_amdgcn_sched_barrier(0);
    __builtin_amdgcn_s_barrier();
    if (kt + 2 < nk) STAGE2(kt & 1, kt + 2);
    __builtin_amdgcn_s_setprio(1);
    #pragma unroll
    for (int m=0;m<8;m++)
      #pragma unroll
      for (int n=0;n<4;n++){
        acc[m][n] = __builtin_amdgcn_mfma_f32_16x16x32_bf16(af[m][0], bf_[n][0], acc[m][n], 0, 0, 0);
        acc[m][n] = __builtin_amdgcn_mfma_f32_16x16x32_bf16(af[m][1], bf_[n][1], acc[m][n], 0, 0, 0);
      }
    __builtin_amdgcn_s_setprio(0);
  }
#undef STAGE2

  const bool isf32 = (MODE == 0) || (MODE == 2 && bcol == 0);
  float bv[4];
  #pragma unroll
  for (int n=0;n<4;n++){
    const int col = bcol + wcol*64 + n*16 + (lane & 15);
    float b = 0.f;
    if (MODE == 1){ if (bias) b = bias[col]; }
    if (MODE == 2){ b = bias[col]; }
    bv[n] = b;
  }

  if (isf32){
    float* outF; int ostride, ocb;
    if (MODE == 0){ outF = (float*)out0; ostride = Nn;  ocb = bcol; }
    else          { outF = (float*)out0; ostride = 256; ocb = 0;    }
    float* sF = (float*)&lds[0][0][0];
    #pragma unroll
    for (int p = 0; p < 2; ++p){
      __syncthreads();
      if (wrow == p){
        #pragma unroll
        for (int m=0;m<8;m++){
          const int row = m*16 + (lane >> 4)*4;
          #pragma unroll
          for (int n=0;n<4;n++){
            const int col = wcol*64 + n*16 + (lane & 15);
            #pragma unroll
            for (int j=0;j<4;j++){
              float v = acc[m][n][j] + bv[n];
              if (ACT) v = v > 0.f ? v : 0.f;
              sF[(row+j)*256 + col] = v;
            }
          }
        }
      }
      __syncthreads();
      const int srow = t >> 6, scol4 = (t & 63) * 4;
      #pragma unroll
      for (int rr = 0; rr < 16; ++rr){
        const int rloc = rr*8 + srow;
        const int grow = brow + p*128 + rloc;
        if (grow < M)
          *(f32x4*)(outF + (size_t)grow*ostride + ocb + scol4) = *(const f32x4*)&sF[rloc*256 + scol4];
      }
    }
  } else {
    ushort_t* outB; int ostride, ocb;
    if (MODE == 1){ outB = (ushort_t*)out0; ostride = Nn;  ocb = bcol; }
    else          { outB = (ushort_t*)out1; ostride = 256; ocb = 0;    }
    ushort_t* sB = (ushort_t*)&lds[0][0][0];
    __syncthreads();
    #pragma unroll
    for (int m=0;m<8;m++){
      const int row = wrow*128 + m*16 + (lane >> 4)*4;
      #pragma unroll
      for (int n=0;n<4;n++){
        const int col = wcol*64 + n*16 + (lane & 15);
        #pragma unroll
        for (int j=0;j<4;j++){
          float v = acc[m][n][j] + bv[n];
          if (ACT) v = v > 0.f ? v : 0.f;
          sB[(row+j)*256 + col] = f2bf(v);
        }
      }
    }
    __syncthreads();
    const int srow = t >> 5, scol8 = (t & 31) * 8;
    #pragma unroll
    for (int rr = 0; rr < 16; ++rr){
      const int rloc = rr*16 + srow;
      const int grow = brow + rloc;
      if (grow < M)
        *(short8*)(outB + (size_t)grow*ostride + ocb + scol8) = *(const short8*)&sB[rloc*256 + scol8];
    }
    if (MODE == 2){
      const int h = t & 7;
      const int hc0 = h * 32;
      #pragma unroll
      for (int k = 0; k < 4; ++k){
        const int rloc = (t >> 3) + k*64;
        const int grow = brow + rloc;
        if (grow < M){
          float a = 0.f, d = 0.f;
          #pragma unroll
          for (int c0 = 0; c0 < 32; c0 += 8){
            short8 gv = *(const short8*)&sB[rloc*256 + hc0 + c0];
            #pragma unroll
            for (int j = 0; j < 8; ++j){
              float g = bf2f((ushort_t)gv[j]);
              a += g*att_s[hc0 + c0 + j];
              d += g*att_d[hc0 + c0 + j];
            }
          }
          asrc[grow*NHD + h] = a;
          adst[grow*NHD + h] = d;
        }
      }
    }
  }
}

// ---- fused GAT aggregate + elu + residual (wave/node, 8-edge chunks) ------
__global__ __launch_bounds__(256) void gat_agg(const int* __restrict__ offs,
                                               const int* __restrict__ eidx,
                                               const float* __restrict__ asrc,
                                               const float* __restrict__ adst,
                                               const ushort_t* __restrict__ gm,
                                               const float* __restrict__ res,
                                               const float* __restrict__ bg,
                                               float* __restrict__ out){
  const int wid = threadIdx.x >> 6, lane = threadIdx.x & 63;
  const int node = blockIdx.x*4 + wid;
  if (node >= NND) return;
  const int h = lane >> 3, jj = lane & 7;
  const int e0 = offs[node], deg = offs[node+1] - e0;
  const float adv = adst[node*NHD + h];

  float mx = -1e30f;
  for (int j = jj; j < deg; j += 8){
    int s = eidx[e0 + j];
    float e = asrc[s*NHD + h] + adv; e = e > 0.f ? e : 0.2f*e;
    mx = fmaxf(mx, e);
  }
  mx = fmaxf(mx, __shfl_xor(mx, 1));
  mx = fmaxf(mx, __shfl_xor(mx, 2));
  mx = fmaxf(mx, __shfl_xor(mx, 4));

  const int c4 = lane*4;
  float sm = 0.f;
  f32x4 acc = {0.f,0.f,0.f,0.f};
  for (int j0 = 0; j0 < deg; j0 += 8){
    const int cnt = (deg - j0) < 8 ? (deg - j0) : 8;
    int s = 0; float w = 0.f;
    if (jj < cnt){
      s = eidx[e0 + j0 + jj];
      float e = asrc[s*NHD + h] + adv; e = e > 0.f ? e : 0.2f*e;
      w = __expf(e - mx);
      sm += w;
    }
    #pragma unroll
    for (int u = 0; u < 8; ++u){
      if (u < cnt){
        const int   su = __builtin_amdgcn_readlane(s, u);
        const float wu = __shfl(w, (h << 3) | u);
        short4v gv = *(const short4v*)(gm + (size_t)su*DHC + c4);
        acc.x += wu*bf2f((ushort_t)gv.x);
        acc.y += wu*bf2f((ushort_t)gv.y);
        acc.z += wu*bf2f((ushort_t)gv.z);
        acc.w += wu*bf2f((ushort_t)gv.w);
      }
    }
  }
  sm += __shfl_xor(sm, 1); sm += __shfl_xor(sm, 2); sm += __shfl_xor(sm, 4);
  const float inv = 1.f/(sm + 1e-16f);

  f32x4 bgv = *(const f32x4*)(bg + c4);
  f32x4 rv  = *(const f32x4*)(res + (size_t)node*DHC + c4);
  f32x4 o;
  #pragma unroll
  for (int q = 0; q < 4; ++q){
    float v = acc[q]*inv + bgv[q];
    v = v > 0.f ? v : expm1f(v);
    o[q] = v + rv[q];
  }
  *(f32x4*)(out + (size_t)node*DHC + c4) = o;
}

extern "C" void kernel_launch(void* const* d_in, const int* in_sizes, int n_in,
                              void* d_out, int out_size, void* d_ws, size_t ws_size,
                              hipStream_t stream){
  (void)in_sizes; (void)n_in; (void)out_size; (void)ws_size;
  const float* x     = (const float*)d_in[0];
  const int*   ei    = (const int*)d_in[1];
  const float* ln_g  = (const float*)d_in[2];
  const float* ln_b  = (const float*)d_in[3];
  const float* W1    = (const float*)d_in[4];
  const float* b1    = (const float*)d_in[5];
  const float* W2    = (const float*)d_in[6];
  const float* b2    = (const float*)d_in[7];
  const float* Wr    = (const float*)d_in[8];
  const float* br    = (const float*)d_in[9];
  const float* Wg    = (const float*)d_in[10];
  const float* att_s = (const float*)d_in[11];
  const float* att_d = (const float*)d_in[12];
  const float* bg    = (const float*)d_in[13];
  float* out = (float*)d_out;

  char* p = (char*)d_ws;
  ushort_t* xn   = (ushort_t*)(p);                   // [0, 153,600,000)
  ushort_t* h1   = (ushort_t*)(p + 153600000);       // -> 256,000,000
  float*    asrc = (float*)(p + 256000000);
  float*    adst = (float*)(p + 257600000);
  int*      cnt  = (int*)(p + 259200000);
  int*      offs = (int*)(p + 259400064);
  int*      cur  = (int*)(p + 259600128);
  int*      eidx = (int*)(p + 259800192);            // -> 263,200,192
  ushort_t* W1T  = (ushort_t*)d_out;                           // 3,145,728
  ushort_t* WrgT = (ushort_t*)((char*)d_out + 3145728);        //   524,288
  ushort_t* W2bf = (ushort_t*)((char*)d_out + 3670016);        // 1,048,576
  ushort_t* WcT  = (ushort_t*)((char*)d_out + 4718592);        // 1,048,576
  float*    b2rg = (float*)((char*)d_out + 5767168);           //     2,048
  float*    res  = (float*)(p + 0);                  //  51,200,000 (f32)
  ushort_t* gm   = (ushort_t*)(p + 51200000);        //  25,600,000 (bf16)

  // k1: W1T + WrgT transposes, W2 cast, b2rg fold, cnt zero
  prep_kernel<<<2246, 256, 0, stream>>>(W1, Wr, Wg, W2, b2, br,
                                        W1T, WrgT, W2bf, b2rg, cnt);

  // k2: WcT = (W2 @ [Wr|Wg])^T  — tiny GEMM
  gemm128<0,1,8,0><<<32, 256, 0, stream>>>(WrgT, W2bf, nullptr, WcT, nullptr,
                                           512, 1024, 512, nullptr, nullptr, nullptr);

  // k3: LN + count_edges
  ln_count<<<LN_BLOCKS + (NE + 255)/256, 256, 0, stream>>>(x, ln_g, ln_b, xn, ei, cnt);

  // k4: GEMM1 (8-phase 256^2) + scan as block 0; grid = 196*4 + 1
  gemm256p8<1,4><<<785, 512, 0, stream>>>(xn, W1T, b1, h1,
                                          NND, DHID, DINP, cnt, offs, cur);

  // k5: fused [res|gm] = h1 @ WcT^T + b2rg  (split epilogue + att + fill)
  gemm256<0,2,2,1><<<G2_NWG + (NND + NE + 511)/512, 512, 0, stream>>>(
      h1, WcT, b2rg, res, gm, NND, 2*DHC, DHID,
      ei, cur, eidx, att_s, att_d, asrc, adst);

  // k6: GAT aggregate
  gat_agg<<<(NND + 3)/4, 256, 0, stream>>>(offs, eidx, asrc, adst, gm, res, bg, out);
}

// Round 14
// 508.604 us; speedup vs baseline: 1.5250x; 1.0428x over previous
//
#include <hip/hip_runtime.h>
#include <hip/hip_bf16.h>
#include <cstdint>
#include <cstddef>

#define NND 50000
#define DIN 1488
#define DINP 1536
#define DHID 1024
#define DOUT 512
#define DHC 256
#define NE 800000
#define NHD 8
#define SPLITC 256

typedef __attribute__((ext_vector_type(8))) short short8;
typedef __attribute__((ext_vector_type(4))) short short4v;
typedef __attribute__((ext_vector_type(4))) float f32x4;
typedef __attribute__((ext_vector_type(4))) int int4v;
typedef unsigned short ushort_t;

__device__ __forceinline__ unsigned short f2bf(float f){
  union { float f; unsigned u; } v; v.f = f;
  unsigned r = v.u + 0x7fffu + ((v.u >> 16) & 1u);
  return (unsigned short)(r >> 16);
}
__device__ __forceinline__ float bf2f(unsigned short u){
  union { unsigned u; float f; } v; v.u = ((unsigned)u) << 16;
  return v.f;
}

__device__ __forceinline__ void async16(const void* g, void* l){
  __builtin_amdgcn_global_load_lds((__attribute__((address_space(1))) void*)g,
                                   (__attribute__((address_space(3))) void*)l, 16, 0, 0);
}

// ---- fused stage 1: LN (wave/row) + weight prep + count_edges --------------
__device__ __forceinline__ void tc_tile(const float* __restrict__ W,
                                        ushort_t* __restrict__ WT,
                                        int K, int Nn, int Kp, int bx, int by){
  __shared__ float tile[32][33];
  const int tx = threadIdx.x & 31, ty = threadIdx.x >> 5;
  const int k0 = bx*32, n0 = by*32;
  for (int i = ty; i < 32; i += 8){
    int k = k0 + i, n = n0 + tx;
    tile[i][tx] = (k < K && n < Nn) ? W[(size_t)k*Nn + n] : 0.f;
  }
  __syncthreads();
  for (int i = ty; i < 32; i += 8){
    int n = n0 + i, k = k0 + tx;
    if (n < Nn && k < Kp) WT[(size_t)n*Kp + k] = f2bf(tile[tx][i]);
  }
}

#define F1_LN   12500
#define F1_PREP (F1_LN + 2050)
__global__ __launch_bounds__(256) void fused1(const float* __restrict__ x,
                                              const float* __restrict__ gw,
                                              const float* __restrict__ bw,
                                              ushort_t* __restrict__ xn,
                                              const int* __restrict__ ei,
                                              int* __restrict__ cnt,
                                              const float* W1, const float* Wr,
                                              const float* Wg, const float* W2,
                                              const float* b2, const float* br,
                                              ushort_t* W1T, ushort_t* WrgT,
                                              ushort_t* W2bf, float* b2rg){
  const int bid = blockIdx.x;
  if (bid < F1_LN){
    const int wid = threadIdx.x >> 6, lane = threadIdx.x & 63;
    const int row = bid*4 + wid;
    if (row >= NND) return;
    const float* xr = x + (size_t)row * DIN;
    float s = 0.f, sq = 0.f;
    for (int i = lane*4; i < DIN; i += 256){
      f32x4 v = *(const f32x4*)(xr + i);
      s  += v.x + v.y + v.z + v.w;
      sq += v.x*v.x + v.y*v.y + v.z*v.z + v.w*v.w;
    }
    #pragma unroll
    for (int o = 32; o; o >>= 1){ s += __shfl_xor(s, o); sq += __shfl_xor(sq, o); }
    const float mu = s * (1.f/DIN);
    const float var = sq * (1.f/DIN) - mu*mu;
    const float rstd = rsqrtf(var + 1e-5f);
    ushort_t* xo = xn + (size_t)row * DINP;
    for (int i = lane*4; i < DIN; i += 256){
      f32x4 v = *(const f32x4*)(xr + i);
      f32x4 gg = *(const f32x4*)(gw + i);
      f32x4 bb = *(const f32x4*)(bw + i);
      union { ushort_t u[4]; unsigned long long q; } o;
      o.u[0] = f2bf((v.x-mu)*rstd*gg.x + bb.x);
      o.u[1] = f2bf((v.y-mu)*rstd*gg.y + bb.y);
      o.u[2] = f2bf((v.z-mu)*rstd*gg.z + bb.z);
      o.u[3] = f2bf((v.w-mu)*rstd*gg.w + bb.w);
      *(unsigned long long*)(xo + i) = o.q;
    }
    if (lane < (DINP - DIN)) xo[DIN + lane] = 0;
    return;
  }
  if (bid < F1_PREP){
    int b = bid - F1_LN;
    if (b < 1536){ tc_tile(W1, W1T, DIN, DHID, DINP, b % 48, b / 48); return; }
    b -= 1536;
    if (b < 128){ tc_tile(Wr, WrgT, DOUT, DHC, DOUT, b % 16, b / 16); return; }
    b -= 128;
    if (b < 128){ tc_tile(Wg, WrgT + 256*DOUT, DOUT, DHC, DOUT, b % 16, b / 16); return; }
    b -= 128;
    if (b < 256){                                 // W2 fp32 -> bf16 cast
      const int idx = (b*256 + threadIdx.x)*8;
      f32x4 v0 = *(const f32x4*)(W2 + idx);
      f32x4 v1 = *(const f32x4*)(W2 + idx + 4);
      union { ushort_t u[8]; short8 s; } o;
      o.u[0]=f2bf(v0.x); o.u[1]=f2bf(v0.y); o.u[2]=f2bf(v0.z); o.u[3]=f2bf(v0.w);
      o.u[4]=f2bf(v1.x); o.u[5]=f2bf(v1.y); o.u[6]=f2bf(v1.z); o.u[7]=f2bf(v1.w);
      *(short8*)(W2bf + idx) = o.s;
      return;
    }
    b -= 256;
    {                                             // b2rg fold (2 blocks)
      const int c = b*256 + threadIdx.x;
      float acc = 0.f;
      if (c < 256){
        for (int j = 0; j < DOUT; ++j) acc += b2[j]*Wr[(size_t)j*DHC + c];
        acc += br[c];
      } else {
        const int cc = c - 256;
        for (int j = 0; j < DOUT; ++j) acc += b2[j]*Wg[(size_t)j*DHC + cc];
      }
      b2rg[c] = acc;
      return;
    }
  }
  {
    int e = (bid - F1_PREP)*256 + threadIdx.x;
    if (e < NE) atomicAdd(&cnt[ei[NE + e]], 1);
  }
}

// ------- 256x256 8-phase GEMM body (device fn; runtime act) -----------------
// Per tile T (BK=64): ph1{rd A m0-3 + B n0-1, stg B-h0(T+1)} ph2{rd A m4-7,
// stg B-h1(T+1)} ph3{rd B n2-3, stg A-h0(T+2)} ph4{stg A-h1(T+2), vmcnt(4),
// bar, MFMA}. 4 barriers + 1 counted vmcnt per tile.
__device__ __forceinline__ void g256p8_body(ushort_t (&lds)[2][2][2][64*128],
                                            const ushort_t* __restrict__ A,
                                            const ushort_t* __restrict__ BT,
                                            const float* __restrict__ bias,
                                            ushort_t* __restrict__ out0,
                                            int M, int Nn, int K,
                                            int bid, int nwg, bool act){
  const int t = threadIdx.x, wid = t >> 6, lane = t & 63;
  const int CB = Nn >> 8;
  const int q = nwg >> 3, r = nwg & 7;
  const int xcd = bid & 7, slot = bid >> 3;
  const int lg = (xcd < r ? xcd*(q+1) : r*(q+1) + (xcd - r)*q) + slot;
  const int brow = (lg / CB) * 256, bcol = (lg % CB) * 256;

  const int l8  = t >> 3;
  const int cb  = (t & 7) << 4;
  const unsigned scb = (unsigned)(cb ^ ((l8 & 7) << 4));
  unsigned rowA[2][2], rowB[2][2];
  #pragma unroll
  for (int hf = 0; hf < 2; ++hf)
    #pragma unroll
    for (int rd = 0; rd < 2; ++rd){
      int ra = brow + hf*128 + rd*64 + l8; ra = ra < M ? ra : M-1;
      int rb = bcol + hf*128 + rd*64 + l8; rb = rb < Nn ? rb : Nn-1;
      rowA[hf][rd] = (unsigned)ra * (unsigned)(K*2);
      rowB[hf][rd] = (unsigned)rb * (unsigned)(K*2);
    }
  const int w8 = wid * 8;

#define STG_A(buf, hf, kt) do {                                               \
    const unsigned _ob = (unsigned)(kt)*128u + scb;                           \
    async16((const char*)A + rowA[hf][0] + _ob, &lds[buf][0][hf][(w8)*64]);   \
    async16((const char*)A + rowA[hf][1] + _ob, &lds[buf][0][hf][(64+w8)*64]);\
  } while(0)
#define STG_B(buf, hf, kt) do {                                               \
    const unsigned _ob = (unsigned)(kt)*128u + scb;                           \
    async16((const char*)BT + rowB[hf][0] + _ob, &lds[buf][1][hf][(w8)*64]);  \
    async16((const char*)BT + rowB[hf][1] + _ob, &lds[buf][1][hf][(64+w8)*64]);\
  } while(0)

  f32x4 acc[8][4];
  #pragma unroll
  for (int i=0;i<8;i++)
    #pragma unroll
    for (int j=0;j<4;j++) acc[i][j] = (f32x4){0.f,0.f,0.f,0.f};

  const int wrow = (wid >> 2), wcol = (wid & 3);
  const int fr = lane & 15;
  const int kb0 = (lane >> 4) << 4;
  const int sx  = (fr & 7) << 4;
  const int ko0 = ((kb0      ) ^ sx) >> 1;
  const int ko1 = ((kb0 | 64 ) ^ sx) >> 1;
  const int bhalf = wcol >> 1, brl = (wcol & 1)*64;

#define RD_A(buf, m) do {                                          \
    const int _ra = ((m)*16 + fr)*64;                              \
    af[m][0] = *(const short8*)&lds[buf][0][wrow][_ra + ko0];      \
    af[m][1] = *(const short8*)&lds[buf][0][wrow][_ra + ko1];      \
  } while(0)
#define RD_B(buf, n) do {                                          \
    const int _rb = (brl + (n)*16 + fr)*64;                        \
    bf[n][0] = *(const short8*)&lds[buf][1][bhalf][_rb + ko0];     \
    bf[n][1] = *(const short8*)&lds[buf][1][bhalf][_rb + ko1];     \
  } while(0)
#define SYNC_PH() do {                                             \
    __builtin_amdgcn_s_barrier();                                  \
    asm volatile("s_waitcnt lgkmcnt(0)" ::: "memory");             \
    __builtin_amdgcn_sched_barrier(0);                             \
  } while(0)
#define MFMA_Q(M0, N0) do {                                        \
    __builtin_amdgcn_s_setprio(1);                                 \
    _Pragma("unroll")                                              \
    for (int _m=(M0); _m<(M0)+4; ++_m)                             \
      _Pragma("unroll")                                            \
      for (int _n=(N0); _n<(N0)+2; ++_n){                          \
        acc[_m][_n] = __builtin_amdgcn_mfma_f32_16x16x32_bf16(af[_m][0], bf[_n][0], acc[_m][_n], 0, 0, 0); \
        acc[_m][_n] = __builtin_amdgcn_mfma_f32_16x16x32_bf16(af[_m][1], bf[_n][1], acc[_m][_n], 0, 0, 0); \
      }                                                            \
    __builtin_amdgcn_s_setprio(0);                                 \
  } while(0)

  const int nk = K >> 6;
  STG_A(0,0,0); STG_A(0,1,0); STG_B(0,0,0); STG_B(0,1,0);
  STG_A(1,0,1); STG_A(1,1,1);
  asm volatile("s_waitcnt vmcnt(4)" ::: "memory");
  __builtin_amdgcn_s_barrier();

  for (int kt = 0; kt < nk; ++kt){
    const int buf = kt & 1, obuf = buf ^ 1;
    short8 af[8][2], bf[4][2];
    RD_A(buf,0); RD_A(buf,1); RD_A(buf,2); RD_A(buf,3);
    RD_B(buf,0); RD_B(buf,1);
    if (kt + 1 < nk) STG_B(obuf, 0, kt + 1);
    SYNC_PH();
    MFMA_Q(0, 0);
    RD_A(buf,4); RD_A(buf,5); RD_A(buf,6); RD_A(buf,7);
    if (kt + 1 < nk) STG_B(obuf, 1, kt + 1);
    SYNC_PH();
    MFMA_Q(4, 0);
    RD_B(buf,2); RD_B(buf,3);
    if (kt + 2 < nk) STG_A(buf, 0, kt + 2);
    SYNC_PH();
    MFMA_Q(0, 2);
    if (kt + 2 < nk){
      STG_A(buf, 1, kt + 2);
      asm volatile("s_waitcnt vmcnt(4)" ::: "memory");
    } else {
      asm volatile("s_waitcnt vmcnt(0)" ::: "memory");
    }
    __builtin_amdgcn_s_barrier();
    MFMA_Q(4, 2);
  }
#undef STG_A
#undef STG_B
#undef RD_A
#undef RD_B
#undef SYNC_PH
#undef MFMA_Q

  float bv[4];
  #pragma unroll
  for (int n=0;n<4;n++){
    const int col = bcol + wcol*64 + n*16 + (lane & 15);
    bv[n] = bias ? bias[col] : 0.f;
  }
  ushort_t* sB = (ushort_t*)&lds[0][0][0][0];
  __syncthreads();
  #pragma unroll
  for (int m=0;m<8;m++){
    const int row = wrow*128 + m*16 + (lane >> 4)*4;
    #pragma unroll
    for (int n=0;n<4;n++){
      const int col = wcol*64 + n*16 + (lane & 15);
      #pragma unroll
      for (int j=0;j<4;j++){
        float v = acc[m][n][j] + bv[n];
        if (act) v = v > 0.f ? v : 0.f;
        sB[(row+j)*256 + col] = f2bf(v);
      }
    }
  }
  __syncthreads();
  const int srow = t >> 5, scol8 = (t & 31) * 8;
  #pragma unroll
  for (int rr = 0; rr < 16; ++rr){
    const int rloc = rr*16 + srow;
    const int grow = brow + rloc;
    if (grow < M)
      *(short8*)(out0 + (size_t)grow*Nn + bcol + scol8) = *(const short8*)&sB[rloc*256 + scol8];
  }
}

// ---- k4 mega kernel: scan (blk 0) + WcT tiny GEMM (blk 1-8) + GEMM1 --------
__global__ __launch_bounds__(512, 1) void mega_gemm(const ushort_t* __restrict__ xn,
                                                    const ushort_t* __restrict__ W1T,
                                                    const float* __restrict__ b1,
                                                    ushort_t* __restrict__ h1,
                                                    const ushort_t* __restrict__ WrgT,
                                                    const ushort_t* __restrict__ W2bf,
                                                    ushort_t* __restrict__ WcT,
                                                    const int* __restrict__ cnt,
                                                    int* __restrict__ offs,
                                                    int* __restrict__ cur){
  __shared__ __align__(16) ushort_t lds[2][2][2][64*128];  // 128 KiB
  const int t = threadIdx.x;

  if (blockIdx.x == 0){
    // CSR scan (256 active threads), hides under the GEMM
    int* sbuf = (int*)&lds[0][0][0][0];
    const int chunk = (NND + 255) >> 8;                  // 196, mult of 4
    int s = 0;
    if (t < 256){
      const int s0 = t*chunk;
      const int s1 = (s0 + chunk < NND) ? s0 + chunk : NND;
      for (int i = s0; i < s1; i += 4){
        int4v v = *(const int4v*)(cnt + i);
        s += v.x + v.y + v.z + v.w + 4;
      }
    }
    sbuf[t] = s; __syncthreads();
    for (int o = 1; o < 256; o <<= 1){
      int xv = (t >= o && t < 256) ? sbuf[t-o] : 0;
      __syncthreads();
      if (t < 256) sbuf[t] += xv;
      __syncthreads();
    }
    if (t < 256){
      int run = sbuf[t] - s;
      const int s0 = t*chunk;
      const int s1 = (s0 + chunk < NND) ? s0 + chunk : NND;
      for (int i = s0; i < s1; i += 4){
        int4v v = *(const int4v*)(cnt + i);
        int4v cu;
        cu.x = run; run += v.x + 1;
        cu.y = run; run += v.y + 1;
        cu.z = run; run += v.z + 1;
        cu.w = run; run += v.w + 1;
        *(int4v*)(cur + i)  = cu;
        *(int4v*)(offs + i) = cu;
      }
      if (t == 255) offs[NND] = run;
    }
    return;
  }
  if (blockIdx.x < 9){
    // WcT = (W2 @ [Wr|Wg])^T : M=512, Nn=1024, K=512 -> 8 blocks
    g256p8_body(lds, WrgT, W2bf, nullptr, WcT, 512, 1024, 512,
                (int)blockIdx.x - 1, 8, false);
    return;
  }
  g256p8_body(lds, xn, W1T, b1, h1, NND, DHID, DINP,
              (int)blockIdx.x - 9, (int)gridDim.x - 9, true);
}

// ------------- 256x256 2-phase bf16 MFMA GEMM (k5) --------------------------
#define G2_NWG 392
template<int ACT, int MODE, int CB, int EXTRA>
__global__ __launch_bounds__(512, 2) void gemm256(const ushort_t* __restrict__ A,
                                                  const ushort_t* __restrict__ BT,
                                                  const float* __restrict__ bias,
                                                  void* __restrict__ out0,
                                                  void* __restrict__ out1,
                                                  int M, int Nn, int K,
                                                  const int* __restrict__ ei,
                                                  int* __restrict__ cur,
                                                  int* __restrict__ eidx,
                                                  const float* __restrict__ att_s,
                                                  const float* __restrict__ att_d,
                                                  float* __restrict__ asrc,
                                                  float* __restrict__ adst){
  __shared__ __align__(16) ushort_t lds[2][2][256*64];   // 128 KiB
  const int t = threadIdx.x, wid = t >> 6, lane = t & 63;

  if (EXTRA == 1 && blockIdx.x >= G2_NWG){
    int i = (blockIdx.x - G2_NWG)*512 + t;
    if (i < NND){
      int p = atomicAdd(&cur[i], 1); eidx[p] = i;
    } else if (i < NND + NE){
      int e = i - NND;
      int src = ei[e], dst = ei[NE + e];
      int p = atomicAdd(&cur[dst], 1);
      eidx[p] = src;
    }
    return;
  }

  const int bid = blockIdx.x, nwg = G2_NWG;
  const int q = nwg >> 3, r = nwg & 7;
  const int xcd = bid & 7, slot = bid >> 3;
  const int lg = (xcd < r ? xcd*(q+1) : r*(q+1) + (xcd - r)*q) + slot;
  const int brow = (lg / CB) * 256, bcol = (lg % CB) * 256;

  const int l8  = t >> 3;
  const int cb  = (t & 7) << 4;
  const unsigned scb = (unsigned)(cb ^ ((l8 & 7) << 4));
  unsigned rowA[4], rowB[4];
  #pragma unroll
  for (int rd = 0; rd < 4; ++rd){
    int ra = brow + rd*64 + l8; ra = ra < M ? ra : M-1;
    int rb = bcol + rd*64 + l8; rb = rb < Nn ? rb : Nn-1;
    rowA[rd] = (unsigned)ra * (unsigned)(K*2);
    rowB[rd] = (unsigned)rb * (unsigned)(K*2);
  }
  const int wst = (wid * 8) * 64;

#define STAGE2(buf, kt) do {                                              \
    const unsigned _ob = (unsigned)(kt)*128u + scb;                       \
    _Pragma("unroll")                                                     \
    for (int _rd = 0; _rd < 4; ++_rd){                                    \
      async16((const char*)A  + rowA[_rd] + _ob, &lds[buf][0][_rd*64*64 + wst]); \
      async16((const char*)BT + rowB[_rd] + _ob, &lds[buf][1][_rd*64*64 + wst]); \
    }                                                                     \
  } while(0)

  f32x4 acc[8][4];
  #pragma unroll
  for (int i=0;i<8;i++)
    #pragma unroll
    for (int j=0;j<4;j++) acc[i][j] = (f32x4){0.f,0.f,0.f,0.f};

  const int wrow = (wid >> 2), wcol = (wid & 3);
  const int fr = lane & 15;
  const int kb0 = (lane >> 4) << 4;
  const int sx  = (fr & 7) << 4;
  const int ko0 = ((kb0      ) ^ sx) >> 1;
  const int ko1 = ((kb0 | 64 ) ^ sx) >> 1;

  const int nk = K >> 6;
  STAGE2(0, 0);
  STAGE2(1, 1);
  for (int kt = 0; kt < nk; ++kt){
    const ushort_t* bA = lds[kt & 1][0];
    const ushort_t* bB = lds[kt & 1][1];
    if (kt + 1 < nk) asm volatile("s_waitcnt vmcnt(8)" ::: "memory");
    else             asm volatile("s_waitcnt vmcnt(0)" ::: "memory");
    __builtin_amdgcn_s_barrier();
    short8 af[8][2], bf_[4][2];
    #pragma unroll
    for (int m=0;m<8;m++){
      const int ra = (wrow*128 + m*16 + fr)*64;
      af[m][0] = *(const short8*)&bA[ra + ko0];
      af[m][1] = *(const short8*)&bA[ra + ko1];
    }
    #pragma unroll
    for (int n=0;n<4;n++){
      const int rb = (wcol*64 + n*16 + fr)*64;
      bf_[n][0] = *(const short8*)&bB[rb + ko0];
      bf_[n][1] = *(const short8*)&bB[rb + ko1];
    }
    asm volatile("s_waitcnt lgkmcnt(0)" ::: "memory");
    __builtin_amdgcn_sched_barrier(0);
    __builtin_amdgcn_s_barrier();
    if (kt + 2 < nk) STAGE2(kt & 1, kt + 2);
    __builtin_amdgcn_s_setprio(1);
    #pragma unroll
    for (int m=0;m<8;m++)
      #pragma unroll
      for (int n=0;n<4;n++){
        acc[m][n] = __builtin_amdgcn_mfma_f32_16x16x32_bf16(af[m][0], bf_[n][0], acc[m][n], 0, 0, 0);
        acc[m][n] = __builtin_amdgcn_mfma_f32_16x16x32_bf16(af[m][1], bf_[n][1], acc[m][n], 0, 0, 0);
      }
    __builtin_amdgcn_s_setprio(0);
  }
#undef STAGE2

  const bool isf32 = (MODE == 0) || (MODE == 2 && bcol == 0);
  float bv[4];
  #pragma unroll
  for (int n=0;n<4;n++){
    const int col = bcol + wcol*64 + n*16 + (lane & 15);
    float b = 0.f;
    if (MODE == 1){ if (bias) b = bias[col]; }
    if (MODE == 2){ b = bias[col]; }
    bv[n] = b;
  }

  if (isf32){
    float* outF; int ostride, ocb;
    if (MODE == 0){ outF = (float*)out0; ostride = Nn;  ocb = bcol; }
    else          { outF = (float*)out0; ostride = 256; ocb = 0;    }
    float* sF = (float*)&lds[0][0][0];
    #pragma unroll
    for (int p = 0; p < 2; ++p){
      __syncthreads();
      if (wrow == p){
        #pragma unroll
        for (int m=0;m<8;m++){
          const int row = m*16 + (lane >> 4)*4;
          #pragma unroll
          for (int n=0;n<4;n++){
            const int col = wcol*64 + n*16 + (lane & 15);
            #pragma unroll
            for (int j=0;j<4;j++){
              float v = acc[m][n][j] + bv[n];
              if (ACT) v = v > 0.f ? v : 0.f;
              sF[(row+j)*256 + col] = v;
            }
          }
        }
      }
      __syncthreads();
      const int srow = t >> 6, scol4 = (t & 63) * 4;
      #pragma unroll
      for (int rr = 0; rr < 16; ++rr){
        const int rloc = rr*8 + srow;
        const int grow = brow + p*128 + rloc;
        if (grow < M)
          *(f32x4*)(outF + (size_t)grow*ostride + ocb + scol4) = *(const f32x4*)&sF[rloc*256 + scol4];
      }
    }
  } else {
    ushort_t* outB; int ostride, ocb;
    if (MODE == 1){ outB = (ushort_t*)out0; ostride = Nn;  ocb = bcol; }
    else          { outB = (ushort_t*)out1; ostride = 256; ocb = 0;    }
    ushort_t* sB = (ushort_t*)&lds[0][0][0];
    __syncthreads();
    #pragma unroll
    for (int m=0;m<8;m++){
      const int row = wrow*128 + m*16 + (lane >> 4)*4;
      #pragma unroll
      for (int n=0;n<4;n++){
        const int col = wcol*64 + n*16 + (lane & 15);
        #pragma unroll
        for (int j=0;j<4;j++){
          float v = acc[m][n][j] + bv[n];
          if (ACT) v = v > 0.f ? v : 0.f;
          sB[(row+j)*256 + col] = f2bf(v);
        }
      }
    }
    __syncthreads();
    const int srow = t >> 5, scol8 = (t & 31) * 8;
    #pragma unroll
    for (int rr = 0; rr < 16; ++rr){
      const int rloc = rr*16 + srow;
      const int grow = brow + rloc;
      if (grow < M)
        *(short8*)(outB + (size_t)grow*ostride + ocb + scol8) = *(const short8*)&sB[rloc*256 + scol8];
    }
    if (MODE == 2){
      const int h = t & 7;
      const int hc0 = h * 32;
      #pragma unroll
      for (int k = 0; k < 4; ++k){
        const int rloc = (t >> 3) + k*64;
        const int grow = brow + rloc;
        if (grow < M){
          float a = 0.f, d = 0.f;
          #pragma unroll
          for (int c0 = 0; c0 < 32; c0 += 8){
            short8 gv = *(const short8*)&sB[rloc*256 + hc0 + c0];
            #pragma unroll
            for (int j = 0; j < 8; ++j){
              float g = bf2f((ushort_t)gv[j]);
              a += g*att_s[hc0 + c0 + j];
              d += g*att_d[hc0 + c0 + j];
            }
          }
          asrc[grow*NHD + h] = a;
          adst[grow*NHD + h] = d;
        }
      }
    }
  }
}

// ---- fused GAT aggregate + elu + residual (wave/node, 8-edge chunks) ------
__global__ __launch_bounds__(256) void gat_agg(const int* __restrict__ offs,
                                               const int* __restrict__ eidx,
                                               const float* __restrict__ asrc,
                                               const float* __restrict__ adst,
                                               const ushort_t* __restrict__ gm,
                                               const float* __restrict__ res,
                                               const float* __restrict__ bg,
                                               float* __restrict__ out){
  const int wid = threadIdx.x >> 6, lane = threadIdx.x & 63;
  const int node = blockIdx.x*4 + wid;
  if (node >= NND) return;
  const int h = lane >> 3, jj = lane & 7;
  const int e0 = offs[node], deg = offs[node+1] - e0;
  const float adv = adst[node*NHD + h];

  float mx = -1e30f;
  for (int j = jj; j < deg; j += 8){
    int s = eidx[e0 + j];
    float e = asrc[s*NHD + h] + adv; e = e > 0.f ? e : 0.2f*e;
    mx = fmaxf(mx, e);
  }
  mx = fmaxf(mx, __shfl_xor(mx, 1));
  mx = fmaxf(mx, __shfl_xor(mx, 2));
  mx = fmaxf(mx, __shfl_xor(mx, 4));

  const int c4 = lane*4;
  float sm = 0.f;
  f32x4 acc = {0.f,0.f,0.f,0.f};
  for (int j0 = 0; j0 < deg; j0 += 8){
    const int cnt = (deg - j0) < 8 ? (deg - j0) : 8;
    int s = 0; float w = 0.f;
    if (jj < cnt){
      s = eidx[e0 + j0 + jj];
      float e = asrc[s*NHD + h] + adv; e = e > 0.f ? e : 0.2f*e;
      w = __expf(e - mx);
      sm += w;
    }
    #pragma unroll
    for (int u = 0; u < 8; ++u){
      if (u < cnt){
        const int   su = __builtin_amdgcn_readlane(s, u);
        const float wu = __shfl(w, (h << 3) | u);
        short4v gv = *(const short4v*)(gm + (size_t)su*DHC + c4);
        acc.x += wu*bf2f((ushort_t)gv.x);
        acc.y += wu*bf2f((ushort_t)gv.y);
        acc.z += wu*bf2f((ushort_t)gv.z);
        acc.w += wu*bf2f((ushort_t)gv.w);
      }
    }
  }
  sm += __shfl_xor(sm, 1); sm += __shfl_xor(sm, 2); sm += __shfl_xor(sm, 4);
  const float inv = 1.f/(sm + 1e-16f);

  f32x4 bgv = *(const f32x4*)(bg + c4);
  f32x4 rv  = *(const f32x4*)(res + (size_t)node*DHC + c4);
  f32x4 o;
  #pragma unroll
  for (int q = 0; q < 4; ++q){
    float v = acc[q]*inv + bgv[q];
    v = v > 0.f ? v : expm1f(v);
    o[q] = v + rv[q];
  }
  *(f32x4*)(out + (size_t)node*DHC + c4) = o;
}

extern "C" void kernel_launch(void* const* d_in, const int* in_sizes, int n_in,
                              void* d_out, int out_size, void* d_ws, size_t ws_size,
                              hipStream_t stream){
  (void)in_sizes; (void)n_in; (void)out_size; (void)ws_size;
  const float* x     = (const float*)d_in[0];
  const int*   ei    = (const int*)d_in[1];
  const float* ln_g  = (const float*)d_in[2];
  const float* ln_b  = (const float*)d_in[3];
  const float* W1    = (const float*)d_in[4];
  const float* b1    = (const float*)d_in[5];
  const float* W2    = (const float*)d_in[6];
  const float* b2    = (const float*)d_in[7];
  const float* Wr    = (const float*)d_in[8];
  const float* br    = (const float*)d_in[9];
  const float* Wg    = (const float*)d_in[10];
  const float* att_s = (const float*)d_in[11];
  const float* att_d = (const float*)d_in[12];
  const float* bg    = (const float*)d_in[13];
  float* out = (float*)d_out;

  char* p = (char*)d_ws;
  ushort_t* xn   = (ushort_t*)(p);                   // [0, 153,600,000)
  ushort_t* h1   = (ushort_t*)(p + 153600000);       // -> 256,000,000
  float*    asrc = (float*)(p + 256000000);
  float*    adst = (float*)(p + 257600000);
  int*      cnt  = (int*)(p + 259200000);
  int*      offs = (int*)(p + 259400064);
  int*      cur  = (int*)(p + 259600128);
  int*      eidx = (int*)(p + 259800192);            // -> 263,200,192
  ushort_t* W1T  = (ushort_t*)d_out;                           // 3,145,728
  ushort_t* WrgT = (ushort_t*)((char*)d_out + 3145728);        //   524,288
  ushort_t* W2bf = (ushort_t*)((char*)d_out + 3670016);        // 1,048,576
  ushort_t* WcT  = (ushort_t*)((char*)d_out + 4718592);        // 1,048,576
  float*    b2rg = (float*)((char*)d_out + 5767168);           //     2,048
  float*    res  = (float*)(p + 0);                  //  51,200,000 (f32)
  ushort_t* gm   = (ushort_t*)(p + 51200000);        //  25,600,000 (bf16)

  // k0: zero edge counters (DMA)
  hipMemsetAsync(cnt, 0, NND*sizeof(int), stream);

  // k1: fused LN + weight prep + count_edges
  fused1<<<F1_PREP + (NE + 255)/256, 256, 0, stream>>>(
      x, ln_g, ln_b, xn, ei, cnt,
      W1, Wr, Wg, W2, b2, br, W1T, WrgT, W2bf, b2rg);

  // k2: scan (blk 0) + WcT tiny GEMM (blk 1-8) + GEMM1 8-phase (784 blks)
  mega_gemm<<<793, 512, 0, stream>>>(xn, W1T, b1, h1, WrgT, W2bf, WcT,
                                     cnt, offs, cur);

  // k3: fused [res|gm] = h1 @ WcT^T + b2rg  (split epilogue + att + fill)
  gemm256<0,2,2,1><<<G2_NWG + (NND + NE + 511)/512, 512, 0, stream>>>(
      h1, WcT, b2rg, res, gm, NND, 2*DHC, DHID,
      ei, cur, eidx, att_s, att_d, asrc, adst);

  // k4: GAT aggregate
  gat_agg<<<(NND + 3)/4, 256, 0, stream>>>(offs, eidx, asrc, adst, gm, res, bg, out);
}

// Round 15
// 489.620 us; speedup vs baseline: 1.5841x; 1.0388x over previous
//
#include <hip/hip_runtime.h>
#include <hip/hip_bf16.h>
#include <cstdint>
#include <cstddef>

#define NND 50000
#define DIN 1488
#define DINP 1536
#define DHID 1024
#define DOUT 512
#define DHC 256
#define NE 800000
#define NHD 8
#define SPLITC 256

typedef __attribute__((ext_vector_type(8))) short short8;
typedef __attribute__((ext_vector_type(4))) short short4v;
typedef __attribute__((ext_vector_type(4))) float f32x4;
typedef __attribute__((ext_vector_type(4))) int int4v;
typedef unsigned short ushort_t;

__device__ __forceinline__ unsigned short f2bf(float f){
  union { float f; unsigned u; } v; v.f = f;
  unsigned r = v.u + 0x7fffu + ((v.u >> 16) & 1u);
  return (unsigned short)(r >> 16);
}
__device__ __forceinline__ float bf2f(unsigned short u){
  union { unsigned u; float f; } v; v.u = ((unsigned)u) << 16;
  return v.f;
}

__device__ __forceinline__ void async16(const void* g, void* l){
  __builtin_amdgcn_global_load_lds((__attribute__((address_space(1))) void*)g,
                                   (__attribute__((address_space(3))) void*)l, 16, 0, 0);
}

// ---- fused stage 1: count_edges + LN (reg-resident, 1 pass) + weight prep --
__device__ __forceinline__ void tc_tile(const float* __restrict__ W,
                                        ushort_t* __restrict__ WT,
                                        int K, int Nn, int Kp, int bx, int by){
  __shared__ float tile[32][33];
  const int tx = threadIdx.x & 31, ty = threadIdx.x >> 5;
  const int k0 = bx*32, n0 = by*32;
  for (int i = ty; i < 32; i += 8){
    int k = k0 + i, n = n0 + tx;
    tile[i][tx] = (k < K && n < Nn) ? W[(size_t)k*Nn + n] : 0.f;
  }
  __syncthreads();
  for (int i = ty; i < 32; i += 8){
    int n = n0 + i, k = k0 + tx;
    if (n < Nn && k < Kp) WT[(size_t)n*Kp + k] = f2bf(tile[tx][i]);
  }
}

#define F1_CNT  3125
#define F1_LN   (F1_CNT + 12500)
__global__ __launch_bounds__(256) void fused1(const float* __restrict__ x,
                                              const float* __restrict__ gw,
                                              const float* __restrict__ bw,
                                              ushort_t* __restrict__ xn,
                                              const int* __restrict__ ei,
                                              int* __restrict__ cnt,
                                              const float* W1, const float* Wr,
                                              const float* Wg, const float* W2,
                                              const float* b2, const float* br,
                                              ushort_t* W1T, ushort_t* WrgT,
                                              ushort_t* W2bf, float* b2rg){
  const int bid = blockIdx.x;
  if (bid < F1_CNT){
    int e = bid*256 + threadIdx.x;
    if (e < NE) atomicAdd(&cnt[ei[NE + e]], 1);
    return;
  }
  if (bid < F1_LN){
    const int wid = threadIdx.x >> 6, lane = threadIdx.x & 63;
    const int row = (bid - F1_CNT)*4 + wid;
    if (row >= NND) return;
    const float* xr = x + (size_t)row * DIN;
    // single pass: row slice held in registers (6 x f32x4 per lane)
    f32x4 xv[6];
    float s = 0.f, sq = 0.f;
    #pragma unroll
    for (int it = 0; it < 6; ++it){
      const int i = lane*4 + it*256;
      xv[it] = (i < DIN) ? *(const f32x4*)(xr + i) : (f32x4){0.f,0.f,0.f,0.f};
      s  += xv[it].x + xv[it].y + xv[it].z + xv[it].w;
      sq += xv[it].x*xv[it].x + xv[it].y*xv[it].y + xv[it].z*xv[it].z + xv[it].w*xv[it].w;
    }
    #pragma unroll
    for (int o = 32; o; o >>= 1){ s += __shfl_xor(s, o); sq += __shfl_xor(sq, o); }
    const float mu = s * (1.f/DIN);
    const float var = sq * (1.f/DIN) - mu*mu;
    const float rstd = rsqrtf(var + 1e-5f);
    ushort_t* xo = xn + (size_t)row * DINP;
    #pragma unroll
    for (int it = 0; it < 6; ++it){
      const int i = lane*4 + it*256;
      if (i < DIN){
        f32x4 gg = *(const f32x4*)(gw + i);
        f32x4 bb = *(const f32x4*)(bw + i);
        union { ushort_t u[4]; unsigned long long q; } o;
        o.u[0] = f2bf((xv[it].x-mu)*rstd*gg.x + bb.x);
        o.u[1] = f2bf((xv[it].y-mu)*rstd*gg.y + bb.y);
        o.u[2] = f2bf((xv[it].z-mu)*rstd*gg.z + bb.z);
        o.u[3] = f2bf((xv[it].w-mu)*rstd*gg.w + bb.w);
        *(unsigned long long*)(xo + i) = o.q;
      }
    }
    if (lane < (DINP - DIN)) xo[DIN + lane] = 0;
    return;
  }
  {
    int b = bid - F1_LN;
    if (b < 1536){ tc_tile(W1, W1T, DIN, DHID, DINP, b % 48, b / 48); return; }
    b -= 1536;
    if (b < 128){ tc_tile(Wr, WrgT, DOUT, DHC, DOUT, b % 16, b / 16); return; }
    b -= 128;
    if (b < 128){ tc_tile(Wg, WrgT + 256*DOUT, DOUT, DHC, DOUT, b % 16, b / 16); return; }
    b -= 128;
    if (b < 256){                                 // W2 fp32 -> bf16 cast
      const int idx = (b*256 + threadIdx.x)*8;
      f32x4 v0 = *(const f32x4*)(W2 + idx);
      f32x4 v1 = *(const f32x4*)(W2 + idx + 4);
      union { ushort_t u[8]; short8 s; } o;
      o.u[0]=f2bf(v0.x); o.u[1]=f2bf(v0.y); o.u[2]=f2bf(v0.z); o.u[3]=f2bf(v0.w);
      o.u[4]=f2bf(v1.x); o.u[5]=f2bf(v1.y); o.u[6]=f2bf(v1.z); o.u[7]=f2bf(v1.w);
      *(short8*)(W2bf + idx) = o.s;
      return;
    }
    b -= 256;
    {                                             // b2rg fold (2 blocks)
      const int c = b*256 + threadIdx.x;
      float acc = 0.f;
      if (c < 256){
        for (int j = 0; j < DOUT; ++j) acc += b2[j]*Wr[(size_t)j*DHC + c];
        acc += br[c];
      } else {
        const int cc = c - 256;
        for (int j = 0; j < DOUT; ++j) acc += b2[j]*Wg[(size_t)j*DHC + cc];
      }
      b2rg[c] = acc;
      return;
    }
  }
}

// ------- 256x256 8-phase GEMM body (device fn; runtime act) -----------------
__device__ __forceinline__ void g256p8_body(ushort_t (&lds)[2][2][2][64*128],
                                            const ushort_t* __restrict__ A,
                                            const ushort_t* __restrict__ BT,
                                            const float* __restrict__ bias,
                                            ushort_t* __restrict__ out0,
                                            int M, int Nn, int K,
                                            int bid, int nwg, bool act){
  const int t = threadIdx.x, wid = t >> 6, lane = t & 63;
  const int CB = Nn >> 8;
  const int q = nwg >> 3, r = nwg & 7;
  const int xcd = bid & 7, slot = bid >> 3;
  const int lg = (xcd < r ? xcd*(q+1) : r*(q+1) + (xcd - r)*q) + slot;
  const int brow = (lg / CB) * 256, bcol = (lg % CB) * 256;

  const int l8  = t >> 3;
  const int cb  = (t & 7) << 4;
  const unsigned scb = (unsigned)(cb ^ ((l8 & 7) << 4));
  unsigned rowA[2][2], rowB[2][2];
  #pragma unroll
  for (int hf = 0; hf < 2; ++hf)
    #pragma unroll
    for (int rd = 0; rd < 2; ++rd){
      int ra = brow + hf*128 + rd*64 + l8; ra = ra < M ? ra : M-1;
      int rb = bcol + hf*128 + rd*64 + l8; rb = rb < Nn ? rb : Nn-1;
      rowA[hf][rd] = (unsigned)ra * (unsigned)(K*2);
      rowB[hf][rd] = (unsigned)rb * (unsigned)(K*2);
    }
  const int w8 = wid * 8;

#define STG_A(buf, hf, kt) do {                                               \
    const unsigned _ob = (unsigned)(kt)*128u + scb;                           \
    async16((const char*)A + rowA[hf][0] + _ob, &lds[buf][0][hf][(w8)*64]);   \
    async16((const char*)A + rowA[hf][1] + _ob, &lds[buf][0][hf][(64+w8)*64]);\
  } while(0)
#define STG_B(buf, hf, kt) do {                                               \
    const unsigned _ob = (unsigned)(kt)*128u + scb;                           \
    async16((const char*)BT + rowB[hf][0] + _ob, &lds[buf][1][hf][(w8)*64]);  \
    async16((const char*)BT + rowB[hf][1] + _ob, &lds[buf][1][hf][(64+w8)*64]);\
  } while(0)

  f32x4 acc[8][4];
  #pragma unroll
  for (int i=0;i<8;i++)
    #pragma unroll
    for (int j=0;j<4;j++) acc[i][j] = (f32x4){0.f,0.f,0.f,0.f};

  const int wrow = (wid >> 2), wcol = (wid & 3);
  const int fr = lane & 15;
  const int kb0 = (lane >> 4) << 4;
  const int sx  = (fr & 7) << 4;
  const int ko0 = ((kb0      ) ^ sx) >> 1;
  const int ko1 = ((kb0 | 64 ) ^ sx) >> 1;
  const int bhalf = wcol >> 1, brl = (wcol & 1)*64;

#define RD_A(buf, m) do {                                          \
    const int _ra = ((m)*16 + fr)*64;                              \
    af[m][0] = *(const short8*)&lds[buf][0][wrow][_ra + ko0];      \
    af[m][1] = *(const short8*)&lds[buf][0][wrow][_ra + ko1];      \
  } while(0)
#define RD_B(buf, n) do {                                          \
    const int _rb = (brl + (n)*16 + fr)*64;                        \
    bf[n][0] = *(const short8*)&lds[buf][1][bhalf][_rb + ko0];     \
    bf[n][1] = *(const short8*)&lds[buf][1][bhalf][_rb + ko1];     \
  } while(0)
#define SYNC_PH() do {                                             \
    __builtin_amdgcn_s_barrier();                                  \
    asm volatile("s_waitcnt lgkmcnt(0)" ::: "memory");             \
    __builtin_amdgcn_sched_barrier(0);                             \
  } while(0)
#define MFMA_Q(M0, N0) do {                                        \
    __builtin_amdgcn_s_setprio(1);                                 \
    _Pragma("unroll")                                              \
    for (int _m=(M0); _m<(M0)+4; ++_m)                             \
      _Pragma("unroll")                                            \
      for (int _n=(N0); _n<(N0)+2; ++_n){                          \
        acc[_m][_n] = __builtin_amdgcn_mfma_f32_16x16x32_bf16(af[_m][0], bf[_n][0], acc[_m][_n], 0, 0, 0); \
        acc[_m][_n] = __builtin_amdgcn_mfma_f32_16x16x32_bf16(af[_m][1], bf[_n][1], acc[_m][_n], 0, 0, 0); \
      }                                                            \
    __builtin_amdgcn_s_setprio(0);                                 \
  } while(0)

  const int nk = K >> 6;
  STG_A(0,0,0); STG_A(0,1,0); STG_B(0,0,0); STG_B(0,1,0);
  STG_A(1,0,1); STG_A(1,1,1);
  asm volatile("s_waitcnt vmcnt(4)" ::: "memory");
  __builtin_amdgcn_s_barrier();

  for (int kt = 0; kt < nk; ++kt){
    const int buf = kt & 1, obuf = buf ^ 1;
    short8 af[8][2], bf[4][2];
    RD_A(buf,0); RD_A(buf,1); RD_A(buf,2); RD_A(buf,3);
    RD_B(buf,0); RD_B(buf,1);
    if (kt + 1 < nk) STG_B(obuf, 0, kt + 1);
    SYNC_PH();
    MFMA_Q(0, 0);
    RD_A(buf,4); RD_A(buf,5); RD_A(buf,6); RD_A(buf,7);
    if (kt + 1 < nk) STG_B(obuf, 1, kt + 1);
    SYNC_PH();
    MFMA_Q(4, 0);
    RD_B(buf,2); RD_B(buf,3);
    if (kt + 2 < nk) STG_A(buf, 0, kt + 2);
    SYNC_PH();
    MFMA_Q(0, 2);
    if (kt + 2 < nk){
      STG_A(buf, 1, kt + 2);
      asm volatile("s_waitcnt vmcnt(4)" ::: "memory");
    } else {
      asm volatile("s_waitcnt vmcnt(0)" ::: "memory");
    }
    __builtin_amdgcn_s_barrier();
    MFMA_Q(4, 2);
  }
#undef STG_A
#undef STG_B
#undef RD_A
#undef RD_B
#undef SYNC_PH
#undef MFMA_Q

  float bv[4];
  #pragma unroll
  for (int n=0;n<4;n++){
    const int col = bcol + wcol*64 + n*16 + (lane & 15);
    bv[n] = bias ? bias[col] : 0.f;
  }
  ushort_t* sB = (ushort_t*)&lds[0][0][0][0];
  __syncthreads();
  #pragma unroll
  for (int m=0;m<8;m++){
    const int row = wrow*128 + m*16 + (lane >> 4)*4;
    #pragma unroll
    for (int n=0;n<4;n++){
      const int col = wcol*64 + n*16 + (lane & 15);
      #pragma unroll
      for (int j=0;j<4;j++){
        float v = acc[m][n][j] + bv[n];
        if (act) v = v > 0.f ? v : 0.f;
        sB[(row+j)*256 + col] = f2bf(v);
      }
    }
  }
  __syncthreads();
  const int srow = t >> 5, scol8 = (t & 31) * 8;
  #pragma unroll
  for (int rr = 0; rr < 16; ++rr){
    const int rloc = rr*16 + srow;
    const int grow = brow + rloc;
    if (grow < M)
      *(short8*)(out0 + (size_t)grow*Nn + bcol + scol8) = *(const short8*)&sB[rloc*256 + scol8];
  }
}

// ---- k2 mega kernel: scan (blk 0) + WcT tiny GEMM (blk 1-8) + GEMM1 --------
__global__ __launch_bounds__(512, 1) void mega_gemm(const ushort_t* __restrict__ xn,
                                                    const ushort_t* __restrict__ W1T,
                                                    const float* __restrict__ b1,
                                                    ushort_t* __restrict__ h1,
                                                    const ushort_t* __restrict__ WrgT,
                                                    const ushort_t* __restrict__ W2bf,
                                                    ushort_t* __restrict__ WcT,
                                                    const int* __restrict__ cnt,
                                                    int* __restrict__ offs,
                                                    int* __restrict__ cur){
  __shared__ __align__(16) ushort_t lds[2][2][2][64*128];  // 128 KiB
  const int t = threadIdx.x;

  if (blockIdx.x == 0){
    int* sbuf = (int*)&lds[0][0][0][0];
    const int chunk = (NND + 255) >> 8;                  // 196, mult of 4
    int s = 0;
    if (t < 256){
      const int s0 = t*chunk;
      const int s1 = (s0 + chunk < NND) ? s0 + chunk : NND;
      for (int i = s0; i < s1; i += 4){
        int4v v = *(const int4v*)(cnt + i);
        s += v.x + v.y + v.z + v.w + 4;
      }
    }
    sbuf[t] = s; __syncthreads();
    for (int o = 1; o < 256; o <<= 1){
      int xv = (t >= o && t < 256) ? sbuf[t-o] : 0;
      __syncthreads();
      if (t < 256) sbuf[t] += xv;
      __syncthreads();
    }
    if (t < 256){
      int run = sbuf[t] - s;
      const int s0 = t*chunk;
      const int s1 = (s0 + chunk < NND) ? s0 + chunk : NND;
      for (int i = s0; i < s1; i += 4){
        int4v v = *(const int4v*)(cnt + i);
        int4v cu;
        cu.x = run; run += v.x + 1;
        cu.y = run; run += v.y + 1;
        cu.z = run; run += v.z + 1;
        cu.w = run; run += v.w + 1;
        *(int4v*)(cur + i)  = cu;
        *(int4v*)(offs + i) = cu;
      }
      if (t == 255) offs[NND] = run;
    }
    return;
  }
  if (blockIdx.x < 9){
    g256p8_body(lds, WrgT, W2bf, nullptr, WcT, 512, 1024, 512,
                (int)blockIdx.x - 1, 8, false);
    return;
  }
  g256p8_body(lds, xn, W1T, b1, h1, NND, DHID, DINP,
              (int)blockIdx.x - 9, (int)gridDim.x - 9, true);
}

// ------------- 256x256 2-phase bf16 MFMA GEMM (k3) --------------------------
#define G2_NWG 392
template<int ACT, int MODE, int CB, int EXTRA>
__global__ __launch_bounds__(512, 2) void gemm256(const ushort_t* __restrict__ A,
                                                  const ushort_t* __restrict__ BT,
                                                  const float* __restrict__ bias,
                                                  void* __restrict__ out0,
                                                  void* __restrict__ out1,
                                                  int M, int Nn, int K,
                                                  const int* __restrict__ ei,
                                                  int* __restrict__ cur,
                                                  int* __restrict__ eidx,
                                                  const float* __restrict__ att_s,
                                                  const float* __restrict__ att_d,
                                                  float* __restrict__ asrc,
                                                  float* __restrict__ adst){
  __shared__ __align__(16) ushort_t lds[2][2][256*64];   // 128 KiB
  const int t = threadIdx.x, wid = t >> 6, lane = t & 63;

  if (EXTRA == 1 && blockIdx.x >= G2_NWG){
    int i = (blockIdx.x - G2_NWG)*512 + t;
    if (i < NND){
      int p = atomicAdd(&cur[i], 1); eidx[p] = i;
    } else if (i < NND + NE){
      int e = i - NND;
      int src = ei[e], dst = ei[NE + e];
      int p = atomicAdd(&cur[dst], 1);
      eidx[p] = src;
    }
    return;
  }

  const int bid = blockIdx.x, nwg = G2_NWG;
  const int q = nwg >> 3, r = nwg & 7;
  const int xcd = bid & 7, slot = bid >> 3;
  const int lg = (xcd < r ? xcd*(q+1) : r*(q+1) + (xcd - r)*q) + slot;
  const int brow = (lg / CB) * 256, bcol = (lg % CB) * 256;

  const int l8  = t >> 3;
  const int cb  = (t & 7) << 4;
  const unsigned scb = (unsigned)(cb ^ ((l8 & 7) << 4));
  unsigned rowA[4], rowB[4];
  #pragma unroll
  for (int rd = 0; rd < 4; ++rd){
    int ra = brow + rd*64 + l8; ra = ra < M ? ra : M-1;
    int rb = bcol + rd*64 + l8; rb = rb < Nn ? rb : Nn-1;
    rowA[rd] = (unsigned)ra * (unsigned)(K*2);
    rowB[rd] = (unsigned)rb * (unsigned)(K*2);
  }
  const int wst = (wid * 8) * 64;

#define STAGE2(buf, kt) do {                                              \
    const unsigned _ob = (unsigned)(kt)*128u + scb;                       \
    _Pragma("unroll")                                                     \
    for (int _rd = 0; _rd < 4; ++_rd){                                    \
      async16((const char*)A  + rowA[_rd] + _ob, &lds[buf][0][_rd*64*64 + wst]); \
      async16((const char*)BT + rowB[_rd] + _ob, &lds[buf][1][_rd*64*64 + wst]); \
    }                                                                     \
  } while(0)

  f32x4 acc[8][4];
  #pragma unroll
  for (int i=0;i<8;i++)
    #pragma unroll
    for (int j=0;j<4;j++) acc[i][j] = (f32x4){0.f,0.f,0.f,0.f};

  const int wrow = (wid >> 2), wcol = (wid & 3);
  const int fr = lane & 15;
  const int kb0 = (lane >> 4) << 4;
  const int sx  = (fr & 7) << 4;
  const int ko0 = ((kb0      ) ^ sx) >> 1;
  const int ko1 = ((kb0 | 64 ) ^ sx) >> 1;

  const int nk = K >> 6;
  STAGE2(0, 0);
  STAGE2(1, 1);
  for (int kt = 0; kt < nk; ++kt){
    const ushort_t* bA = lds[kt & 1][0];
    const ushort_t* bB = lds[kt & 1][1];
    if (kt + 1 < nk) asm volatile("s_waitcnt vmcnt(8)" ::: "memory");
    else             asm volatile("s_waitcnt vmcnt(0)" ::: "memory");
    __builtin_amdgcn_s_barrier();
    short8 af[8][2], bf_[4][2];
    #pragma unroll
    for (int m=0;m<8;m++){
      const int ra = (wrow*128 + m*16 + fr)*64;
      af[m][0] = *(const short8*)&bA[ra + ko0];
      af[m][1] = *(const short8*)&bA[ra + ko1];
    }
    #pragma unroll
    for (int n=0;n<4;n++){
      const int rb = (wcol*64 + n*16 + fr)*64;
      bf_[n][0] = *(const short8*)&bB[rb + ko0];
      bf_[n][1] = *(const short8*)&bB[rb + ko1];
    }
    asm volatile("s_waitcnt lgkmcnt(0)" ::: "memory");
    __builtin_amdgcn_sched_barrier(0);
    __builtin_amdgcn_s_barrier();
    if (kt + 2 < nk) STAGE2(kt & 1, kt + 2);
    __builtin_amdgcn_s_setprio(1);
    #pragma unroll
    for (int m=0;m<8;m++)
      #pragma unroll
      for (int n=0;n<4;n++){
        acc[m][n] = __builtin_amdgcn_mfma_f32_16x16x32_bf16(af[m][0], bf_[n][0], acc[m][n], 0, 0, 0);
        acc[m][n] = __builtin_amdgcn_mfma_f32_16x16x32_bf16(af[m][1], bf_[n][1], acc[m][n], 0, 0, 0);
      }
    __builtin_amdgcn_s_setprio(0);
  }
#undef STAGE2

  const bool isf32 = (MODE == 0) || (MODE == 2 && bcol == 0);
  float bv[4];
  #pragma unroll
  for (int n=0;n<4;n++){
    const int col = bcol + wcol*64 + n*16 + (lane & 15);
    float b = 0.f;
    if (MODE == 1){ if (bias) b = bias[col]; }
    if (MODE == 2){ b = bias[col]; }
    bv[n] = b;
  }

  if (isf32){
    float* outF; int ostride, ocb;
    if (MODE == 0){ outF = (float*)out0; ostride = Nn;  ocb = bcol; }
    else          { outF = (float*)out0; ostride = 256; ocb = 0;    }
    float* sF = (float*)&lds[0][0][0];
    #pragma unroll
    for (int p = 0; p < 2; ++p){
      __syncthreads();
      if (wrow == p){
        #pragma unroll
        for (int m=0;m<8;m++){
          const int row = m*16 + (lane >> 4)*4;
          #pragma unroll
          for (int n=0;n<4;n++){
            const int col = wcol*64 + n*16 + (lane & 15);
            #pragma unroll
            for (int j=0;j<4;j++){
              float v = acc[m][n][j] + bv[n];
              if (ACT) v = v > 0.f ? v : 0.f;
              sF[(row+j)*256 + col] = v;
            }
          }
        }
      }
      __syncthreads();
      const int srow = t >> 6, scol4 = (t & 63) * 4;
      #pragma unroll
      for (int rr = 0; rr < 16; ++rr){
        const int rloc = rr*8 + srow;
        const int grow = brow + p*128 + rloc;
        if (grow < M)
          *(f32x4*)(outF + (size_t)grow*ostride + ocb + scol4) = *(const f32x4*)&sF[rloc*256 + scol4];
      }
    }
  } else {
    ushort_t* outB; int ostride, ocb;
    if (MODE == 1){ outB = (ushort_t*)out0; ostride = Nn;  ocb = bcol; }
    else          { outB = (ushort_t*)out1; ostride = 256; ocb = 0;    }
    ushort_t* sB = (ushort_t*)&lds[0][0][0];
    __syncthreads();
    #pragma unroll
    for (int m=0;m<8;m++){
      const int row = wrow*128 + m*16 + (lane >> 4)*4;
      #pragma unroll
      for (int n=0;n<4;n++){
        const int col = wcol*64 + n*16 + (lane & 15);
        #pragma unroll
        for (int j=0;j<4;j++){
          float v = acc[m][n][j] + bv[n];
          if (ACT) v = v > 0.f ? v : 0.f;
          sB[(row+j)*256 + col] = f2bf(v);
        }
      }
    }
    __syncthreads();
    const int srow = t >> 5, scol8 = (t & 31) * 8;
    #pragma unroll
    for (int rr = 0; rr < 16; ++rr){
      const int rloc = rr*16 + srow;
      const int grow = brow + rloc;
      if (grow < M)
        *(short8*)(outB + (size_t)grow*ostride + ocb + scol8) = *(const short8*)&sB[rloc*256 + scol8];
    }
    if (MODE == 2){
      const int h = t & 7;
      const int hc0 = h * 32;
      #pragma unroll
      for (int k = 0; k < 4; ++k){
        const int rloc = (t >> 3) + k*64;
        const int grow = brow + rloc;
        if (grow < M){
          float a = 0.f, d = 0.f;
          #pragma unroll
          for (int c0 = 0; c0 < 32; c0 += 8){
            short8 gv = *(const short8*)&sB[rloc*256 + hc0 + c0];
            #pragma unroll
            for (int j = 0; j < 8; ++j){
              float g = bf2f((ushort_t)gv[j]);
              a += g*att_s[hc0 + c0 + j];
              d += g*att_d[hc0 + c0 + j];
            }
          }
          asrc[grow*NHD + h] = a;
          adst[grow*NHD + h] = d;
        }
      }
    }
  }
}

// ---- fused GAT aggregate + elu + residual (wave/node, 8-edge chunks) ------
__global__ __launch_bounds__(256) void gat_agg(const int* __restrict__ offs,
                                               const int* __restrict__ eidx,
                                               const float* __restrict__ asrc,
                                               const float* __restrict__ adst,
                                               const ushort_t* __restrict__ gm,
                                               const float* __restrict__ res,
                                               const float* __restrict__ bg,
                                               float* __restrict__ out){
  const int wid = threadIdx.x >> 6, lane = threadIdx.x & 63;
  const int node = blockIdx.x*4 + wid;
  if (node >= NND) return;
  const int h = lane >> 3, jj = lane & 7;
  const int e0 = offs[node], deg = offs[node+1] - e0;
  const float adv = adst[node*NHD + h];

  float mx = -1e30f;
  for (int j = jj; j < deg; j += 8){
    int s = eidx[e0 + j];
    float e = asrc[s*NHD + h] + adv; e = e > 0.f ? e : 0.2f*e;
    mx = fmaxf(mx, e);
  }
  mx = fmaxf(mx, __shfl_xor(mx, 1));
  mx = fmaxf(mx, __shfl_xor(mx, 2));
  mx = fmaxf(mx, __shfl_xor(mx, 4));

  const int c4 = lane*4;
  float sm = 0.f;
  f32x4 acc = {0.f,0.f,0.f,0.f};
  for (int j0 = 0; j0 < deg; j0 += 8){
    const int cnt = (deg - j0) < 8 ? (deg - j0) : 8;
    int s = 0; float w = 0.f;
    if (jj < cnt){
      s = eidx[e0 + j0 + jj];
      float e = asrc[s*NHD + h] + adv; e = e > 0.f ? e : 0.2f*e;
      w = __expf(e - mx);
      sm += w;
    }
    #pragma unroll
    for (int u = 0; u < 8; ++u){
      if (u < cnt){
        const int   su = __builtin_amdgcn_readlane(s, u);
        const float wu = __shfl(w, (h << 3) | u);
        short4v gv = *(const short4v*)(gm + (size_t)su*DHC + c4);
        acc.x += wu*bf2f((ushort_t)gv.x);
        acc.y += wu*bf2f((ushort_t)gv.y);
        acc.z += wu*bf2f((ushort_t)gv.z);
        acc.w += wu*bf2f((ushort_t)gv.w);
      }
    }
  }
  sm += __shfl_xor(sm, 1); sm += __shfl_xor(sm, 2); sm += __shfl_xor(sm, 4);
  const float inv = 1.f/(sm + 1e-16f);

  f32x4 bgv = *(const f32x4*)(bg + c4);
  f32x4 rv  = *(const f32x4*)(res + (size_t)node*DHC + c4);
  f32x4 o;
  #pragma unroll
  for (int q = 0; q < 4; ++q){
    float v = acc[q]*inv + bgv[q];
    v = v > 0.f ? v : expm1f(v);
    o[q] = v + rv[q];
  }
  *(f32x4*)(out + (size_t)node*DHC + c4) = o;
}

extern "C" void kernel_launch(void* const* d_in, const int* in_sizes, int n_in,
                              void* d_out, int out_size, void* d_ws, size_t ws_size,
                              hipStream_t stream){
  (void)in_sizes; (void)n_in; (void)out_size; (void)ws_size;
  const float* x     = (const float*)d_in[0];
  const int*   ei    = (const int*)d_in[1];
  const float* ln_g  = (const float*)d_in[2];
  const float* ln_b  = (const float*)d_in[3];
  const float* W1    = (const float*)d_in[4];
  const float* b1    = (const float*)d_in[5];
  const float* W2    = (const float*)d_in[6];
  const float* b2    = (const float*)d_in[7];
  const float* Wr    = (const float*)d_in[8];
  const float* br    = (const float*)d_in[9];
  const float* Wg    = (const float*)d_in[10];
  const float* att_s = (const float*)d_in[11];
  const float* att_d = (const float*)d_in[12];
  const float* bg    = (const float*)d_in[13];
  float* out = (float*)d_out;

  char* p = (char*)d_ws;
  ushort_t* xn   = (ushort_t*)(p);                   // [0, 153,600,000)
  ushort_t* h1   = (ushort_t*)(p + 153600000);       // -> 256,000,000
  float*    asrc = (float*)(p + 256000000);
  float*    adst = (float*)(p + 257600000);
  int*      cnt  = (int*)(p + 259200000);
  int*      offs = (int*)(p + 259400064);
  int*      cur  = (int*)(p + 259600128);
  int*      eidx = (int*)(p + 259800192);            // -> 263,200,192
  ushort_t* W1T  = (ushort_t*)d_out;                           // 3,145,728
  ushort_t* WrgT = (ushort_t*)((char*)d_out + 3145728);        //   524,288
  ushort_t* W2bf = (ushort_t*)((char*)d_out + 3670016);        // 1,048,576
  ushort_t* WcT  = (ushort_t*)((char*)d_out + 4718592);        // 1,048,576
  float*    b2rg = (float*)((char*)d_out + 5767168);           //     2,048
  float*    res  = (float*)(p + 0);                  //  51,200,000 (f32)
  ushort_t* gm   = (ushort_t*)(p + 51200000);        //  25,600,000 (bf16)

  // k0: zero edge counters (DMA)
  hipMemsetAsync(cnt, 0, NND*sizeof(int), stream);

  // k1: fused count_edges + LN (1-pass, reg-resident) + weight prep
  fused1<<<F1_LN + 2050, 256, 0, stream>>>(
      x, ln_g, ln_b, xn, ei, cnt,
      W1, Wr, Wg, W2, b2, br, W1T, WrgT, W2bf, b2rg);

  // k2: scan (blk 0) + WcT tiny GEMM (blk 1-8) + GEMM1 8-phase (784 blks)
  mega_gemm<<<793, 512, 0, stream>>>(xn, W1T, b1, h1, WrgT, W2bf, WcT,
                                     cnt, offs, cur);

  // k3: fused [res|gm] = h1 @ WcT^T + b2rg  (split epilogue + att + fill)
  gemm256<0,2,2,1><<<G2_NWG + (NND + NE + 511)/512, 512, 0, stream>>>(
      h1, WcT, b2rg, res, gm, NND, 2*DHC, DHID,
      ei, cur, eidx, att_s, att_d, asrc, adst);

  // k4: GAT aggregate
  gat_agg<<<(NND + 3)/4, 256, 0, stream>>>(offs, eidx, asrc, adst, gm, res, bg, out);
}

// Round 16
// 481.788 us; speedup vs baseline: 1.6099x; 1.0163x over previous
//
#include <hip/hip_runtime.h>
#include <hip/hip_bf16.h>
#include <cstdint>
#include <cstddef>

#define NND 50000
#define DIN 1488
#define DINP 1536
#define DHID 1024
#define DOUT 512
#define DHC 256
#define NE 800000
#define NHD 8

typedef __attribute__((ext_vector_type(8))) short short8;
typedef __attribute__((ext_vector_type(4))) short short4v;
typedef __attribute__((ext_vector_type(4))) float f32x4;
typedef __attribute__((ext_vector_type(4))) int int4v;
typedef unsigned short ushort_t;

__device__ __forceinline__ unsigned short f2bf(float f){
  union { float f; unsigned u; } v; v.f = f;
  unsigned r = v.u + 0x7fffu + ((v.u >> 16) & 1u);
  return (unsigned short)(r >> 16);
}
__device__ __forceinline__ float bf2f(unsigned short u){
  union { unsigned u; float f; } v; v.u = ((unsigned)u) << 16;
  return v.f;
}

__device__ __forceinline__ void async16(const void* g, void* l){
  __builtin_amdgcn_global_load_lds((__attribute__((address_space(1))) void*)g,
                                   (__attribute__((address_space(3))) void*)l, 16, 0, 0);
}

// ---- fused stage 1: count_edges + LN (1-pass, 16B stores) + weight prep ----
__device__ __forceinline__ void tc_tile(const float* __restrict__ W,
                                        ushort_t* __restrict__ WT,
                                        int K, int Nn, int Kp, int bx, int by){
  __shared__ float tile[32][33];
  const int tx = threadIdx.x & 31, ty = threadIdx.x >> 5;
  const int k0 = bx*32, n0 = by*32;
  for (int i = ty; i < 32; i += 8){
    int k = k0 + i, n = n0 + tx;
    tile[i][tx] = (k < K && n < Nn) ? W[(size_t)k*Nn + n] : 0.f;
  }
  __syncthreads();
  for (int i = ty; i < 32; i += 8){
    int n = n0 + i, k = k0 + tx;
    if (n < Nn && k < Kp) WT[(size_t)n*Kp + k] = f2bf(tile[tx][i]);
  }
}

#define F1_CNT  3125
#define F1_LN   (F1_CNT + 12500)
__global__ __launch_bounds__(256) void fused1(const float* __restrict__ x,
                                              const float* __restrict__ gw,
                                              const float* __restrict__ bw,
                                              ushort_t* __restrict__ xn,
                                              const int* __restrict__ ei,
                                              int* __restrict__ cnt,
                                              const float* W1, const float* Wr,
                                              const float* Wg, const float* W2,
                                              const float* b2, const float* br,
                                              ushort_t* W1T, ushort_t* WrgT,
                                              ushort_t* W2bf, float* b2rg){
  const int bid = blockIdx.x;
  if (bid < F1_CNT){
    int e = bid*256 + threadIdx.x;
    if (e < NE) atomicAdd(&cnt[ei[NE + e]], 1);
    return;
  }
  if (bid < F1_LN){
    const int wid = threadIdx.x >> 6, lane = threadIdx.x & 63;
    const int row = (bid - F1_CNT)*4 + wid;
    if (row >= NND) return;
    const float* xr = x + (size_t)row * DIN;
    // 1 pass, 8 elems/lane/iter (3 iters cover 1536; groups don't straddle 1488)
    f32x4 xa[3], xb[3];
    float s = 0.f, sq = 0.f;
    #pragma unroll
    for (int it = 0; it < 3; ++it){
      const int i = lane*8 + it*512;
      if (i < DIN){
        xa[it] = *(const f32x4*)(xr + i);
        xb[it] = *(const f32x4*)(xr + i + 4);
      } else {
        xa[it] = (f32x4){0.f,0.f,0.f,0.f};
        xb[it] = (f32x4){0.f,0.f,0.f,0.f};
      }
      s  += xa[it].x + xa[it].y + xa[it].z + xa[it].w
          + xb[it].x + xb[it].y + xb[it].z + xb[it].w;
      sq += xa[it].x*xa[it].x + xa[it].y*xa[it].y + xa[it].z*xa[it].z + xa[it].w*xa[it].w
          + xb[it].x*xb[it].x + xb[it].y*xb[it].y + xb[it].z*xb[it].z + xb[it].w*xb[it].w;
    }
    #pragma unroll
    for (int o = 32; o; o >>= 1){ s += __shfl_xor(s, o); sq += __shfl_xor(sq, o); }
    const float mu = s * (1.f/DIN);
    const float var = sq * (1.f/DIN) - mu*mu;
    const float rstd = rsqrtf(var + 1e-5f);
    ushort_t* xo = xn + (size_t)row * DINP;
    #pragma unroll
    for (int it = 0; it < 3; ++it){
      const int i = lane*8 + it*512;
      union { ushort_t u[8]; short8 v; } o;
      if (i < DIN){
        f32x4 ga = *(const f32x4*)(gw + i);
        f32x4 gb = *(const f32x4*)(gw + i + 4);
        f32x4 ba = *(const f32x4*)(bw + i);
        f32x4 bb = *(const f32x4*)(bw + i + 4);
        o.u[0] = f2bf((xa[it].x-mu)*rstd*ga.x + ba.x);
        o.u[1] = f2bf((xa[it].y-mu)*rstd*ga.y + ba.y);
        o.u[2] = f2bf((xa[it].z-mu)*rstd*ga.z + ba.z);
        o.u[3] = f2bf((xa[it].w-mu)*rstd*ga.w + ba.w);
        o.u[4] = f2bf((xb[it].x-mu)*rstd*gb.x + bb.x);
        o.u[5] = f2bf((xb[it].y-mu)*rstd*gb.y + bb.y);
        o.u[6] = f2bf((xb[it].z-mu)*rstd*gb.z + bb.z);
        o.u[7] = f2bf((xb[it].w-mu)*rstd*gb.w + bb.w);
      } else {
        o.u[0]=o.u[1]=o.u[2]=o.u[3]=o.u[4]=o.u[5]=o.u[6]=o.u[7]=0;
      }
      *(short8*)(xo + i) = o.v;     // 16B store (covers K-pad with zeros)
    }
    return;
  }
  {
    int b = bid - F1_LN;
    if (b < 1536){ tc_tile(W1, W1T, DIN, DHID, DINP, b % 48, b / 48); return; }
    b -= 1536;
    if (b < 128){ tc_tile(Wr, WrgT, DOUT, DHC, DOUT, b % 16, b / 16); return; }
    b -= 128;
    if (b < 128){ tc_tile(Wg, WrgT + 256*DOUT, DOUT, DHC, DOUT, b % 16, b / 16); return; }
    b -= 128;
    if (b < 256){                                 // W2 fp32 -> bf16 cast
      const int idx = (b*256 + threadIdx.x)*8;
      f32x4 v0 = *(const f32x4*)(W2 + idx);
      f32x4 v1 = *(const f32x4*)(W2 + idx + 4);
      union { ushort_t u[8]; short8 s; } o;
      o.u[0]=f2bf(v0.x); o.u[1]=f2bf(v0.y); o.u[2]=f2bf(v0.z); o.u[3]=f2bf(v0.w);
      o.u[4]=f2bf(v1.x); o.u[5]=f2bf(v1.y); o.u[6]=f2bf(v1.z); o.u[7]=f2bf(v1.w);
      *(short8*)(W2bf + idx) = o.s;
      return;
    }
    b -= 256;
    {                                             // b2rg fold (2 blocks)
      const int c = b*256 + threadIdx.x;
      float acc = 0.f;
      if (c < 256){
        for (int j = 0; j < DOUT; ++j) acc += b2[j]*Wr[(size_t)j*DHC + c];
        acc += br[c];
      } else {
        const int cc = c - 256;
        for (int j = 0; j < DOUT; ++j) acc += b2[j]*Wg[(size_t)j*DHC + cc];
      }
      b2rg[c] = acc;
      return;
    }
  }
}

// ------- 256x256 8-phase GEMM body (device fn; runtime act; bf16 out) -------
__device__ __forceinline__ void g256p8_body(ushort_t (&lds)[2][2][2][64*128],
                                            const ushort_t* __restrict__ A,
                                            const ushort_t* __restrict__ BT,
                                            const float* __restrict__ bias,
                                            ushort_t* __restrict__ out0,
                                            int M, int Nn, int K,
                                            int bid, int nwg, bool act){
  const int t = threadIdx.x, wid = t >> 6, lane = t & 63;
  const int CB = Nn >> 8;
  const int q = nwg >> 3, r = nwg & 7;
  const int xcd = bid & 7, slot = bid >> 3;
  const int lg = (xcd < r ? xcd*(q+1) : r*(q+1) + (xcd - r)*q) + slot;
  const int brow = (lg / CB) * 256, bcol = (lg % CB) * 256;

  const int l8  = t >> 3;
  const int cb  = (t & 7) << 4;
  const unsigned scb = (unsigned)(cb ^ ((l8 & 7) << 4));
  unsigned rowA[2][2], rowB[2][2];
  #pragma unroll
  for (int hf = 0; hf < 2; ++hf)
    #pragma unroll
    for (int rd = 0; rd < 2; ++rd){
      int ra = brow + hf*128 + rd*64 + l8; ra = ra < M ? ra : M-1;
      int rb = bcol + hf*128 + rd*64 + l8; rb = rb < Nn ? rb : Nn-1;
      rowA[hf][rd] = (unsigned)ra * (unsigned)(K*2);
      rowB[hf][rd] = (unsigned)rb * (unsigned)(K*2);
    }
  const int w8 = wid * 8;

#define STG_A(buf, hf, kt) do {                                               \
    const unsigned _ob = (unsigned)(kt)*128u + scb;                           \
    async16((const char*)A + rowA[hf][0] + _ob, &lds[buf][0][hf][(w8)*64]);   \
    async16((const char*)A + rowA[hf][1] + _ob, &lds[buf][0][hf][(64+w8)*64]);\
  } while(0)
#define STG_B(buf, hf, kt) do {                                               \
    const unsigned _ob = (unsigned)(kt)*128u + scb;                           \
    async16((const char*)BT + rowB[hf][0] + _ob, &lds[buf][1][hf][(w8)*64]);  \
    async16((const char*)BT + rowB[hf][1] + _ob, &lds[buf][1][hf][(64+w8)*64]);\
  } while(0)

  f32x4 acc[8][4];
  #pragma unroll
  for (int i=0;i<8;i++)
    #pragma unroll
    for (int j=0;j<4;j++) acc[i][j] = (f32x4){0.f,0.f,0.f,0.f};

  const int wrow = (wid >> 2), wcol = (wid & 3);
  const int fr = lane & 15;
  const int kb0 = (lane >> 4) << 4;
  const int sx  = (fr & 7) << 4;
  const int ko0 = ((kb0      ) ^ sx) >> 1;
  const int ko1 = ((kb0 | 64 ) ^ sx) >> 1;
  const int bhalf = wcol >> 1, brl = (wcol & 1)*64;

#define RD_A(buf, m) do {                                          \
    const int _ra = ((m)*16 + fr)*64;                              \
    af[m][0] = *(const short8*)&lds[buf][0][wrow][_ra + ko0];      \
    af[m][1] = *(const short8*)&lds[buf][0][wrow][_ra + ko1];      \
  } while(0)
#define RD_B(buf, n) do {                                          \
    const int _rb = (brl + (n)*16 + fr)*64;                        \
    bf[n][0] = *(const short8*)&lds[buf][1][bhalf][_rb + ko0];     \
    bf[n][1] = *(const short8*)&lds[buf][1][bhalf][_rb + ko1];     \
  } while(0)
#define SYNC_PH() do {                                             \
    __builtin_amdgcn_s_barrier();                                  \
    asm volatile("s_waitcnt lgkmcnt(0)" ::: "memory");             \
    __builtin_amdgcn_sched_barrier(0);                             \
  } while(0)
#define MFMA_Q(M0, N0) do {                                        \
    __builtin_amdgcn_s_setprio(1);                                 \
    _Pragma("unroll")                                              \
    for (int _m=(M0); _m<(M0)+4; ++_m)                             \
      _Pragma("unroll")                                            \
      for (int _n=(N0); _n<(N0)+2; ++_n){                          \
        acc[_m][_n] = __builtin_amdgcn_mfma_f32_16x16x32_bf16(af[_m][0], bf[_n][0], acc[_m][_n], 0, 0, 0); \
        acc[_m][_n] = __builtin_amdgcn_mfma_f32_16x16x32_bf16(af[_m][1], bf[_n][1], acc[_m][_n], 0, 0, 0); \
      }                                                            \
    __builtin_amdgcn_s_setprio(0);                                 \
  } while(0)

  const int nk = K >> 6;
  STG_A(0,0,0); STG_A(0,1,0); STG_B(0,0,0); STG_B(0,1,0);
  STG_A(1,0,1); STG_A(1,1,1);
  asm volatile("s_waitcnt vmcnt(4)" ::: "memory");
  __builtin_amdgcn_s_barrier();

  for (int kt = 0; kt < nk; ++kt){
    const int buf = kt & 1, obuf = buf ^ 1;
    short8 af[8][2], bf[4][2];
    RD_A(buf,0); RD_A(buf,1); RD_A(buf,2); RD_A(buf,3);
    RD_B(buf,0); RD_B(buf,1);
    if (kt + 1 < nk) STG_B(obuf, 0, kt + 1);
    SYNC_PH();
    MFMA_Q(0, 0);
    RD_A(buf,4); RD_A(buf,5); RD_A(buf,6); RD_A(buf,7);
    if (kt + 1 < nk) STG_B(obuf, 1, kt + 1);
    SYNC_PH();
    MFMA_Q(4, 0);
    RD_B(buf,2); RD_B(buf,3);
    if (kt + 2 < nk) STG_A(buf, 0, kt + 2);
    SYNC_PH();
    MFMA_Q(0, 2);
    if (kt + 2 < nk){
      STG_A(buf, 1, kt + 2);
      asm volatile("s_waitcnt vmcnt(4)" ::: "memory");
    } else {
      asm volatile("s_waitcnt vmcnt(0)" ::: "memory");
    }
    __builtin_amdgcn_s_barrier();
    MFMA_Q(4, 2);
  }

  float bv[4];
  #pragma unroll
  for (int n=0;n<4;n++){
    const int col = bcol + wcol*64 + n*16 + (lane & 15);
    bv[n] = bias ? bias[col] : 0.f;
  }
  ushort_t* sB = (ushort_t*)&lds[0][0][0][0];
  __syncthreads();
  #pragma unroll
  for (int m=0;m<8;m++){
    const int row = wrow*128 + m*16 + (lane >> 4)*4;
    #pragma unroll
    for (int n=0;n<4;n++){
      const int col = wcol*64 + n*16 + (lane & 15);
      #pragma unroll
      for (int j=0;j<4;j++){
        float v = acc[m][n][j] + bv[n];
        if (act) v = v > 0.f ? v : 0.f;
        sB[(row+j)*256 + col] = f2bf(v);
      }
    }
  }
  __syncthreads();
  const int srow = t >> 5, scol8 = (t & 31) * 8;
  #pragma unroll
  for (int rr = 0; rr < 16; ++rr){
    const int rloc = rr*16 + srow;
    const int grow = brow + rloc;
    if (grow < M)
      *(short8*)(out0 + (size_t)grow*Nn + bcol + scol8) = *(const short8*)&sB[rloc*256 + scol8];
  }
}

// ---- k2 mega kernel: scan (blk 0) + WcT tiny GEMM (blk 1-8) + GEMM1 --------
__global__ __launch_bounds__(512, 1) void mega_gemm(const ushort_t* __restrict__ xn,
                                                    const ushort_t* __restrict__ W1T,
                                                    const float* __restrict__ b1,
                                                    ushort_t* __restrict__ h1,
                                                    const ushort_t* __restrict__ WrgT,
                                                    const ushort_t* __restrict__ W2bf,
                                                    ushort_t* __restrict__ WcT,
                                                    const int* __restrict__ cnt,
                                                    int* __restrict__ offs,
                                                    int* __restrict__ cur){
  __shared__ __align__(16) ushort_t lds[2][2][2][64*128];  // 128 KiB
  const int t = threadIdx.x;

  if (blockIdx.x == 0){
    int* sbuf = (int*)&lds[0][0][0][0];
    const int chunk = (NND + 255) >> 8;                  // 196, mult of 4
    int s = 0;
    if (t < 256){
      const int s0 = t*chunk;
      const int s1 = (s0 + chunk < NND) ? s0 + chunk : NND;
      for (int i = s0; i < s1; i += 4){
        int4v v = *(const int4v*)(cnt + i);
        s += v.x + v.y + v.z + v.w + 4;
      }
    }
    sbuf[t] = s; __syncthreads();
    for (int o = 1; o < 256; o <<= 1){
      int xv = (t >= o && t < 256) ? sbuf[t-o] : 0;
      __syncthreads();
      if (t < 256) sbuf[t] += xv;
      __syncthreads();
    }
    if (t < 256){
      int run = sbuf[t] - s;
      const int s0 = t*chunk;
      const int s1 = (s0 + chunk < NND) ? s0 + chunk : NND;
      for (int i = s0; i < s1; i += 4){
        int4v v = *(const int4v*)(cnt + i);
        int4v cu;
        cu.x = run; run += v.x + 1;
        cu.y = run; run += v.y + 1;
        cu.z = run; run += v.z + 1;
        cu.w = run; run += v.w + 1;
        *(int4v*)(cur + i)  = cu;
        *(int4v*)(offs + i) = cu;
      }
      if (t == 255) offs[NND] = run;
    }
    return;
  }
  if (blockIdx.x < 9){
    g256p8_body(lds, WrgT, W2bf, nullptr, WcT, 512, 1024, 512,
                (int)blockIdx.x - 1, 8, false);
    return;
  }
  g256p8_body(lds, xn, W1T, b1, h1, NND, DHID, DINP,
              (int)blockIdx.x - 9, (int)gridDim.x - 9, true);
}

// ---- k3: 8-phase GEMM [res|gm] = h1 @ WcT^T + b2rg, split epilogue + att ---
// Blocks >= G3_NWG do CSR fill.
#define G3_NWG 392
__global__ __launch_bounds__(512, 1) void gemm3p8(const ushort_t* __restrict__ A,
                                                  const ushort_t* __restrict__ BT,
                                                  const float* __restrict__ bias,
                                                  float* __restrict__ res,
                                                  ushort_t* __restrict__ gm,
                                                  const int* __restrict__ ei,
                                                  int* __restrict__ cur,
                                                  int* __restrict__ eidx,
                                                  const float* __restrict__ att_s,
                                                  const float* __restrict__ att_d,
                                                  float* __restrict__ asrc,
                                                  float* __restrict__ adst){
  __shared__ __align__(16) ushort_t lds[2][2][2][64*128];  // 128 KiB
  const int t = threadIdx.x, wid = t >> 6, lane = t & 63;

  if (blockIdx.x >= G3_NWG){
    int i = (blockIdx.x - G3_NWG)*512 + t;
    if (i < NND){
      int p = atomicAdd(&cur[i], 1); eidx[p] = i;
    } else if (i < NND + NE){
      int e = i - NND;
      int src = ei[e], dst = ei[NE + e];
      int p = atomicAdd(&cur[dst], 1);
      eidx[p] = src;
    }
    return;
  }

  const int M = NND, Nn = 512, K = DHID;
  const int bid = blockIdx.x, nwg = G3_NWG;
  const int CB = 2;
  const int q = nwg >> 3, r = nwg & 7;
  const int xcd = bid & 7, slot = bid >> 3;
  const int lg = (xcd < r ? xcd*(q+1) : r*(q+1) + (xcd - r)*q) + slot;
  const int brow = (lg / CB) * 256, bcol = (lg % CB) * 256;

  const int l8  = t >> 3;
  const int cb  = (t & 7) << 4;
  const unsigned scb = (unsigned)(cb ^ ((l8 & 7) << 4));
  unsigned rowA[2][2], rowB[2][2];
  #pragma unroll
  for (int hf = 0; hf < 2; ++hf)
    #pragma unroll
    for (int rd = 0; rd < 2; ++rd){
      int ra = brow + hf*128 + rd*64 + l8; ra = ra < M ? ra : M-1;
      int rb = bcol + hf*128 + rd*64 + l8; rb = rb < Nn ? rb : Nn-1;
      rowA[hf][rd] = (unsigned)ra * (unsigned)(K*2);
      rowB[hf][rd] = (unsigned)rb * (unsigned)(K*2);
    }
  const int w8 = wid * 8;

  f32x4 acc[8][4];
  #pragma unroll
  for (int i=0;i<8;i++)
    #pragma unroll
    for (int j=0;j<4;j++) acc[i][j] = (f32x4){0.f,0.f,0.f,0.f};

  const int wrow = (wid >> 2), wcol = (wid & 3);
  const int fr = lane & 15;
  const int kb0 = (lane >> 4) << 4;
  const int sx  = (fr & 7) << 4;
  const int ko0 = ((kb0      ) ^ sx) >> 1;
  const int ko1 = ((kb0 | 64 ) ^ sx) >> 1;
  const int bhalf = wcol >> 1, brl = (wcol & 1)*64;

  const int nk = K >> 6;
  STG_A(0,0,0); STG_A(0,1,0); STG_B(0,0,0); STG_B(0,1,0);
  STG_A(1,0,1); STG_A(1,1,1);
  asm volatile("s_waitcnt vmcnt(4)" ::: "memory");
  __builtin_amdgcn_s_barrier();

  for (int kt = 0; kt < nk; ++kt){
    const int buf = kt & 1, obuf = buf ^ 1;
    short8 af[8][2], bf[4][2];
    RD_A(buf,0); RD_A(buf,1); RD_A(buf,2); RD_A(buf,3);
    RD_B(buf,0); RD_B(buf,1);
    if (kt + 1 < nk) STG_B(obuf, 0, kt + 1);
    SYNC_PH();
    MFMA_Q(0, 0);
    RD_A(buf,4); RD_A(buf,5); RD_A(buf,6); RD_A(buf,7);
    if (kt + 1 < nk) STG_B(obuf, 1, kt + 1);
    SYNC_PH();
    MFMA_Q(4, 0);
    RD_B(buf,2); RD_B(buf,3);
    if (kt + 2 < nk) STG_A(buf, 0, kt + 2);
    SYNC_PH();
    MFMA_Q(0, 2);
    if (kt + 2 < nk){
      STG_A(buf, 1, kt + 2);
      asm volatile("s_waitcnt vmcnt(4)" ::: "memory");
    } else {
      asm volatile("s_waitcnt vmcnt(0)" ::: "memory");
    }
    __builtin_amdgcn_s_barrier();
    MFMA_Q(4, 2);
  }
#undef STG_A
#undef STG_B
#undef RD_A
#undef RD_B
#undef SYNC_PH
#undef MFMA_Q

  // ---- split epilogue: bcol==0 -> res f32 (2-pass); bcol==256 -> gm + att --
  float bv[4];
  #pragma unroll
  for (int n=0;n<4;n++){
    const int col = bcol + wcol*64 + n*16 + (lane & 15);
    bv[n] = bias[col];
  }
  if (bcol == 0){
    float* sF = (float*)&lds[0][0][0][0];            // [128][256] f32
    #pragma unroll
    for (int p = 0; p < 2; ++p){
      __syncthreads();
      if (wrow == p){
        #pragma unroll
        for (int m=0;m<8;m++){
          const int row = m*16 + (lane >> 4)*4;
          #pragma unroll
          for (int n=0;n<4;n++){
            const int col = wcol*64 + n*16 + (lane & 15);
            #pragma unroll
            for (int j=0;j<4;j++)
              sF[(row+j)*256 + col] = acc[m][n][j] + bv[n];
          }
        }
      }
      __syncthreads();
      const int srow = t >> 6, scol4 = (t & 63) * 4;
      #pragma unroll
      for (int rr = 0; rr < 16; ++rr){
        const int rloc = rr*8 + srow;
        const int grow = brow + p*128 + rloc;
        if (grow < M)
          *(f32x4*)(res + (size_t)grow*256 + scol4) = *(const f32x4*)&sF[rloc*256 + scol4];
      }
    }
  } else {
    ushort_t* sB = (ushort_t*)&lds[0][0][0][0];      // [256][256] bf16
    __syncthreads();
    #pragma unroll
    for (int m=0;m<8;m++){
      const int row = wrow*128 + m*16 + (lane >> 4)*4;
      #pragma unroll
      for (int n=0;n<4;n++){
        const int col = wcol*64 + n*16 + (lane & 15);
        #pragma unroll
        for (int j=0;j<4;j++)
          sB[(row+j)*256 + col] = f2bf(acc[m][n][j] + bv[n]);
      }
    }
    __syncthreads();
    const int srow = t >> 5, scol8 = (t & 31) * 8;
    #pragma unroll
    for (int rr = 0; rr < 16; ++rr){
      const int rloc = rr*16 + srow;
      const int grow = brow + rloc;
      if (grow < M)
        *(short8*)(gm + (size_t)grow*256 + scol8) = *(const short8*)&sB[rloc*256 + scol8];
    }
    // fused att-scores from the gm tile in LDS
    const int h = t & 7;
    const int hc0 = h * 32;
    #pragma unroll
    for (int k = 0; k < 4; ++k){
      const int rloc = (t >> 3) + k*64;
      const int grow = brow + rloc;
      if (grow < M){
        float a = 0.f, d = 0.f;
        #pragma unroll
        for (int c0 = 0; c0 < 32; c0 += 8){
          short8 gv = *(const short8*)&sB[rloc*256 + hc0 + c0];
          #pragma unroll
          for (int j = 0; j < 8; ++j){
            float g = bf2f((ushort_t)gv[j]);
            a += g*att_s[hc0 + c0 + j];
            d += g*att_d[hc0 + c0 + j];
          }
        }
        asrc[grow*NHD + h] = a;
        adst[grow*NHD + h] = d;
      }
    }
  }
}

// ---- fused GAT aggregate + elu + residual (wave/node, 8-edge chunks) ------
__global__ __launch_bounds__(256) void gat_agg(const int* __restrict__ offs,
                                               const int* __restrict__ eidx,
                                               const float* __restrict__ asrc,
                                               const float* __restrict__ adst,
                                               const ushort_t* __restrict__ gm,
                                               const float* __restrict__ res,
                                               const float* __restrict__ bg,
                                               float* __restrict__ out){
  const int wid = threadIdx.x >> 6, lane = threadIdx.x & 63;
  const int node = blockIdx.x*4 + wid;
  if (node >= NND) return;
  const int h = lane >> 3, jj = lane & 7;
  const int e0 = offs[node], deg = offs[node+1] - e0;
  const float adv = adst[node*NHD + h];

  float mx = -1e30f;
  for (int j = jj; j < deg; j += 8){
    int s = eidx[e0 + j];
    float e = asrc[s*NHD + h] + adv; e = e > 0.f ? e : 0.2f*e;
    mx = fmaxf(mx, e);
  }
  mx = fmaxf(mx, __shfl_xor(mx, 1));
  mx = fmaxf(mx, __shfl_xor(mx, 2));
  mx = fmaxf(mx, __shfl_xor(mx, 4));

  const int c4 = lane*4;
  float sm = 0.f;
  f32x4 acc = {0.f,0.f,0.f,0.f};
  for (int j0 = 0; j0 < deg; j0 += 8){
    const int cnt = (deg - j0) < 8 ? (deg - j0) : 8;
    int s = 0; float w = 0.f;
    if (jj < cnt){
      s = eidx[e0 + j0 + jj];
      float e = asrc[s*NHD + h] + adv; e = e > 0.f ? e : 0.2f*e;
      w = __expf(e - mx);
      sm += w;
    }
    #pragma unroll
    for (int u = 0; u < 8; ++u){
      if (u < cnt){
        const int   su = __builtin_amdgcn_readlane(s, u);
        const float wu = __shfl(w, (h << 3) | u);
        short4v gv = *(const short4v*)(gm + (size_t)su*DHC + c4);
        acc.x += wu*bf2f((ushort_t)gv.x);
        acc.y += wu*bf2f((ushort_t)gv.y);
        acc.z += wu*bf2f((ushort_t)gv.z);
        acc.w += wu*bf2f((ushort_t)gv.w);
      }
    }
  }
  sm += __shfl_xor(sm, 1); sm += __shfl_xor(sm, 2); sm += __shfl_xor(sm, 4);
  const float inv = 1.f/(sm + 1e-16f);

  f32x4 bgv = *(const f32x4*)(bg + c4);
  f32x4 rv  = *(const f32x4*)(res + (size_t)node*DHC + c4);
  f32x4 o;
  #pragma unroll
  for (int q = 0; q < 4; ++q){
    float v = acc[q]*inv + bgv[q];
    v = v > 0.f ? v : expm1f(v);
    o[q] = v + rv[q];
  }
  *(f32x4*)(out + (size_t)node*DHC + c4) = o;
}

extern "C" void kernel_launch(void* const* d_in, const int* in_sizes, int n_in,
                              void* d_out, int out_size, void* d_ws, size_t ws_size,
                              hipStream_t stream){
  (void)in_sizes; (void)n_in; (void)out_size; (void)ws_size;
  const float* x     = (const float*)d_in[0];
  const int*   ei    = (const int*)d_in[1];
  const float* ln_g  = (const float*)d_in[2];
  const float* ln_b  = (const float*)d_in[3];
  const float* W1    = (const float*)d_in[4];
  const float* b1    = (const float*)d_in[5];
  const float* W2    = (const float*)d_in[6];
  const float* b2    = (const float*)d_in[7];
  const float* Wr    = (const float*)d_in[8];
  const float* br    = (const float*)d_in[9];
  const float* Wg    = (const float*)d_in[10];
  const float* att_s = (const float*)d_in[11];
  const float* att_d = (const float*)d_in[12];
  const float* bg    = (const float*)d_in[13];
  float* out = (float*)d_out;

  char* p = (char*)d_ws;
  ushort_t* xn   = (ushort_t*)(p);                   // [0, 153,600,000)
  ushort_t* h1   = (ushort_t*)(p + 153600000);       // -> 256,000,000
  float*    asrc = (float*)(p + 256000000);
  float*    adst = (float*)(p + 257600000);
  int*      cnt  = (int*)(p + 259200000);
  int*      offs = (int*)(p + 259400064);
  int*      cur  = (int*)(p + 259600128);
  int*      eidx = (int*)(p + 259800192);            // -> 263,200,192
  ushort_t* W1T  = (ushort_t*)d_out;                           // 3,145,728
  ushort_t* WrgT = (ushort_t*)((char*)d_out + 3145728);        //   524,288
  ushort_t* W2bf = (ushort_t*)((char*)d_out + 3670016);        // 1,048,576
  ushort_t* WcT  = (ushort_t*)((char*)d_out + 4718592);        // 1,048,576
  float*    b2rg = (float*)((char*)d_out + 5767168);           //     2,048
  float*    res  = (float*)(p + 0);                  //  51,200,000 (f32)
  ushort_t* gm   = (ushort_t*)(p + 51200000);        //  25,600,000 (bf16)

  // k0: zero edge counters (DMA)
  hipMemsetAsync(cnt, 0, NND*sizeof(int), stream);

  // k1: fused count_edges + LN (1-pass, 16B stores) + weight prep
  fused1<<<F1_LN + 2050, 256, 0, stream>>>(
      x, ln_g, ln_b, xn, ei, cnt,
      W1, Wr, Wg, W2, b2, br, W1T, WrgT, W2bf, b2rg);

  // k2: scan (blk 0) + WcT tiny GEMM (blk 1-8) + GEMM1 8-phase (784 blks)
  mega_gemm<<<793, 512, 0, stream>>>(xn, W1T, b1, h1, WrgT, W2bf, WcT,
                                     cnt, offs, cur);

  // k3: 8-phase fused [res|gm] = h1 @ WcT^T + b2rg (split + att + fill)
  gemm3p8<<<G3_NWG + (NND + NE + 511)/512, 512, 0, stream>>>(
      h1, WcT, b2rg, res, gm,
      ei, cur, eidx, att_s, att_d, asrc, adst);

  // k4: GAT aggregate
  gat_agg<<<(NND + 3)/4, 256, 0, stream>>>(offs, eidx, asrc, adst, gm, res, bg, out);
}